// Round 2
// baseline (1208.805 us; speedup 1.0000x reference)
//
#include <hip/hip_runtime.h>

#define BB 64
#define NN 2048
#define QQ 1024
#define SS 512
#define NCH 16
#define PREPB 609
#define QKN3 8

__device__ const int PIDX[36] = {
    0, 2, 5, 8, 12, 17, 22, 27, 32, 38, 45, 52, 59, 66, 73, 80,
    88, 97, 106, 115, 124, 133, 142, 151, 160,
    170, 181, 192, 203, 214, 225, 236, 247, 258, 269, 280};

struct MArgs {
    const float *x, *dirs, *A_sh, *De0, *De1, *De2, *Dc1, *Dc2, *Dc3;
    const float *W0, *b0, *W1, *b1, *W2, *b2;
    const float *g0, *be0, *g1, *be1, *g2, *be2;
    const float *Wfc1, *bfc1, *gfc1, *befc1, *Wfc2, *bfc2, *gfc2, *befc2, *Wout, *bout;
    float *pbuf, *Dg0t, *rs0, *Det1, *Det2, *yq, *ym, *lshp;
    float *ht0, *ht1, *ht2, *stats, *part, *part3, *out;
};

struct SmGemm { float lA[32][68]; float lB[32][68]; float lsu[64]; float ltu[64]; };
struct SmEv   { float lA[32][68]; float lB[32][68]; float sred[2][64]; };
struct SmE0   { float lsh[36][3]; float llm[576]; float lred[4][32]; };

// ================= hand-rolled grid barrier (no cooperative_groups dependency) ============
// Generation-counter barrier; replay-safe (counter returns to 0, gen monotonic).
// __threadfence() = agent-scope acq_rel fence -> cross-XCD L2 writeback/invalidate.
__device__ unsigned long long g_bar_count = 0ull;
__device__ unsigned long long g_bar_gen = 0ull;

__device__ __forceinline__ void gbar() {
    __syncthreads();
    __threadfence();
    if (threadIdx.x == 0) {
        unsigned long long gen =
            __hip_atomic_load(&g_bar_gen, __ATOMIC_RELAXED, __HIP_MEMORY_SCOPE_AGENT);
        unsigned long long arrived =
            __hip_atomic_fetch_add(&g_bar_count, 1ull, __ATOMIC_ACQ_REL, __HIP_MEMORY_SCOPE_AGENT) + 1ull;
        if (arrived == (unsigned long long)gridDim.x) {
            __hip_atomic_store(&g_bar_count, 0ull, __ATOMIC_RELAXED, __HIP_MEMORY_SCOPE_AGENT);
            __hip_atomic_fetch_add(&g_bar_gen, 1ull, __ATOMIC_RELEASE, __HIP_MEMORY_SCOPE_AGENT);
        } else {
            while (__hip_atomic_load(&g_bar_gen, __ATOMIC_ACQUIRE, __HIP_MEMORY_SCOPE_AGENT) == gen)
                __builtin_amdgcn_s_sleep(2);
        }
    }
    __syncthreads();
    __threadfence();
}

// ================= megakernel phase bodies =================
// Each phase leads with __syncthreads() to protect LDS reuse across grid-stride iterations.

__device__ void ph_shell(const MArgs& a, int wb, char* smraw, int tid) {
    __syncthreads();
    float4* lx = reinterpret_cast<float4*>(smraw);
    int b = wb & 63, zc = wb >> 6;
    const float KL = 18.033688011112042f;  // log2(e)/SIGMA2, SIGMA2=0.08
    const float* xb = a.x + ((size_t)b * NN + zc * (NN / NCH)) * 3;
    for (int n = tid; n < NN / NCH; n += 256) {
        float X = xb[n * 3 + 0];
        float Y = xb[n * 3 + 1];
        float Z = xb[n * 3 + 2];
        lx[n] = make_float4(X, Y, Z, -KL * (X * X + Y * Y + Z * Z));
    }
    __syncthreads();
    float cxs[3][2], cys[3][2], czs[3][2], bas[3][2];
#pragma unroll
    for (int i = 0; i < 3; i++) {
        float r = (i == 0) ? 0.4f : ((i == 1) ? 0.8f : 1.2f);
#pragma unroll
        for (int h = 0; h < 2; h++) {
            int s = tid + h * 256;
            float cx = r * a.dirs[(i * SS + s) * 3 + 0];
            float cy = r * a.dirs[(i * SS + s) * 3 + 1];
            float cz = r * a.dirs[(i * SS + s) * 3 + 2];
            bas[i][h] = -KL * (cx * cx + cy * cy + cz * cz);
            cxs[i][h] = 2.f * KL * cx;
            cys[i][h] = 2.f * KL * cy;
            czs[i][h] = 2.f * KL * cz;
        }
    }
    float acc[3][2];
#pragma unroll
    for (int i = 0; i < 3; i++) { acc[i][0] = 0.f; acc[i][1] = 0.f; }
    // exp2(dot+pw+ba) == exp2(dot+pw)*exp2(ba); arg <= KL*|c|^2 <= 26 -> no overflow.
#pragma unroll 4
    for (int n = 0; n < NN / NCH; n++) {
        float4 p = lx[n];
#pragma unroll
        for (int i = 0; i < 3; i++)
#pragma unroll
            for (int h = 0; h < 2; h++)
                acc[i][h] += __builtin_amdgcn_exp2f(
                    fmaf(cxs[i][h], p.x, fmaf(cys[i][h], p.y, fmaf(czs[i][h], p.z, p.w))));
    }
#pragma unroll
    for (int i = 0; i < 3; i++) {
        float* o = a.pbuf + ((size_t)(zc * 3 + i) * BB + b) * SS;
        o[tid] = acc[i][0] * __builtin_amdgcn_exp2f(bas[i][0]);
        o[tid + 256] = acc[i][1] * __builtin_amdgcn_exp2f(bas[i][1]);
    }
}

__device__ void ph_sh(const MArgs& a, int wb, char* smraw, int tid) {
    __syncthreads();
    float* lf = reinterpret_cast<float*>(smraw);
    int b = wb & 63;
    int t = wb >> 6;  // 0..5
    int c = t % 3, h = t / 3;
    float v = 0.f;
#pragma unroll
    for (int zc = 0; zc < NCH; zc++)
        v += a.pbuf[((size_t)(zc * 3 + c) * BB + b) * SS + h * 256 + tid];
    lf[tid] = v * (1.0f / NN);
    __syncthreads();
    int w = tid >> 6, lane = tid & 63;
    for (int j = w; j < 36; j += 4) {
        const float* As = a.A_sh + j * SS + h * 256;
        float acc = 0.f;
#pragma unroll
        for (int k = 0; k < 4; k++) acc = fmaf(lf[lane + 64 * k], As[lane + 64 * k], acc);
#pragma unroll
        for (int o = 32; o > 0; o >>= 1) acc += __shfl_xor(acc, o, 64);
        if (lane == 0) a.lshp[((b * 36 + j) * 3 + c) * 2 + h] = acc;
    }
}

__device__ void ph_prep(const MArgs& a, int wb, char* smraw, int tid) {
    __syncthreads();
    float (*tile)[33] = reinterpret_cast<float (*)[33]>(smraw);
    int r = tid >> 5, c = tid & 31;
    if (wb < 576) {  // De1 -> Det1 [165][1024]
        int i = wb - 384;
        int tq = i & 31, tt = i >> 5;
        int q0 = tq * 32, t0 = tt * 32;
        for (int rr = r; rr < 32; rr += 8) {
            int t = t0 + c;
            tile[rr][c] = (t < 165) ? a.De1[(q0 + rr) * 165 + t] : 0.f;
        }
        __syncthreads();
        for (int rr = r; rr < 32; rr += 8) {
            int t = t0 + rr;
            if (t < 165) a.Det1[t * QQ + q0 + c] = tile[c][rr];
        }
    } else if (wb < 672) {  // De2 -> Det2 [84][1024]
        int i = wb - 576;
        int tq = i & 31, tt = i >> 5;
        int q0 = tq * 32, t0 = tt * 32;
        for (int rr = r; rr < 32; rr += 8) {
            int t = t0 + c;
            tile[rr][c] = (t < 84) ? a.De2[(q0 + rr) * 84 + t] : 0.f;
        }
        __syncthreads();
        for (int rr = r; rr < 32; rr += 8) {
            int t = t0 + rr;
            if (t < 84) a.Det2[t * QQ + q0 + c] = tile[c][rr];
        }
    } else if (wb < 736) {  // gather De0[:, PIDX] -> Dg0t [36][1024]
        int i = wb - 672;
        int tq = i & 31, tj = i >> 5;
        int q0 = tq * 32, j0 = tj * 32;
        for (int rr = r; rr < 32; rr += 8) {
            int j = j0 + c;
            tile[rr][c] = (j < 36) ? a.De0[(q0 + rr) * 286 + PIDX[j]] : 0.f;
        }
        __syncthreads();
        for (int rr = r; rr < 32; rr += 8) {
            int j = j0 + rr;
            if (j < 36) a.Dg0t[j * QQ + q0 + c] = tile[c][rr];
        }
    } else {  // rowsum of De0: one q per wave
        int w = tid >> 6, lane = tid & 63;
        int q = (wb - 736) * 4 + w;
        float s = 0.f;
#pragma unroll
        for (int p = 0; p < 5; p++) {
            int idx = lane + p * 64;
            if (idx < 286) s += a.De0[q * 286 + idx];
        }
#pragma unroll
        for (int o = 32; o > 0; o >>= 1) s += __shfl_xor(s, o, 64);
        if (lane == 0) a.rs0[q] = s;
    }
}

__device__ void ph_eval0(const MArgs& a, int wb, char* smraw, int tid) {
    __syncthreads();
    SmE0& s = *reinterpret_cast<SmE0*>(smraw);
    int qc = wb & 3, b = wb >> 2;
    if (tid < 108) {
        int j = tid / 3, c = tid % 3;
        s.lsh[j][c] = a.lshp[((b * 36 + j) * 3 + c) * 2 + 0] +
                      a.lshp[((b * 36 + j) * 3 + c) * 2 + 1];
    }
    __syncthreads();
    for (int i = tid; i < 576; i += 256) {
        int j = i >> 4, u = i & 15;
        float m = 0.f;
#pragma unroll
        for (int c = 0; c < 3; c++) m = fmaf(s.lsh[j][c], a.W0[c * 16 + u], m);
        s.llm[i] = m;
    }
    __syncthreads();
    int q = qc * 256 + tid;
    float acc[16];
#pragma unroll
    for (int u = 0; u < 16; u++) acc[u] = 0.f;
#pragma unroll 4
    for (int j = 0; j < 36; j++) {
        float d = a.Dg0t[j * QQ + q];
#pragma unroll
        for (int u = 0; u < 16; u++) acc[u] = fmaf(d, s.llm[j * 16 + u], acc[u]);
    }
    float rb = a.rs0[q];
#pragma unroll
    for (int u = 0; u < 16; u++) acc[u] = fmaf(a.b0[u], rb, acc[u]);
#pragma unroll
    for (int u = 0; u < 16; u++) a.yq[((size_t)b * 16 + u) * QQ + q] = acc[u];
    int lane = tid & 63, w = tid >> 6;
#pragma unroll
    for (int u = 0; u < 16; u++) {
        float v = acc[u], v2 = acc[u] * acc[u];
#pragma unroll
        for (int o = 32; o > 0; o >>= 1) {
            v += __shfl_xor(v, o, 64);
            v2 += __shfl_xor(v2, o, 64);
        }
        if (lane == 0) { s.lred[w][u] = v; s.lred[w][16 + u] = v2; }
    }
    __syncthreads();
    if (tid < 32)
        atomicAdd(&a.stats[tid], s.lred[0][tid] + s.lred[1][tid] + s.lred[2][tid] + s.lred[3][tid]);
}

template <int TT, int UU, int QKN>
__device__ void ph_coefG(const float* __restrict__ yq, const float* __restrict__ Dc,
                         const float* __restrict__ stats, const float* __restrict__ g,
                         const float* __restrict__ be, float* __restrict__ part,
                         int mt, int nt, int qk, char* smraw, int tid) {
    __syncthreads();
    constexpr int KC = QQ / QKN;
    SmGemm& s = *reinterpret_cast<SmGemm*>(smraw);
    int m0 = mt * 64, n0 = nt * 64, k0 = qk * KC;
    if (tid < UU) {
        const float inv = 1.0f / (BB * QQ);
        float mm = stats[tid] * inv;
        float var = stats[UU + tid] * inv - mm * mm;
        float sc = g[tid] * rsqrtf(fmaxf(var, 0.f) + 1e-3f);
        s.lsu[tid] = sc;
        s.ltu[tid] = be[tid] - mm * sc;
    }
    __syncthreads();
    int r = tid >> 2, f = (tid & 3) * 4;
    bool mok = (m0 + r) < TT;
    const float* arow = Dc + (size_t)(mok ? (m0 + r) : 0) * QQ;
    const float* brow = yq + (size_t)(n0 + r) * QQ;
    float su = s.lsu[(n0 + r) % UU], tu = s.ltu[(n0 + r) % UU];
    int tg = tid >> 4, ug = tid & 15;
    float acc[4][4];
#pragma unroll
    for (int i = 0; i < 4; i++)
#pragma unroll
        for (int j = 0; j < 4; j++) acc[i][j] = 0.f;
    for (int kb = 0; kb < KC; kb += 32) {
        int kg = k0 + kb;
#pragma unroll
        for (int p = 0; p < 2; p++) {
            int ko = f + p * 16;
            float4 a4 = make_float4(0.f, 0.f, 0.f, 0.f);
            if (mok) a4 = *(const float4*)(arow + kg + ko);
            float4 b4 = *(const float4*)(brow + kg + ko);
#pragma unroll
            for (int i = 0; i < 4; i++) {
                float v = fmaf((&b4.x)[i], su, tu);
                s.lA[ko + i][r] = (&a4.x)[i];
                s.lB[ko + i][r] = (v > 0.f) ? v : 0.3f * v;
            }
        }
        __syncthreads();
#pragma unroll 2
        for (int kk = 0; kk < 32; kk++) {
            float4 a4 = *(const float4*)&s.lA[kk][tg * 4];
            float4 b4 = *(const float4*)&s.lB[kk][ug * 4];
#pragma unroll
            for (int i = 0; i < 4; i++) {
                float av = (&a4.x)[i];
                acc[i][0] = fmaf(av, b4.x, acc[i][0]);
                acc[i][1] = fmaf(av, b4.y, acc[i][1]);
                acc[i][2] = fmaf(av, b4.z, acc[i][2]);
                acc[i][3] = fmaf(av, b4.w, acc[i][3]);
            }
        }
        __syncthreads();
    }
    int n = n0 + ug * 4;
    int b = n / UU, u0 = n % UU;
#pragma unroll
    for (int i = 0; i < 4; i++) {
        int t = m0 + tg * 4 + i;
        if (t < TT)
            *(float4*)&part[(((size_t)qk * BB + b) * TT + t) * UU + u0] =
                make_float4(acc[i][0], acc[i][1], acc[i][2], acc[i][3]);
    }
}

template <int TT, int CC, int UU, int QKN, int TTp, int TS>
__device__ void ph_redmix(const float* __restrict__ part, const float* __restrict__ W,
                          const float* __restrict__ bias, float* __restrict__ ym,
                          int b, int ts, char* smraw, int tid) {
    __syncthreads();
    constexpr int TSL = TTp / TS;
    float* lyt = reinterpret_cast<float*>(smraw);  // [TSL][CC+1]
    int t0 = ts * TSL;
    for (int i = tid; i < TSL * CC; i += 256) {
        int tl = i / CC, c = i % CC;
        int t = t0 + tl;
        float v = 0.f;
        if (t < TT) {
#pragma unroll
            for (int k = 0; k < QKN; k++)
                v += part[(size_t)k * (BB * TT * CC) + ((size_t)b * TT + t) * CC + c];
        }
        lyt[tl * (CC + 1) + c] = v;
    }
    __syncthreads();
    for (int i = tid; i < UU * TSL; i += 256) {
        int u = i / TSL, tl = i % TSL;
        int t = t0 + tl;
        float m = 0.f;
        if (t < TT) {
            m = bias[u];
#pragma unroll
            for (int c = 0; c < CC; c++) m = fmaf(lyt[tl * (CC + 1) + c], W[c * UU + u], m);
        }
        ym[((size_t)b * UU + u) * TTp + t] = m;
    }
}

template <int TT, int TTp, int UU>
__device__ void ph_evalG(const float* __restrict__ ym, const float* __restrict__ Det,
                         float* __restrict__ yq, float* __restrict__ stats,
                         int mt, int qt, char* smraw, int tid) {
    __syncthreads();
    SmEv& s = *reinterpret_cast<SmEv*>(smraw);
    int m0 = mt * 64, q0 = qt * 64;
    int r = tid >> 2, f = (tid & 3) * 4;
    const float* arow = ym + (size_t)(m0 + r) * TTp;
    int br = tid >> 4, bq = (tid & 15) * 4;
    int tg = tid >> 4, ug = tid & 15;
    float acc[4][4];
#pragma unroll
    for (int i = 0; i < 4; i++)
#pragma unroll
        for (int j = 0; j < 4; j++) acc[i][j] = 0.f;
    for (int kb = 0; kb < TT; kb += 32) {
#pragma unroll
        for (int p = 0; p < 2; p++) {
            int ko = f + p * 16;
            float4 a4 = *(const float4*)(arow + kb + ko);
#pragma unroll
            for (int i = 0; i < 4; i++) s.lA[ko + i][r] = (&a4.x)[i];
            int kk = br + p * 16;
            int t = kb + kk;
            float4 b4 = make_float4(0.f, 0.f, 0.f, 0.f);
            if (t < TT) b4 = *(const float4*)(Det + (size_t)t * QQ + q0 + bq);
            *(float4*)&s.lB[kk][bq] = b4;
        }
        __syncthreads();
#pragma unroll 2
        for (int kk = 0; kk < 32; kk++) {
            float4 a4 = *(const float4*)&s.lA[kk][tg * 4];
            float4 b4 = *(const float4*)&s.lB[kk][ug * 4];
#pragma unroll
            for (int i = 0; i < 4; i++) {
                float av = (&a4.x)[i];
                acc[i][0] = fmaf(av, b4.x, acc[i][0]);
                acc[i][1] = fmaf(av, b4.y, acc[i][1]);
                acc[i][2] = fmaf(av, b4.z, acc[i][2]);
                acc[i][3] = fmaf(av, b4.w, acc[i][3]);
            }
        }
        __syncthreads();
    }
    float s1[4], s2[4];
#pragma unroll
    for (int i = 0; i < 4; i++) {
        int m = m0 + tg * 4 + i;
        *(float4*)&yq[(size_t)m * QQ + q0 + ug * 4] =
            make_float4(acc[i][0], acc[i][1], acc[i][2], acc[i][3]);
        s1[i] = (acc[i][0] + acc[i][1]) + (acc[i][2] + acc[i][3]);
        s2[i] = fmaf(acc[i][0], acc[i][0], fmaf(acc[i][1], acc[i][1],
                 fmaf(acc[i][2], acc[i][2], acc[i][3] * acc[i][3])));
    }
#pragma unroll
    for (int o = 1; o < 16; o <<= 1) {
#pragma unroll
        for (int i = 0; i < 4; i++) {
            s1[i] += __shfl_xor(s1[i], o, 64);
            s2[i] += __shfl_xor(s2[i], o, 64);
        }
    }
    if (ug == 0) {
#pragma unroll
        for (int i = 0; i < 4; i++) {
            s.sred[0][tg * 4 + i] = s1[i];
            s.sred[1][tg * 4 + i] = s2[i];
        }
    }
    __syncthreads();
    if (tid < 2 * UU) {
        int which = tid / UU, u = tid % UU;
        float sv = 0.f;
        for (int rr = u; rr < 64; rr += UU) sv += s.sred[which][rr];
        atomicAdd(&stats[which * UU + u], sv);
    }
}

__device__ void ph_norms(const float* __restrict__ part, float* __restrict__ ht0,
                         int b, int blk, char* smraw, int tid) {
    __syncthreads();
    float (*red)[64] = reinterpret_cast<float (*)[64]>(smraw);
    int tq = tid >> 6, u = tid & 63;
    const int offs[4] = {0, 1, 10, 35};
    const int ends[4] = {1, 10, 35, 84};
    float acc = 0.f;
    for (int t = offs[blk] + tq; t < ends[blk]; t += 4) {
        float v = 0.f;
#pragma unroll
        for (int k = 0; k < QKN3; k++)
            v += part[(size_t)k * (BB * 84 * 64) + (b * 84 + t) * 64 + u];
        acc = fmaf(v, v, acc);
    }
    red[tq][u] = acc;
    __syncthreads();
    if (tq == 0) {
        float sv = red[0][u] + red[1][u] + red[2][u] + red[3][u];
        ht0[(blk * 64 + u) * BB + b] = sqrtf(fmaxf(sv, 0.f));
    }
}

template <int K, int J>
__device__ void ph_fc(const float* __restrict__ in, const float* __restrict__ W,
                      const float* __restrict__ bias, const float* __restrict__ g,
                      const float* __restrict__ be, float* __restrict__ out,
                      int j, char* smraw, int tid) {
    __syncthreads();
    float (*red)[64] = reinterpret_cast<float (*)[64]>(smraw);
    int b = tid & 63, kq = tid >> 6;
    constexpr int KS = K / 4;
    int kbeg = kq * KS;
    float a0 = 0.f, a1 = 0.f, a2 = 0.f, a3 = 0.f;
#pragma unroll 4
    for (int k = kbeg; k < kbeg + KS; k += 4) {
        a0 = fmaf(in[k * BB + b], W[(size_t)k * J + j], a0);
        a1 = fmaf(in[(k + 1) * BB + b], W[(size_t)(k + 1) * J + j], a1);
        a2 = fmaf(in[(k + 2) * BB + b], W[(size_t)(k + 2) * J + j], a2);
        a3 = fmaf(in[(k + 3) * BB + b], W[(size_t)(k + 3) * J + j], a3);
    }
    red[kq][b] = (a0 + a1) + (a2 + a3);
    __syncthreads();
    if (kq == 0) {
        float acc = bias[j] + red[0][b] + red[1][b] + red[2][b] + red[3][b];
        float s1 = acc, s2 = acc * acc;
#pragma unroll
        for (int o = 32; o > 0; o >>= 1) {
            s1 += __shfl_xor(s1, o, 64);
            s2 += __shfl_xor(s2, o, 64);
        }
        float m = s1 * (1.0f / 64.f);
        float var = s2 * (1.0f / 64.f) - m * m;
        float sc = g[j] * rsqrtf(fmaxf(var, 0.f) + 1e-3f);
        float v = (acc - m) * sc + be[j];
        out[j * BB + b] = fmaxf(v, 0.f);
    }
}

__device__ void ph_out(const float* __restrict__ ht2, const float* __restrict__ Wout,
                       const float* __restrict__ bout, float* __restrict__ outp,
                       int b, char* smraw, int tid) {
    __syncthreads();
    float (*red)[64] = reinterpret_cast<float (*)[64]>(smraw);
    int o = tid & 63, kq = tid >> 6;
    float a0 = 0.f, a1 = 0.f, a2 = 0.f, a3 = 0.f;
    int kbeg = kq * 64;
    if (o < 40) {
#pragma unroll 4
        for (int k = kbeg; k < kbeg + 64; k += 4) {
            a0 = fmaf(ht2[k * BB + b], Wout[k * 40 + o], a0);
            a1 = fmaf(ht2[(k + 1) * BB + b], Wout[(k + 1) * 40 + o], a1);
            a2 = fmaf(ht2[(k + 2) * BB + b], Wout[(k + 2) * 40 + o], a2);
            a3 = fmaf(ht2[(k + 3) * BB + b], Wout[(k + 3) * 40 + o], a3);
        }
    }
    red[kq][o] = (a0 + a1) + (a2 + a3);
    __syncthreads();
    if (kq == 0) {
        float acc = red[0][o] + red[1][o] + red[2][o] + red[3][o] + ((o < 40) ? bout[o] : 0.f);
        float m = (o < 40) ? acc : -3.0e38f;
#pragma unroll
        for (int s = 32; s > 0; s >>= 1) m = fmaxf(m, __shfl_xor(m, s, 64));
        const float L2E = 1.4426950408889634f;
        float e = (o < 40) ? exp2f((acc - m) * L2E) : 0.f;
        float ssum = e;
#pragma unroll
        for (int s = 32; s > 0; s >>= 1) ssum += __shfl_xor(ssum, s, 64);
        if (o < 40) outp[b * 40 + o] = e / ssum;
    }
}

// ================= megakernel: grid-stride phases, works for any grid size =================
__global__ void __launch_bounds__(256, 2) k_mega(MArgs a) {
    __shared__ __align__(16) char smraw[17920];
    const int tid = threadIdx.x;
    const int G = gridDim.x;
    for (int wb = blockIdx.x; wb < 1024; wb += G) ph_shell(a, wb, smraw, tid);
    gbar();
    for (int wb = blockIdx.x; wb < 993; wb += G) {
        if (wb < 384) ph_sh(a, wb, smraw, tid);
        else if (wb < 992) ph_prep(a, wb, smraw, tid);
        else { __syncthreads(); if (tid < 224) a.stats[tid] = 0.f; }
    }
    gbar();
    for (int wb = blockIdx.x; wb < 256; wb += G) ph_eval0(a, wb, smraw, tid);
    gbar();
    for (int wb = blockIdx.x; wb < 384; wb += G) {
        int mt = wb % 3, t = wb / 3;
        ph_coefG<165, 16, 8>(a.yq, a.Dc1, a.stats, a.g0, a.be0, a.part, mt, t & 15, t >> 4, smraw, tid);
    }
    gbar();
    for (int wb = blockIdx.x; wb < 512; wb += G)
        ph_redmix<165, 16, 32, 8, 192, 8>(a.part, a.W1, a.b1, a.ym, wb & 63, wb >> 6, smraw, tid);
    gbar();
    for (int wb = blockIdx.x; wb < 512; wb += G)
        ph_evalG<165, 192, 32>(a.ym, a.Det1, a.yq, a.stats + 32, wb & 31, wb >> 5, smraw, tid);
    gbar();
    for (int wb = blockIdx.x; wb < 512; wb += G) {
        int mt = wb & 1, t = wb >> 1;
        ph_coefG<84, 32, 8>(a.yq, a.Dc2, a.stats + 32, a.g1, a.be1, a.part, mt, t & 31, t >> 5, smraw, tid);
    }
    gbar();
    for (int wb = blockIdx.x; wb < 512; wb += G)
        ph_redmix<84, 32, 64, 8, 96, 8>(a.part, a.W2, a.b2, a.ym, wb & 63, wb >> 6, smraw, tid);
    gbar();
    for (int wb = blockIdx.x; wb < 1024; wb += G)
        ph_evalG<84, 96, 64>(a.ym, a.Det2, a.yq, a.stats + 96, wb & 63, wb >> 6, smraw, tid);
    gbar();
    for (int wb = blockIdx.x; wb < 1024; wb += G) {
        int mt = wb & 1, t = wb >> 1;
        ph_coefG<84, 64, QKN3>(a.yq, a.Dc3, a.stats + 96, a.g2, a.be2, a.part3, mt, t & 63, t >> 6, smraw, tid);
    }
    gbar();
    for (int wb = blockIdx.x; wb < 256; wb += G) ph_norms(a.part3, a.ht0, wb & 63, wb >> 6, smraw, tid);
    gbar();
    for (int wb = blockIdx.x; wb < 512; wb += G)
        ph_fc<256, 512>(a.ht0, a.Wfc1, a.bfc1, a.gfc1, a.befc1, a.ht1, wb, smraw, tid);
    gbar();
    for (int wb = blockIdx.x; wb < 256; wb += G)
        ph_fc<512, 256>(a.ht1, a.Wfc2, a.bfc2, a.gfc2, a.befc2, a.ht2, wb, smraw, tid);
    gbar();
    for (int wb = blockIdx.x; wb < 64; wb += G) ph_out(a.ht2, a.Wout, a.bout, a.out, wb, smraw, tid);
}

// ================= fallback: the proven 14-kernel pipeline (verbatim baseline) =================
__global__ __launch_bounds__(256) void k_preshell(
    const float* __restrict__ De0, const float* __restrict__ De1, const float* __restrict__ De2,
    float* __restrict__ Dg0t, float* __restrict__ rs0,
    float* __restrict__ Det1, float* __restrict__ Det2,
    float* __restrict__ stats,
    const float* __restrict__ x, const float* __restrict__ dirs, float* __restrict__ pbuf) {
    __shared__ float tile[32][33];
    __shared__ float4 lx[NN / NCH];
    int blk = blockIdx.x, tid = threadIdx.x;
    if (blk < PREPB) {
        int r = tid >> 5, c = tid & 31;
        if (blk < 192) {
            int tq = blk & 31, tt = blk >> 5;
            int q0 = tq * 32, t0 = tt * 32;
            for (int rr = r; rr < 32; rr += 8) {
                int t = t0 + c;
                tile[rr][c] = (t < 165) ? De1[(q0 + rr) * 165 + t] : 0.f;
            }
            __syncthreads();
            for (int rr = r; rr < 32; rr += 8) {
                int t = t0 + rr;
                if (t < 165) Det1[t * QQ + q0 + c] = tile[c][rr];
            }
        } else if (blk < 288) {
            int i = blk - 192;
            int tq = i & 31, tt = i >> 5;
            int q0 = tq * 32, t0 = tt * 32;
            for (int rr = r; rr < 32; rr += 8) {
                int t = t0 + c;
                tile[rr][c] = (t < 84) ? De2[(q0 + rr) * 84 + t] : 0.f;
            }
            __syncthreads();
            for (int rr = r; rr < 32; rr += 8) {
                int t = t0 + rr;
                if (t < 84) Det2[t * QQ + q0 + c] = tile[c][rr];
            }
        } else if (blk < 352) {
            int i = blk - 288;
            int tq = i & 31, tj = i >> 5;
            int q0 = tq * 32, j0 = tj * 32;
            for (int rr = r; rr < 32; rr += 8) {
                int j = j0 + c;
                tile[rr][c] = (j < 36) ? De0[(q0 + rr) * 286 + PIDX[j]] : 0.f;
            }
            __syncthreads();
            for (int rr = r; rr < 32; rr += 8) {
                int j = j0 + rr;
                if (j < 36) Dg0t[j * QQ + q0 + c] = tile[c][rr];
            }
        } else if (blk < 608) {
            int w = tid >> 6, lane = tid & 63;
            int q = (blk - 352) * 4 + w;
            float s = 0.f;
#pragma unroll
            for (int p = 0; p < 5; p++) {
                int idx = lane + p * 64;
                if (idx < 286) s += De0[q * 286 + idx];
            }
#pragma unroll
            for (int o = 32; o > 0; o >>= 1) s += __shfl_xor(s, o, 64);
            if (lane == 0) rs0[q] = s;
        } else {
            if (tid < 224) stats[tid] = 0.f;
        }
        return;
    }
    int idx = blk - PREPB;
    int b = idx & 63, zc = idx >> 6;
    const float KL = 18.033688011112042f;
    const float* xb = x + ((size_t)b * NN + zc * (NN / NCH)) * 3;
    for (int n = tid; n < NN / NCH; n += 256) {
        float X = xb[n * 3 + 0];
        float Y = xb[n * 3 + 1];
        float Z = xb[n * 3 + 2];
        lx[n] = make_float4(X, Y, Z, -KL * (X * X + Y * Y + Z * Z));
    }
    __syncthreads();
    float cxs[3][2], cys[3][2], czs[3][2], bas[3][2];
#pragma unroll
    for (int i = 0; i < 3; i++) {
        float r = (i == 0) ? 0.4f : ((i == 1) ? 0.8f : 1.2f);
#pragma unroll
        for (int h = 0; h < 2; h++) {
            int s = tid + h * 256;
            float cx = r * dirs[(i * SS + s) * 3 + 0];
            float cy = r * dirs[(i * SS + s) * 3 + 1];
            float cz = r * dirs[(i * SS + s) * 3 + 2];
            bas[i][h] = -KL * (cx * cx + cy * cy + cz * cz);
            cxs[i][h] = 2.f * KL * cx;
            cys[i][h] = 2.f * KL * cy;
            czs[i][h] = 2.f * KL * cz;
        }
    }
    float acc[3][2];
#pragma unroll
    for (int i = 0; i < 3; i++) { acc[i][0] = 0.f; acc[i][1] = 0.f; }
#pragma unroll 4
    for (int n = 0; n < NN / NCH; n++) {
        float4 p = lx[n];
#pragma unroll
        for (int i = 0; i < 3; i++)
#pragma unroll
            for (int h = 0; h < 2; h++)
                acc[i][h] += __builtin_amdgcn_exp2f(
                    fmaf(cxs[i][h], p.x, fmaf(cys[i][h], p.y, fmaf(czs[i][h], p.z, p.w + bas[i][h]))));
    }
#pragma unroll
    for (int i = 0; i < 3; i++) {
        float* o = pbuf + ((size_t)(zc * 3 + i) * BB + b) * SS;
        o[tid] = acc[i][0];
        o[tid + 256] = acc[i][1];
    }
}

__global__ __launch_bounds__(256) void k_sh(const float* __restrict__ pbuf,
                                            const float* __restrict__ A_sh,
                                            float* __restrict__ lshp) {
    __shared__ float lf[256];
    int b = blockIdx.x, c = blockIdx.y, h = blockIdx.z, tid = threadIdx.x;
    float v = 0.f;
#pragma unroll
    for (int zc = 0; zc < NCH; zc++)
        v += pbuf[((size_t)(zc * 3 + c) * BB + b) * SS + h * 256 + tid];
    lf[tid] = v * (1.0f / NN);
    __syncthreads();
    int w = tid >> 6, lane = tid & 63;
    for (int j = w; j < 36; j += 4) {
        const float* As = A_sh + j * SS + h * 256;
        float a = 0.f;
#pragma unroll
        for (int k = 0; k < 4; k++) a = fmaf(lf[lane + 64 * k], As[lane + 64 * k], a);
#pragma unroll
        for (int o = 32; o > 0; o >>= 1) a += __shfl_xor(a, o, 64);
        if (lane == 0) lshp[((b * 36 + j) * 3 + c) * 2 + h] = a;
    }
}

__global__ __launch_bounds__(256) void k_eval0(const float* __restrict__ lshp,
                                               const float* __restrict__ W0,
                                               const float* __restrict__ b0,
                                               const float* __restrict__ Dg0t,
                                               const float* __restrict__ rs0,
                                               float* __restrict__ yq, float* __restrict__ stats) {
    __shared__ float lsh[36][3];
    __shared__ float llm[576];
    __shared__ float lred[4][32];
    int qc = blockIdx.x, b = blockIdx.y, tid = threadIdx.x;
    if (tid < 108) {
        int j = tid / 3, c = tid % 3;
        lsh[j][c] = lshp[((b * 36 + j) * 3 + c) * 2 + 0] + lshp[((b * 36 + j) * 3 + c) * 2 + 1];
    }
    __syncthreads();
    for (int i = tid; i < 576; i += 256) {
        int j = i >> 4, u = i & 15;
        float m = 0.f;
#pragma unroll
        for (int c = 0; c < 3; c++) m = fmaf(lsh[j][c], W0[c * 16 + u], m);
        llm[i] = m;
    }
    __syncthreads();
    int q = qc * 256 + tid;
    float acc[16];
#pragma unroll
    for (int u = 0; u < 16; u++) acc[u] = 0.f;
#pragma unroll 4
    for (int j = 0; j < 36; j++) {
        float d = Dg0t[j * QQ + q];
#pragma unroll
        for (int u = 0; u < 16; u++) acc[u] = fmaf(d, llm[j * 16 + u], acc[u]);
    }
    float rb = rs0[q];
#pragma unroll
    for (int u = 0; u < 16; u++) acc[u] = fmaf(b0[u], rb, acc[u]);
#pragma unroll
    for (int u = 0; u < 16; u++) yq[((size_t)b * 16 + u) * QQ + q] = acc[u];
    int lane = tid & 63, w = tid >> 6;
#pragma unroll
    for (int u = 0; u < 16; u++) {
        float v = acc[u], v2 = acc[u] * acc[u];
#pragma unroll
        for (int o = 32; o > 0; o >>= 1) {
            v += __shfl_xor(v, o, 64);
            v2 += __shfl_xor(v2, o, 64);
        }
        if (lane == 0) { lred[w][u] = v; lred[w][16 + u] = v2; }
    }
    __syncthreads();
    if (tid < 32) atomicAdd(&stats[tid], lred[0][tid] + lred[1][tid] + lred[2][tid] + lred[3][tid]);
}

template <int TT, int UU, int QKN>
__global__ __launch_bounds__(256) void k_coefG(const float* __restrict__ yq,
                                               const float* __restrict__ Dc,
                                               const float* __restrict__ stats,
                                               const float* __restrict__ g,
                                               const float* __restrict__ be,
                                               float* __restrict__ part) {
    constexpr int KC = QQ / QKN;
    __shared__ float lA[32][68];
    __shared__ float lB[32][68];
    __shared__ float lsu[UU], ltu[UU];
    int mt = blockIdx.x, nt = blockIdx.y, qk = blockIdx.z, tid = threadIdx.x;
    int m0 = mt * 64, n0 = nt * 64, k0 = qk * KC;
    if (tid < UU) {
        const float inv = 1.0f / (BB * QQ);
        float mm = stats[tid] * inv;
        float var = stats[UU + tid] * inv - mm * mm;
        float s = g[tid] * rsqrtf(fmaxf(var, 0.f) + 1e-3f);
        lsu[tid] = s;
        ltu[tid] = be[tid] - mm * s;
    }
    __syncthreads();
    int r = tid >> 2, f = (tid & 3) * 4;
    bool mok = (m0 + r) < TT;
    const float* arow = Dc + (size_t)(mok ? (m0 + r) : 0) * QQ;
    const float* brow = yq + (size_t)(n0 + r) * QQ;
    float su = lsu[(n0 + r) % UU], tu = ltu[(n0 + r) % UU];
    int tg = tid >> 4, ug = tid & 15;
    float acc[4][4];
#pragma unroll
    for (int i = 0; i < 4; i++)
#pragma unroll
        for (int j = 0; j < 4; j++) acc[i][j] = 0.f;
    for (int kb = 0; kb < KC; kb += 32) {
        int kg = k0 + kb;
#pragma unroll
        for (int p = 0; p < 2; p++) {
            int ko = f + p * 16;
            float4 a4 = make_float4(0.f, 0.f, 0.f, 0.f);
            if (mok) a4 = *(const float4*)(arow + kg + ko);
            float4 b4 = *(const float4*)(brow + kg + ko);
#pragma unroll
            for (int i = 0; i < 4; i++) {
                float v = fmaf((&b4.x)[i], su, tu);
                lA[ko + i][r] = (&a4.x)[i];
                lB[ko + i][r] = (v > 0.f) ? v : 0.3f * v;
            }
        }
        __syncthreads();
#pragma unroll 2
        for (int kk = 0; kk < 32; kk++) {
            float4 a4 = *(const float4*)&lA[kk][tg * 4];
            float4 b4 = *(const float4*)&lB[kk][ug * 4];
#pragma unroll
            for (int i = 0; i < 4; i++) {
                float av = (&a4.x)[i];
                acc[i][0] = fmaf(av, b4.x, acc[i][0]);
                acc[i][1] = fmaf(av, b4.y, acc[i][1]);
                acc[i][2] = fmaf(av, b4.z, acc[i][2]);
                acc[i][3] = fmaf(av, b4.w, acc[i][3]);
            }
        }
        __syncthreads();
    }
    int n = n0 + ug * 4;
    int b = n / UU, u0 = n % UU;
#pragma unroll
    for (int i = 0; i < 4; i++) {
        int t = m0 + tg * 4 + i;
        if (t < TT)
            *(float4*)&part[(((size_t)qk * BB + b) * TT + t) * UU + u0] =
                make_float4(acc[i][0], acc[i][1], acc[i][2], acc[i][3]);
    }
}

template <int TT, int CC, int UU, int QKN, int TTp, int TS>
__global__ __launch_bounds__(256) void k_redmix(const float* __restrict__ part,
                                                const float* __restrict__ W,
                                                const float* __restrict__ bias,
                                                float* __restrict__ ym) {
    constexpr int TSL = TTp / TS;
    __shared__ float lyt[TSL][CC + 1];
    int b = blockIdx.x, ts = blockIdx.y, tid = threadIdx.x;
    int t0 = ts * TSL;
    for (int i = tid; i < TSL * CC; i += 256) {
        int tl = i / CC, c = i % CC;
        int t = t0 + tl;
        float v = 0.f;
        if (t < TT) {
#pragma unroll
            for (int k = 0; k < QKN; k++)
                v += part[(size_t)k * (BB * TT * CC) + ((size_t)b * TT + t) * CC + c];
        }
        lyt[tl][c] = v;
    }
    __syncthreads();
    for (int i = tid; i < UU * TSL; i += 256) {
        int u = i / TSL, tl = i % TSL;
        int t = t0 + tl;
        float m = 0.f;
        if (t < TT) {
            m = bias[u];
#pragma unroll
            for (int c = 0; c < CC; c++) m = fmaf(lyt[tl][c], W[c * UU + u], m);
        }
        ym[((size_t)b * UU + u) * TTp + t] = m;
    }
}

template <int TT, int TTp, int UU>
__global__ __launch_bounds__(256) void k_evalG(const float* __restrict__ ym,
                                               const float* __restrict__ Det,
                                               float* __restrict__ yq,
                                               float* __restrict__ stats) {
    __shared__ float lA[32][68];
    __shared__ float lB[32][68];
    __shared__ float sred[2][64];
    int mt = blockIdx.x, qt = blockIdx.y, tid = threadIdx.x;
    int m0 = mt * 64, q0 = qt * 64;
    int r = tid >> 2, f = (tid & 3) * 4;
    const float* arow = ym + (size_t)(m0 + r) * TTp;
    int br = tid >> 4, bq = (tid & 15) * 4;
    int tg = tid >> 4, ug = tid & 15;
    float acc[4][4];
#pragma unroll
    for (int i = 0; i < 4; i++)
#pragma unroll
        for (int j = 0; j < 4; j++) acc[i][j] = 0.f;
    for (int kb = 0; kb < TT; kb += 32) {
#pragma unroll
        for (int p = 0; p < 2; p++) {
            int ko = f + p * 16;
            float4 a4 = *(const float4*)(arow + kb + ko);
#pragma unroll
            for (int i = 0; i < 4; i++) lA[ko + i][r] = (&a4.x)[i];
            int kk = br + p * 16;
            int t = kb + kk;
            float4 b4 = make_float4(0.f, 0.f, 0.f, 0.f);
            if (t < TT) b4 = *(const float4*)(Det + (size_t)t * QQ + q0 + bq);
            *(float4*)&lB[kk][bq] = b4;
        }
        __syncthreads();
#pragma unroll 2
        for (int kk = 0; kk < 32; kk++) {
            float4 a4 = *(const float4*)&lA[kk][tg * 4];
            float4 b4 = *(const float4*)&lB[kk][ug * 4];
#pragma unroll
            for (int i = 0; i < 4; i++) {
                float av = (&a4.x)[i];
                acc[i][0] = fmaf(av, b4.x, acc[i][0]);
                acc[i][1] = fmaf(av, b4.y, acc[i][1]);
                acc[i][2] = fmaf(av, b4.z, acc[i][2]);
                acc[i][3] = fmaf(av, b4.w, acc[i][3]);
            }
        }
        __syncthreads();
    }
    float s1[4], s2[4];
#pragma unroll
    for (int i = 0; i < 4; i++) {
        int m = m0 + tg * 4 + i;
        *(float4*)&yq[(size_t)m * QQ + q0 + ug * 4] =
            make_float4(acc[i][0], acc[i][1], acc[i][2], acc[i][3]);
        s1[i] = (acc[i][0] + acc[i][1]) + (acc[i][2] + acc[i][3]);
        s2[i] = fmaf(acc[i][0], acc[i][0], fmaf(acc[i][1], acc[i][1],
                 fmaf(acc[i][2], acc[i][2], acc[i][3] * acc[i][3])));
    }
#pragma unroll
    for (int o = 1; o < 16; o <<= 1) {
#pragma unroll
        for (int i = 0; i < 4; i++) {
            s1[i] += __shfl_xor(s1[i], o, 64);
            s2[i] += __shfl_xor(s2[i], o, 64);
        }
    }
    if (ug == 0) {
#pragma unroll
        for (int i = 0; i < 4; i++) {
            sred[0][tg * 4 + i] = s1[i];
            sred[1][tg * 4 + i] = s2[i];
        }
    }
    __syncthreads();
    if (tid < 2 * UU) {
        int which = tid / UU, u = tid % UU;
        float s = 0.f;
        for (int rr = u; rr < 64; rr += UU) s += sred[which][rr];
        atomicAdd(&stats[which * UU + u], s);
    }
}

__global__ __launch_bounds__(256) void k_norms(const float* __restrict__ part, float* __restrict__ ht0) {
    __shared__ float red[4][64];
    int b = blockIdx.x, blk = blockIdx.y;
    int tq = threadIdx.x >> 6, u = threadIdx.x & 63;
    const int offs[4] = {0, 1, 10, 35};
    const int ends[4] = {1, 10, 35, 84};
    float a = 0.f;
    for (int t = offs[blk] + tq; t < ends[blk]; t += 4) {
        float v = 0.f;
#pragma unroll
        for (int k = 0; k < QKN3; k++)
            v += part[(size_t)k * (BB * 84 * 64) + (b * 84 + t) * 64 + u];
        a = fmaf(v, v, a);
    }
    red[tq][u] = a;
    __syncthreads();
    if (tq == 0) {
        float s = red[0][u] + red[1][u] + red[2][u] + red[3][u];
        ht0[(blk * 64 + u) * BB + b] = sqrtf(fmaxf(s, 0.f));
    }
}

template <int K, int J>
__global__ __launch_bounds__(512) void k_fc(const float* __restrict__ in, const float* __restrict__ W,
                                            const float* __restrict__ bias, const float* __restrict__ g,
                                            const float* __restrict__ be, float* __restrict__ out) {
    __shared__ float red[8][64];
    int j = blockIdx.x;
    int b = threadIdx.x & 63, kq = threadIdx.x >> 6;
    constexpr int KS = K / 8;
    int kbeg = kq * KS;
    float a0 = 0.f, a1 = 0.f, a2 = 0.f, a3 = 0.f;
#pragma unroll 4
    for (int k = kbeg; k < kbeg + KS; k += 4) {
        a0 = fmaf(in[k * BB + b], W[(size_t)k * J + j], a0);
        a1 = fmaf(in[(k + 1) * BB + b], W[(size_t)(k + 1) * J + j], a1);
        a2 = fmaf(in[(k + 2) * BB + b], W[(size_t)(k + 2) * J + j], a2);
        a3 = fmaf(in[(k + 3) * BB + b], W[(size_t)(k + 3) * J + j], a3);
    }
    red[kq][b] = (a0 + a1) + (a2 + a3);
    __syncthreads();
    if (kq == 0) {
        float acc = bias[j];
#pragma unroll
        for (int i = 0; i < 8; i++) acc += red[i][b];
        float s1 = acc, s2 = acc * acc;
#pragma unroll
        for (int o = 32; o > 0; o >>= 1) {
            s1 += __shfl_xor(s1, o, 64);
            s2 += __shfl_xor(s2, o, 64);
        }
        float m = s1 * (1.0f / 64.f);
        float var = s2 * (1.0f / 64.f) - m * m;
        float sc = g[j] * rsqrtf(fmaxf(var, 0.f) + 1e-3f);
        float v = (acc - m) * sc + be[j];
        out[j * BB + b] = fmaxf(v, 0.f);
    }
}

__global__ __launch_bounds__(256) void k_out(const float* __restrict__ ht2, const float* __restrict__ Wout,
                                             const float* __restrict__ bout, float* __restrict__ outp) {
    __shared__ float red[4][64];
    __shared__ float sm[64];
    int b = blockIdx.x;
    int o = threadIdx.x & 63, kq = threadIdx.x >> 6;
    float a0 = 0.f, a1 = 0.f, a2 = 0.f, a3 = 0.f;
    int kbeg = kq * 64;
    if (o < 40) {
#pragma unroll 4
        for (int k = kbeg; k < kbeg + 64; k += 4) {
            a0 = fmaf(ht2[k * BB + b], Wout[k * 40 + o], a0);
            a1 = fmaf(ht2[(k + 1) * BB + b], Wout[(k + 1) * 40 + o], a1);
            a2 = fmaf(ht2[(k + 2) * BB + b], Wout[(k + 2) * 40 + o], a2);
            a3 = fmaf(ht2[(k + 3) * BB + b], Wout[(k + 3) * 40 + o], a3);
        }
    }
    red[kq][o] = (a0 + a1) + (a2 + a3);
    __syncthreads();
    if (kq == 0) {
        float acc = red[0][o] + red[1][o] + red[2][o] + red[3][o] + ((o < 40) ? bout[o] : 0.f);
        sm[o] = (o < 40) ? acc : -3.0e38f;
        __syncthreads();
        for (int s = 32; s > 0; s >>= 1) {
            if (o < s) sm[o] = fmaxf(sm[o], sm[o + s]);
            __syncthreads();
        }
        float m = sm[0];
        __syncthreads();
        const float L2E = 1.4426950408889634f;
        float e = (o < 40) ? exp2f((acc - m) * L2E) : 0.f;
        sm[o] = e;
        __syncthreads();
        for (int s = 32; s > 0; s >>= 1) {
            if (o < s) sm[o] += sm[o + s];
            __syncthreads();
        }
        if (o < 40) outp[b * 40 + o] = e / sm[0];
    }
}

// ---------------- workspace layout (float offsets, unchanged) ----------------
#define OFF_PBUF 0
#define OFF_DG0T 1572864
#define OFF_RS0 1609728
#define OFF_DET1 1610752
#define OFF_DET2 1779712
#define OFF_YQ 1865728
#define OFF_YM 6060032
#define OFF_LSH 6453248
#define OFF_HT0 6467072
#define OFF_HT1 6483456
#define OFF_HT2 6516224
#define OFF_STATS 6532608
#define OFF_PART 6532864
#define OFF_PART3 7909120

extern "C" void kernel_launch(void* const* d_in, const int* in_sizes, int n_in,
                              void* d_out, int out_size, void* d_ws, size_t ws_size,
                              hipStream_t stream) {
    float* ws = (float*)d_ws;
    MArgs a;
    a.x = (const float*)d_in[0];
    a.dirs = (const float*)d_in[1];
    a.A_sh = (const float*)d_in[2];
    a.De0 = (const float*)d_in[3];
    a.De1 = (const float*)d_in[4];
    a.De2 = (const float*)d_in[5];
    a.Dc1 = (const float*)d_in[6];
    a.Dc2 = (const float*)d_in[7];
    a.Dc3 = (const float*)d_in[8];
    a.W0 = (const float*)d_in[9];
    a.b0 = (const float*)d_in[10];
    a.W1 = (const float*)d_in[11];
    a.b1 = (const float*)d_in[12];
    a.W2 = (const float*)d_in[13];
    a.b2 = (const float*)d_in[14];
    a.g0 = (const float*)d_in[15];
    a.be0 = (const float*)d_in[16];
    a.g1 = (const float*)d_in[17];
    a.be1 = (const float*)d_in[18];
    a.g2 = (const float*)d_in[19];
    a.be2 = (const float*)d_in[20];
    a.Wfc1 = (const float*)d_in[21];
    a.bfc1 = (const float*)d_in[22];
    a.gfc1 = (const float*)d_in[23];
    a.befc1 = (const float*)d_in[24];
    a.Wfc2 = (const float*)d_in[25];
    a.bfc2 = (const float*)d_in[26];
    a.gfc2 = (const float*)d_in[27];
    a.befc2 = (const float*)d_in[28];
    a.Wout = (const float*)d_in[29];
    a.bout = (const float*)d_in[30];
    a.pbuf = ws + OFF_PBUF;
    a.Dg0t = ws + OFF_DG0T;
    a.rs0 = ws + OFF_RS0;
    a.Det1 = ws + OFF_DET1;
    a.Det2 = ws + OFF_DET2;
    a.yq = ws + OFF_YQ;
    a.ym = ws + OFF_YM;
    a.lshp = ws + OFF_LSH;
    a.ht0 = ws + OFF_HT0;
    a.ht1 = ws + OFF_HT1;
    a.ht2 = ws + OFF_HT2;
    a.stats = ws + OFF_STATS;
    a.part = ws + OFF_PART;
    a.part3 = ws + OFF_PART3;
    a.out = (float*)d_out;

    // ---- one-time cooperative viability gate (host queries only; no stream ops) ----
    static int mode = -1;
    static int gsize = 0;
    if (mode < 0) {
        int dev = 0;
        (void)hipGetDevice(&dev);
        int coop = 0;
        (void)hipDeviceGetAttribute(&coop, hipDeviceAttributeCooperativeLaunch, dev);
        int ncu = 0;
        (void)hipDeviceGetAttribute(&ncu, hipDeviceAttributeMultiprocessorCount, dev);
        int occ = 0;
        hipError_t e = hipOccupancyMaxActiveBlocksPerMultiprocessor(&occ, (const void*)k_mega, 256, 0);
        long long mg = (long long)occ * (long long)ncu;
        if (coop && e == hipSuccess && mg >= 256) {
            gsize = (int)(mg > 1024 ? 1024 : mg);
            mode = 1;
        } else {
            mode = 0;
        }
    }

    if (mode == 1) {
        void* kargs[] = {(void*)&a};
        hipError_t le =
            hipLaunchCooperativeKernel((const void*)k_mega, dim3(gsize), dim3(256), kargs, 0, stream);
        if (le == hipSuccess) return;
        mode = 0;  // permanent fallback if the runtime rejects cooperative launch
    }

    // ---- fallback: proven 14-kernel pipeline ----
    float* stats0 = a.stats;
    float* stats1 = a.stats + 32;
    float* stats2 = a.stats + 96;
    k_preshell<<<PREPB + BB * NCH, 256, 0, stream>>>(
        a.De0, a.De1, a.De2, a.Dg0t, a.rs0, a.Det1, a.Det2, a.stats, a.x, a.dirs, a.pbuf);
    k_sh<<<dim3(BB, 3, 2), 256, 0, stream>>>(a.pbuf, a.A_sh, a.lshp);
    k_eval0<<<dim3(4, BB), 256, 0, stream>>>(a.lshp, a.W0, a.b0, a.Dg0t, a.rs0, a.yq, stats0);
    k_coefG<165, 16, 8><<<dim3(3, 16, 8), 256, 0, stream>>>(a.yq, a.Dc1, stats0, a.g0, a.be0, a.part);
    k_redmix<165, 16, 32, 8, 192, 8><<<dim3(BB, 8), 256, 0, stream>>>(a.part, a.W1, a.b1, a.ym);
    k_evalG<165, 192, 32><<<dim3(32, 16), 256, 0, stream>>>(a.ym, a.Det1, a.yq, stats1);
    k_coefG<84, 32, 8><<<dim3(2, 32, 8), 256, 0, stream>>>(a.yq, a.Dc2, stats1, a.g1, a.be1, a.part);
    k_redmix<84, 32, 64, 8, 96, 8><<<dim3(BB, 8), 256, 0, stream>>>(a.part, a.W2, a.b2, a.ym);
    k_evalG<84, 96, 64><<<dim3(64, 16), 256, 0, stream>>>(a.ym, a.Det2, a.yq, stats2);
    k_coefG<84, 64, QKN3><<<dim3(2, 64, QKN3), 256, 0, stream>>>(a.yq, a.Dc3, stats2, a.g2, a.be2, a.part3);
    k_norms<<<dim3(BB, 4), 256, 0, stream>>>(a.part3, a.ht0);
    k_fc<256, 512><<<512, 512, 0, stream>>>(a.ht0, a.Wfc1, a.bfc1, a.gfc1, a.befc1, a.ht1);
    k_fc<512, 256><<<256, 512, 0, stream>>>(a.ht1, a.Wfc2, a.bfc2, a.gfc2, a.befc2, a.ht2);
    k_out<<<BB, 256, 0, stream>>>(a.ht2, a.Wout, a.bout, a.out);
}

// Round 3
// 499.219 us; speedup vs baseline: 2.4214x; 2.4214x over previous
//
#include <hip/hip_runtime.h>

#define BB 64
#define NN 2048
#define QQ 1024
#define SS 512
#define NCH 16
#define PREPB 609
#define QKN3 8

__device__ const int PIDX[36] = {
    0, 2, 5, 8, 12, 17, 22, 27, 32, 38, 45, 52, 59, 66, 73, 80,
    88, 97, 106, 115, 124, 133, 142, 151, 160,
    170, 181, 192, 203, 214, 225, 236, 247, 258, 269, 280};

struct MArgs {
    const float *x, *dirs, *A_sh, *De0, *De1, *De2, *Dc1, *Dc2, *Dc3;
    const float *W0, *b0, *W1, *b1, *W2, *b2;
    const float *g0, *be0, *g1, *be1, *g2, *be2;
    const float *Wfc1, *bfc1, *gfc1, *befc1, *Wfc2, *bfc2, *gfc2, *befc2, *Wout, *bout;
    float *pbuf, *Dg0t, *rs0, *Det1, *Det2, *yq, *ym, *lshp;
    float *ht0, *ht1, *ht2, *stats, *part, *part3, *out;
};

struct SmGemm { float lA[32][68]; float lB[32][68]; float lsu[64]; float ltu[64]; };
struct SmEv   { float lA[32][68]; float lB[32][68]; float sred[2][64]; };
struct SmE0   { float lsh[36][3]; float llm[576]; float lred[4][32]; };

// ================= tree grid barrier =================
// Spin probes use relaxed atomic RMW (fetch_add 0): executes at the memory-side
// coherence point (fresh cross-XCD value) WITHOUT emitting buffer_inv. Round-2's
// per-iteration ACQUIRE loads invalidated the spinner's whole XCD L2 every probe,
// destroying the cache of still-working blocks (2914us for 68us of VALU work).
// Data visibility = one explicit release fence (wbl2) before arrival and one
// acquire fence (inv) after release detection, per block per barrier.
// State lines padded to 256B. Counters return to 0 each use; gens grow
// monotonically across graph replays. Grid forced to a multiple of 32 host-side.
__device__ unsigned g_grp_cnt[32 * 64];
__device__ unsigned g_grp_gen[32 * 64];
__device__ unsigned g_root_cnt[64];
__device__ unsigned g_root_gen[64];

__device__ __forceinline__ unsigned bar_probe(unsigned* p) {
    return __hip_atomic_fetch_add(p, 0u, __ATOMIC_RELAXED, __HIP_MEMORY_SCOPE_AGENT);
}

__device__ __forceinline__ void gbar() {
    __syncthreads();
    if (threadIdx.x == 0) {
        __builtin_amdgcn_fence(__ATOMIC_RELEASE, "agent");  // wbl2: publish this block's stores
        const int G = (int)gridDim.x;
        const int gsz = G >> 5;  // 32 groups; G is a multiple of 32
        const int grp = (int)blockIdx.x / gsz;
        unsigned* gcnt = &g_grp_cnt[grp << 6];
        unsigned* ggen = &g_grp_gen[grp << 6];
        if ((int)blockIdx.x % gsz == 0) {
            unsigned rg = bar_probe(&g_root_gen[0]);
            while (bar_probe(gcnt) < (unsigned)(gsz - 1)) __builtin_amdgcn_s_sleep(4);
            __hip_atomic_exchange(gcnt, 0u, __ATOMIC_RELAXED, __HIP_MEMORY_SCOPE_AGENT);
            unsigned arrived = __hip_atomic_fetch_add(&g_root_cnt[0], 1u, __ATOMIC_RELAXED,
                                                      __HIP_MEMORY_SCOPE_AGENT) + 1u;
            if (arrived == 32u) {
                __hip_atomic_exchange(&g_root_cnt[0], 0u, __ATOMIC_RELAXED, __HIP_MEMORY_SCOPE_AGENT);
                __hip_atomic_fetch_add(&g_root_gen[0], 1u, __ATOMIC_RELAXED, __HIP_MEMORY_SCOPE_AGENT);
            } else {
                while (bar_probe(&g_root_gen[0]) == rg) __builtin_amdgcn_s_sleep(4);
            }
            __hip_atomic_fetch_add(ggen, 1u, __ATOMIC_RELAXED, __HIP_MEMORY_SCOPE_AGENT);
        } else {
            unsigned gg = bar_probe(ggen);
            __hip_atomic_fetch_add(gcnt, 1u, __ATOMIC_RELAXED, __HIP_MEMORY_SCOPE_AGENT);
            while (bar_probe(ggen) == gg) __builtin_amdgcn_s_sleep(4);
        }
        __builtin_amdgcn_fence(__ATOMIC_ACQUIRE, "agent");  // inv: see other blocks' stores
    }
    __syncthreads();
}

// ================= megakernel phase bodies (unchanged from Round 2, correctness-proven) ====
// Each phase leads with __syncthreads() to protect LDS reuse across grid-stride iterations.

__device__ void ph_shell(const MArgs& a, int wb, char* smraw, int tid) {
    __syncthreads();
    float4* lx = reinterpret_cast<float4*>(smraw);
    int b = wb & 63, zc = wb >> 6;
    const float KL = 18.033688011112042f;  // log2(e)/SIGMA2, SIGMA2=0.08
    const float* xb = a.x + ((size_t)b * NN + zc * (NN / NCH)) * 3;
    for (int n = tid; n < NN / NCH; n += 256) {
        float X = xb[n * 3 + 0];
        float Y = xb[n * 3 + 1];
        float Z = xb[n * 3 + 2];
        lx[n] = make_float4(X, Y, Z, -KL * (X * X + Y * Y + Z * Z));
    }
    __syncthreads();
    float cxs[3][2], cys[3][2], czs[3][2], bas[3][2];
#pragma unroll
    for (int i = 0; i < 3; i++) {
        float r = (i == 0) ? 0.4f : ((i == 1) ? 0.8f : 1.2f);
#pragma unroll
        for (int h = 0; h < 2; h++) {
            int s = tid + h * 256;
            float cx = r * a.dirs[(i * SS + s) * 3 + 0];
            float cy = r * a.dirs[(i * SS + s) * 3 + 1];
            float cz = r * a.dirs[(i * SS + s) * 3 + 2];
            bas[i][h] = -KL * (cx * cx + cy * cy + cz * cz);
            cxs[i][h] = 2.f * KL * cx;
            cys[i][h] = 2.f * KL * cy;
            czs[i][h] = 2.f * KL * cz;
        }
    }
    float acc[3][2];
#pragma unroll
    for (int i = 0; i < 3; i++) { acc[i][0] = 0.f; acc[i][1] = 0.f; }
#pragma unroll 4
    for (int n = 0; n < NN / NCH; n++) {
        float4 p = lx[n];
#pragma unroll
        for (int i = 0; i < 3; i++)
#pragma unroll
            for (int h = 0; h < 2; h++)
                acc[i][h] += __builtin_amdgcn_exp2f(
                    fmaf(cxs[i][h], p.x, fmaf(cys[i][h], p.y, fmaf(czs[i][h], p.z, p.w))));
    }
#pragma unroll
    for (int i = 0; i < 3; i++) {
        float* o = a.pbuf + ((size_t)(zc * 3 + i) * BB + b) * SS;
        o[tid] = acc[i][0] * __builtin_amdgcn_exp2f(bas[i][0]);
        o[tid + 256] = acc[i][1] * __builtin_amdgcn_exp2f(bas[i][1]);
    }
}

__device__ void ph_sh(const MArgs& a, int wb, char* smraw, int tid) {
    __syncthreads();
    float* lf = reinterpret_cast<float*>(smraw);
    int b = wb & 63;
    int t = wb >> 6;  // 0..5
    int c = t % 3, h = t / 3;
    float v = 0.f;
#pragma unroll
    for (int zc = 0; zc < NCH; zc++)
        v += a.pbuf[((size_t)(zc * 3 + c) * BB + b) * SS + h * 256 + tid];
    lf[tid] = v * (1.0f / NN);
    __syncthreads();
    int w = tid >> 6, lane = tid & 63;
    for (int j = w; j < 36; j += 4) {
        const float* As = a.A_sh + j * SS + h * 256;
        float acc = 0.f;
#pragma unroll
        for (int k = 0; k < 4; k++) acc = fmaf(lf[lane + 64 * k], As[lane + 64 * k], acc);
#pragma unroll
        for (int o = 32; o > 0; o >>= 1) acc += __shfl_xor(acc, o, 64);
        if (lane == 0) a.lshp[((b * 36 + j) * 3 + c) * 2 + h] = acc;
    }
}

__device__ void ph_prep(const MArgs& a, int wb, char* smraw, int tid) {
    __syncthreads();
    float (*tile)[33] = reinterpret_cast<float (*)[33]>(smraw);
    int r = tid >> 5, c = tid & 31;
    if (wb < 576) {  // De1 -> Det1 [165][1024]
        int i = wb - 384;
        int tq = i & 31, tt = i >> 5;
        int q0 = tq * 32, t0 = tt * 32;
        for (int rr = r; rr < 32; rr += 8) {
            int t = t0 + c;
            tile[rr][c] = (t < 165) ? a.De1[(q0 + rr) * 165 + t] : 0.f;
        }
        __syncthreads();
        for (int rr = r; rr < 32; rr += 8) {
            int t = t0 + rr;
            if (t < 165) a.Det1[t * QQ + q0 + c] = tile[c][rr];
        }
    } else if (wb < 672) {  // De2 -> Det2 [84][1024]
        int i = wb - 576;
        int tq = i & 31, tt = i >> 5;
        int q0 = tq * 32, t0 = tt * 32;
        for (int rr = r; rr < 32; rr += 8) {
            int t = t0 + c;
            tile[rr][c] = (t < 84) ? a.De2[(q0 + rr) * 84 + t] : 0.f;
        }
        __syncthreads();
        for (int rr = r; rr < 32; rr += 8) {
            int t = t0 + rr;
            if (t < 84) a.Det2[t * QQ + q0 + c] = tile[c][rr];
        }
    } else if (wb < 736) {  // gather De0[:, PIDX] -> Dg0t [36][1024]
        int i = wb - 672;
        int tq = i & 31, tj = i >> 5;
        int q0 = tq * 32, j0 = tj * 32;
        for (int rr = r; rr < 32; rr += 8) {
            int j = j0 + c;
            tile[rr][c] = (j < 36) ? a.De0[(q0 + rr) * 286 + PIDX[j]] : 0.f;
        }
        __syncthreads();
        for (int rr = r; rr < 32; rr += 8) {
            int j = j0 + rr;
            if (j < 36) a.Dg0t[j * QQ + q0 + c] = tile[c][rr];
        }
    } else {  // rowsum of De0: one q per wave
        int w = tid >> 6, lane = tid & 63;
        int q = (wb - 736) * 4 + w;
        float s = 0.f;
#pragma unroll
        for (int p = 0; p < 5; p++) {
            int idx = lane + p * 64;
            if (idx < 286) s += a.De0[q * 286 + idx];
        }
#pragma unroll
        for (int o = 32; o > 0; o >>= 1) s += __shfl_xor(s, o, 64);
        if (lane == 0) a.rs0[q] = s;
    }
}

__device__ void ph_eval0(const MArgs& a, int wb, char* smraw, int tid) {
    __syncthreads();
    SmE0& s = *reinterpret_cast<SmE0*>(smraw);
    int qc = wb & 3, b = wb >> 2;
    if (tid < 108) {
        int j = tid / 3, c = tid % 3;
        s.lsh[j][c] = a.lshp[((b * 36 + j) * 3 + c) * 2 + 0] +
                      a.lshp[((b * 36 + j) * 3 + c) * 2 + 1];
    }
    __syncthreads();
    for (int i = tid; i < 576; i += 256) {
        int j = i >> 4, u = i & 15;
        float m = 0.f;
#pragma unroll
        for (int c = 0; c < 3; c++) m = fmaf(s.lsh[j][c], a.W0[c * 16 + u], m);
        s.llm[i] = m;
    }
    __syncthreads();
    int q = qc * 256 + tid;
    float acc[16];
#pragma unroll
    for (int u = 0; u < 16; u++) acc[u] = 0.f;
#pragma unroll 4
    for (int j = 0; j < 36; j++) {
        float d = a.Dg0t[j * QQ + q];
#pragma unroll
        for (int u = 0; u < 16; u++) acc[u] = fmaf(d, s.llm[j * 16 + u], acc[u]);
    }
    float rb = a.rs0[q];
#pragma unroll
    for (int u = 0; u < 16; u++) acc[u] = fmaf(a.b0[u], rb, acc[u]);
#pragma unroll
    for (int u = 0; u < 16; u++) a.yq[((size_t)b * 16 + u) * QQ + q] = acc[u];
    int lane = tid & 63, w = tid >> 6;
#pragma unroll
    for (int u = 0; u < 16; u++) {
        float v = acc[u], v2 = acc[u] * acc[u];
#pragma unroll
        for (int o = 32; o > 0; o >>= 1) {
            v += __shfl_xor(v, o, 64);
            v2 += __shfl_xor(v2, o, 64);
        }
        if (lane == 0) { s.lred[w][u] = v; s.lred[w][16 + u] = v2; }
    }
    __syncthreads();
    if (tid < 32)
        atomicAdd(&a.stats[tid], s.lred[0][tid] + s.lred[1][tid] + s.lred[2][tid] + s.lred[3][tid]);
}

template <int TT, int UU, int QKN>
__device__ void ph_coefG(const float* __restrict__ yq, const float* __restrict__ Dc,
                         const float* __restrict__ stats, const float* __restrict__ g,
                         const float* __restrict__ be, float* __restrict__ part,
                         int mt, int nt, int qk, char* smraw, int tid) {
    __syncthreads();
    constexpr int KC = QQ / QKN;
    SmGemm& s = *reinterpret_cast<SmGemm*>(smraw);
    int m0 = mt * 64, n0 = nt * 64, k0 = qk * KC;
    if (tid < UU) {
        const float inv = 1.0f / (BB * QQ);
        float mm = stats[tid] * inv;
        float var = stats[UU + tid] * inv - mm * mm;
        float sc = g[tid] * rsqrtf(fmaxf(var, 0.f) + 1e-3f);
        s.lsu[tid] = sc;
        s.ltu[tid] = be[tid] - mm * sc;
    }
    __syncthreads();
    int r = tid >> 2, f = (tid & 3) * 4;
    bool mok = (m0 + r) < TT;
    const float* arow = Dc + (size_t)(mok ? (m0 + r) : 0) * QQ;
    const float* brow = yq + (size_t)(n0 + r) * QQ;
    float su = s.lsu[(n0 + r) % UU], tu = s.ltu[(n0 + r) % UU];
    int tg = tid >> 4, ug = tid & 15;
    float acc[4][4];
#pragma unroll
    for (int i = 0; i < 4; i++)
#pragma unroll
        for (int j = 0; j < 4; j++) acc[i][j] = 0.f;
    for (int kb = 0; kb < KC; kb += 32) {
        int kg = k0 + kb;
#pragma unroll
        for (int p = 0; p < 2; p++) {
            int ko = f + p * 16;
            float4 a4 = make_float4(0.f, 0.f, 0.f, 0.f);
            if (mok) a4 = *(const float4*)(arow + kg + ko);
            float4 b4 = *(const float4*)(brow + kg + ko);
#pragma unroll
            for (int i = 0; i < 4; i++) {
                float v = fmaf((&b4.x)[i], su, tu);
                s.lA[ko + i][r] = (&a4.x)[i];
                s.lB[ko + i][r] = (v > 0.f) ? v : 0.3f * v;
            }
        }
        __syncthreads();
#pragma unroll 2
        for (int kk = 0; kk < 32; kk++) {
            float4 a4 = *(const float4*)&s.lA[kk][tg * 4];
            float4 b4 = *(const float4*)&s.lB[kk][ug * 4];
#pragma unroll
            for (int i = 0; i < 4; i++) {
                float av = (&a4.x)[i];
                acc[i][0] = fmaf(av, b4.x, acc[i][0]);
                acc[i][1] = fmaf(av, b4.y, acc[i][1]);
                acc[i][2] = fmaf(av, b4.z, acc[i][2]);
                acc[i][3] = fmaf(av, b4.w, acc[i][3]);
            }
        }
        __syncthreads();
    }
    int n = n0 + ug * 4;
    int b = n / UU, u0 = n % UU;
#pragma unroll
    for (int i = 0; i < 4; i++) {
        int t = m0 + tg * 4 + i;
        if (t < TT)
            *(float4*)&part[(((size_t)qk * BB + b) * TT + t) * UU + u0] =
                make_float4(acc[i][0], acc[i][1], acc[i][2], acc[i][3]);
    }
}

template <int TT, int CC, int UU, int QKN, int TTp, int TS>
__device__ void ph_redmix(const float* __restrict__ part, const float* __restrict__ W,
                          const float* __restrict__ bias, float* __restrict__ ym,
                          int b, int ts, char* smraw, int tid) {
    __syncthreads();
    constexpr int TSL = TTp / TS;
    float* lyt = reinterpret_cast<float*>(smraw);  // [TSL][CC+1]
    int t0 = ts * TSL;
    for (int i = tid; i < TSL * CC; i += 256) {
        int tl = i / CC, c = i % CC;
        int t = t0 + tl;
        float v = 0.f;
        if (t < TT) {
#pragma unroll
            for (int k = 0; k < QKN; k++)
                v += part[(size_t)k * (BB * TT * CC) + ((size_t)b * TT + t) * CC + c];
        }
        lyt[tl * (CC + 1) + c] = v;
    }
    __syncthreads();
    for (int i = tid; i < UU * TSL; i += 256) {
        int u = i / TSL, tl = i % TSL;
        int t = t0 + tl;
        float m = 0.f;
        if (t < TT) {
            m = bias[u];
#pragma unroll
            for (int c = 0; c < CC; c++) m = fmaf(lyt[tl * (CC + 1) + c], W[c * UU + u], m);
        }
        ym[((size_t)b * UU + u) * TTp + t] = m;
    }
}

template <int TT, int TTp, int UU>
__device__ void ph_evalG(const float* __restrict__ ym, const float* __restrict__ Det,
                         float* __restrict__ yq, float* __restrict__ stats,
                         int mt, int qt, char* smraw, int tid) {
    __syncthreads();
    SmEv& s = *reinterpret_cast<SmEv*>(smraw);
    int m0 = mt * 64, q0 = qt * 64;
    int r = tid >> 2, f = (tid & 3) * 4;
    const float* arow = ym + (size_t)(m0 + r) * TTp;
    int br = tid >> 4, bq = (tid & 15) * 4;
    int tg = tid >> 4, ug = tid & 15;
    float acc[4][4];
#pragma unroll
    for (int i = 0; i < 4; i++)
#pragma unroll
        for (int j = 0; j < 4; j++) acc[i][j] = 0.f;
    for (int kb = 0; kb < TT; kb += 32) {
#pragma unroll
        for (int p = 0; p < 2; p++) {
            int ko = f + p * 16;
            float4 a4 = *(const float4*)(arow + kb + ko);
#pragma unroll
            for (int i = 0; i < 4; i++) s.lA[ko + i][r] = (&a4.x)[i];
            int kk = br + p * 16;
            int t = kb + kk;
            float4 b4 = make_float4(0.f, 0.f, 0.f, 0.f);
            if (t < TT) b4 = *(const float4*)(Det + (size_t)t * QQ + q0 + bq);
            *(float4*)&s.lB[kk][bq] = b4;
        }
        __syncthreads();
#pragma unroll 2
        for (int kk = 0; kk < 32; kk++) {
            float4 a4 = *(const float4*)&s.lA[kk][tg * 4];
            float4 b4 = *(const float4*)&s.lB[kk][ug * 4];
#pragma unroll
            for (int i = 0; i < 4; i++) {
                float av = (&a4.x)[i];
                acc[i][0] = fmaf(av, b4.x, acc[i][0]);
                acc[i][1] = fmaf(av, b4.y, acc[i][1]);
                acc[i][2] = fmaf(av, b4.z, acc[i][2]);
                acc[i][3] = fmaf(av, b4.w, acc[i][3]);
            }
        }
        __syncthreads();
    }
    float s1[4], s2[4];
#pragma unroll
    for (int i = 0; i < 4; i++) {
        int m = m0 + tg * 4 + i;
        *(float4*)&yq[(size_t)m * QQ + q0 + ug * 4] =
            make_float4(acc[i][0], acc[i][1], acc[i][2], acc[i][3]);
        s1[i] = (acc[i][0] + acc[i][1]) + (acc[i][2] + acc[i][3]);
        s2[i] = fmaf(acc[i][0], acc[i][0], fmaf(acc[i][1], acc[i][1],
                 fmaf(acc[i][2], acc[i][2], acc[i][3] * acc[i][3])));
    }
#pragma unroll
    for (int o = 1; o < 16; o <<= 1) {
#pragma unroll
        for (int i = 0; i < 4; i++) {
            s1[i] += __shfl_xor(s1[i], o, 64);
            s2[i] += __shfl_xor(s2[i], o, 64);
        }
    }
    if (ug == 0) {
#pragma unroll
        for (int i = 0; i < 4; i++) {
            s.sred[0][tg * 4 + i] = s1[i];
            s.sred[1][tg * 4 + i] = s2[i];
        }
    }
    __syncthreads();
    if (tid < 2 * UU) {
        int which = tid / UU, u = tid % UU;
        float sv = 0.f;
        for (int rr = u; rr < 64; rr += UU) sv += s.sred[which][rr];
        atomicAdd(&stats[which * UU + u], sv);
    }
}

__device__ void ph_norms(const float* __restrict__ part, float* __restrict__ ht0,
                         int b, int blk, char* smraw, int tid) {
    __syncthreads();
    float (*red)[64] = reinterpret_cast<float (*)[64]>(smraw);
    int tq = tid >> 6, u = tid & 63;
    const int offs[4] = {0, 1, 10, 35};
    const int ends[4] = {1, 10, 35, 84};
    float acc = 0.f;
    for (int t = offs[blk] + tq; t < ends[blk]; t += 4) {
        float v = 0.f;
#pragma unroll
        for (int k = 0; k < QKN3; k++)
            v += part[(size_t)k * (BB * 84 * 64) + (b * 84 + t) * 64 + u];
        acc = fmaf(v, v, acc);
    }
    red[tq][u] = acc;
    __syncthreads();
    if (tq == 0) {
        float sv = red[0][u] + red[1][u] + red[2][u] + red[3][u];
        ht0[(blk * 64 + u) * BB + b] = sqrtf(fmaxf(sv, 0.f));
    }
}

template <int K, int J>
__device__ void ph_fc(const float* __restrict__ in, const float* __restrict__ W,
                      const float* __restrict__ bias, const float* __restrict__ g,
                      const float* __restrict__ be, float* __restrict__ out,
                      int j, char* smraw, int tid) {
    __syncthreads();
    float (*red)[64] = reinterpret_cast<float (*)[64]>(smraw);
    int b = tid & 63, kq = tid >> 6;
    constexpr int KS = K / 4;
    int kbeg = kq * KS;
    float a0 = 0.f, a1 = 0.f, a2 = 0.f, a3 = 0.f;
#pragma unroll 4
    for (int k = kbeg; k < kbeg + KS; k += 4) {
        a0 = fmaf(in[k * BB + b], W[(size_t)k * J + j], a0);
        a1 = fmaf(in[(k + 1) * BB + b], W[(size_t)(k + 1) * J + j], a1);
        a2 = fmaf(in[(k + 2) * BB + b], W[(size_t)(k + 2) * J + j], a2);
        a3 = fmaf(in[(k + 3) * BB + b], W[(size_t)(k + 3) * J + j], a3);
    }
    red[kq][b] = (a0 + a1) + (a2 + a3);
    __syncthreads();
    if (kq == 0) {
        float acc = bias[j] + red[0][b] + red[1][b] + red[2][b] + red[3][b];
        float s1 = acc, s2 = acc * acc;
#pragma unroll
        for (int o = 32; o > 0; o >>= 1) {
            s1 += __shfl_xor(s1, o, 64);
            s2 += __shfl_xor(s2, o, 64);
        }
        float m = s1 * (1.0f / 64.f);
        float var = s2 * (1.0f / 64.f) - m * m;
        float sc = g[j] * rsqrtf(fmaxf(var, 0.f) + 1e-3f);
        float v = (acc - m) * sc + be[j];
        out[j * BB + b] = fmaxf(v, 0.f);
    }
}

__device__ void ph_out(const float* __restrict__ ht2, const float* __restrict__ Wout,
                       const float* __restrict__ bout, float* __restrict__ outp,
                       int b, char* smraw, int tid) {
    __syncthreads();
    float (*red)[64] = reinterpret_cast<float (*)[64]>(smraw);
    int o = tid & 63, kq = tid >> 6;
    float a0 = 0.f, a1 = 0.f, a2 = 0.f, a3 = 0.f;
    int kbeg = kq * 64;
    if (o < 40) {
#pragma unroll 4
        for (int k = kbeg; k < kbeg + 64; k += 4) {
            a0 = fmaf(ht2[k * BB + b], Wout[k * 40 + o], a0);
            a1 = fmaf(ht2[(k + 1) * BB + b], Wout[(k + 1) * 40 + o], a1);
            a2 = fmaf(ht2[(k + 2) * BB + b], Wout[(k + 2) * 40 + o], a2);
            a3 = fmaf(ht2[(k + 3) * BB + b], Wout[(k + 3) * 40 + o], a3);
        }
    }
    red[kq][o] = (a0 + a1) + (a2 + a3);
    __syncthreads();
    if (kq == 0) {
        float acc = red[0][o] + red[1][o] + red[2][o] + red[3][o] + ((o < 40) ? bout[o] : 0.f);
        float m = (o < 40) ? acc : -3.0e38f;
#pragma unroll
        for (int s = 32; s > 0; s >>= 1) m = fmaxf(m, __shfl_xor(m, s, 64));
        const float L2E = 1.4426950408889634f;
        float e = (o < 40) ? exp2f((acc - m) * L2E) : 0.f;
        float ssum = e;
#pragma unroll
        for (int s = 32; s > 0; s >>= 1) ssum += __shfl_xor(ssum, s, 64);
        if (o < 40) outp[b * 40 + o] = e / ssum;
    }
}

// ================= megakernel: grid-stride phases, works for any grid size =================
__global__ void __launch_bounds__(256, 2) k_mega(MArgs a) {
    __shared__ __align__(16) char smraw[17920];
    const int tid = threadIdx.x;
    const int G = gridDim.x;
    for (int wb = blockIdx.x; wb < 1024; wb += G) ph_shell(a, wb, smraw, tid);
    gbar();
    for (int wb = blockIdx.x; wb < 993; wb += G) {
        if (wb < 384) ph_sh(a, wb, smraw, tid);
        else if (wb < 992) ph_prep(a, wb, smraw, tid);
        else { __syncthreads(); if (tid < 224) a.stats[tid] = 0.f; }
    }
    gbar();
    for (int wb = blockIdx.x; wb < 256; wb += G) ph_eval0(a, wb, smraw, tid);
    gbar();
    for (int wb = blockIdx.x; wb < 384; wb += G) {
        int mt = wb % 3, t = wb / 3;
        ph_coefG<165, 16, 8>(a.yq, a.Dc1, a.stats, a.g0, a.be0, a.part, mt, t & 15, t >> 4, smraw, tid);
    }
    gbar();
    for (int wb = blockIdx.x; wb < 512; wb += G)
        ph_redmix<165, 16, 32, 8, 192, 8>(a.part, a.W1, a.b1, a.ym, wb & 63, wb >> 6, smraw, tid);
    gbar();
    for (int wb = blockIdx.x; wb < 512; wb += G)
        ph_evalG<165, 192, 32>(a.ym, a.Det1, a.yq, a.stats + 32, wb & 31, wb >> 5, smraw, tid);
    gbar();
    for (int wb = blockIdx.x; wb < 512; wb += G) {
        int mt = wb & 1, t = wb >> 1;
        ph_coefG<84, 32, 8>(a.yq, a.Dc2, a.stats + 32, a.g1, a.be1, a.part, mt, t & 31, t >> 5, smraw, tid);
    }
    gbar();
    for (int wb = blockIdx.x; wb < 512; wb += G)
        ph_redmix<84, 32, 64, 8, 96, 8>(a.part, a.W2, a.b2, a.ym, wb & 63, wb >> 6, smraw, tid);
    gbar();
    for (int wb = blockIdx.x; wb < 1024; wb += G)
        ph_evalG<84, 96, 64>(a.ym, a.Det2, a.yq, a.stats + 96, wb & 63, wb >> 6, smraw, tid);
    gbar();
    for (int wb = blockIdx.x; wb < 1024; wb += G) {
        int mt = wb & 1, t = wb >> 1;
        ph_coefG<84, 64, QKN3>(a.yq, a.Dc3, a.stats + 96, a.g2, a.be2, a.part3, mt, t & 63, t >> 6, smraw, tid);
    }
    gbar();
    for (int wb = blockIdx.x; wb < 256; wb += G) ph_norms(a.part3, a.ht0, wb & 63, wb >> 6, smraw, tid);
    gbar();
    for (int wb = blockIdx.x; wb < 512; wb += G)
        ph_fc<256, 512>(a.ht0, a.Wfc1, a.bfc1, a.gfc1, a.befc1, a.ht1, wb, smraw, tid);
    gbar();
    for (int wb = blockIdx.x; wb < 256; wb += G)
        ph_fc<512, 256>(a.ht1, a.Wfc2, a.bfc2, a.gfc2, a.befc2, a.ht2, wb, smraw, tid);
    gbar();
    for (int wb = blockIdx.x; wb < 64; wb += G) ph_out(a.ht2, a.Wout, a.bout, a.out, wb, smraw, tid);
}

// ================= fallback: the proven 14-kernel pipeline (verbatim baseline) =================
__global__ __launch_bounds__(256) void k_preshell(
    const float* __restrict__ De0, const float* __restrict__ De1, const float* __restrict__ De2,
    float* __restrict__ Dg0t, float* __restrict__ rs0,
    float* __restrict__ Det1, float* __restrict__ Det2,
    float* __restrict__ stats,
    const float* __restrict__ x, const float* __restrict__ dirs, float* __restrict__ pbuf) {
    __shared__ float tile[32][33];
    __shared__ float4 lx[NN / NCH];
    int blk = blockIdx.x, tid = threadIdx.x;
    if (blk < PREPB) {
        int r = tid >> 5, c = tid & 31;
        if (blk < 192) {
            int tq = blk & 31, tt = blk >> 5;
            int q0 = tq * 32, t0 = tt * 32;
            for (int rr = r; rr < 32; rr += 8) {
                int t = t0 + c;
                tile[rr][c] = (t < 165) ? De1[(q0 + rr) * 165 + t] : 0.f;
            }
            __syncthreads();
            for (int rr = r; rr < 32; rr += 8) {
                int t = t0 + rr;
                if (t < 165) Det1[t * QQ + q0 + c] = tile[c][rr];
            }
        } else if (blk < 288) {
            int i = blk - 192;
            int tq = i & 31, tt = i >> 5;
            int q0 = tq * 32, t0 = tt * 32;
            for (int rr = r; rr < 32; rr += 8) {
                int t = t0 + c;
                tile[rr][c] = (t < 84) ? De2[(q0 + rr) * 84 + t] : 0.f;
            }
            __syncthreads();
            for (int rr = r; rr < 32; rr += 8) {
                int t = t0 + rr;
                if (t < 84) Det2[t * QQ + q0 + c] = tile[c][rr];
            }
        } else if (blk < 352) {
            int i = blk - 288;
            int tq = i & 31, tj = i >> 5;
            int q0 = tq * 32, j0 = tj * 32;
            for (int rr = r; rr < 32; rr += 8) {
                int j = j0 + c;
                tile[rr][c] = (j < 36) ? De0[(q0 + rr) * 286 + PIDX[j]] : 0.f;
            }
            __syncthreads();
            for (int rr = r; rr < 32; rr += 8) {
                int j = j0 + rr;
                if (j < 36) Dg0t[j * QQ + q0 + c] = tile[c][rr];
            }
        } else if (blk < 608) {
            int w = tid >> 6, lane = tid & 63;
            int q = (blk - 352) * 4 + w;
            float s = 0.f;
#pragma unroll
            for (int p = 0; p < 5; p++) {
                int idx = lane + p * 64;
                if (idx < 286) s += De0[q * 286 + idx];
            }
#pragma unroll
            for (int o = 32; o > 0; o >>= 1) s += __shfl_xor(s, o, 64);
            if (lane == 0) rs0[q] = s;
        } else {
            if (tid < 224) stats[tid] = 0.f;
        }
        return;
    }
    int idx = blk - PREPB;
    int b = idx & 63, zc = idx >> 6;
    const float KL = 18.033688011112042f;
    const float* xb = x + ((size_t)b * NN + zc * (NN / NCH)) * 3;
    for (int n = tid; n < NN / NCH; n += 256) {
        float X = xb[n * 3 + 0];
        float Y = xb[n * 3 + 1];
        float Z = xb[n * 3 + 2];
        lx[n] = make_float4(X, Y, Z, -KL * (X * X + Y * Y + Z * Z));
    }
    __syncthreads();
    float cxs[3][2], cys[3][2], czs[3][2], bas[3][2];
#pragma unroll
    for (int i = 0; i < 3; i++) {
        float r = (i == 0) ? 0.4f : ((i == 1) ? 0.8f : 1.2f);
#pragma unroll
        for (int h = 0; h < 2; h++) {
            int s = tid + h * 256;
            float cx = r * dirs[(i * SS + s) * 3 + 0];
            float cy = r * dirs[(i * SS + s) * 3 + 1];
            float cz = r * dirs[(i * SS + s) * 3 + 2];
            bas[i][h] = -KL * (cx * cx + cy * cy + cz * cz);
            cxs[i][h] = 2.f * KL * cx;
            cys[i][h] = 2.f * KL * cy;
            czs[i][h] = 2.f * KL * cz;
        }
    }
    float acc[3][2];
#pragma unroll
    for (int i = 0; i < 3; i++) { acc[i][0] = 0.f; acc[i][1] = 0.f; }
#pragma unroll 4
    for (int n = 0; n < NN / NCH; n++) {
        float4 p = lx[n];
#pragma unroll
        for (int i = 0; i < 3; i++)
#pragma unroll
            for (int h = 0; h < 2; h++)
                acc[i][h] += __builtin_amdgcn_exp2f(
                    fmaf(cxs[i][h], p.x, fmaf(cys[i][h], p.y, fmaf(czs[i][h], p.z, p.w + bas[i][h]))));
    }
#pragma unroll
    for (int i = 0; i < 3; i++) {
        float* o = pbuf + ((size_t)(zc * 3 + i) * BB + b) * SS;
        o[tid] = acc[i][0];
        o[tid + 256] = acc[i][1];
    }
}

__global__ __launch_bounds__(256) void k_sh(const float* __restrict__ pbuf,
                                            const float* __restrict__ A_sh,
                                            float* __restrict__ lshp) {
    __shared__ float lf[256];
    int b = blockIdx.x, c = blockIdx.y, h = blockIdx.z, tid = threadIdx.x;
    float v = 0.f;
#pragma unroll
    for (int zc = 0; zc < NCH; zc++)
        v += pbuf[((size_t)(zc * 3 + c) * BB + b) * SS + h * 256 + tid];
    lf[tid] = v * (1.0f / NN);
    __syncthreads();
    int w = tid >> 6, lane = tid & 63;
    for (int j = w; j < 36; j += 4) {
        const float* As = A_sh + j * SS + h * 256;
        float a = 0.f;
#pragma unroll
        for (int k = 0; k < 4; k++) a = fmaf(lf[lane + 64 * k], As[lane + 64 * k], a);
#pragma unroll
        for (int o = 32; o > 0; o >>= 1) a += __shfl_xor(a, o, 64);
        if (lane == 0) lshp[((b * 36 + j) * 3 + c) * 2 + h] = a;
    }
}

__global__ __launch_bounds__(256) void k_eval0(const float* __restrict__ lshp,
                                               const float* __restrict__ W0,
                                               const float* __restrict__ b0,
                                               const float* __restrict__ Dg0t,
                                               const float* __restrict__ rs0,
                                               float* __restrict__ yq, float* __restrict__ stats) {
    __shared__ float lsh[36][3];
    __shared__ float llm[576];
    __shared__ float lred[4][32];
    int qc = blockIdx.x, b = blockIdx.y, tid = threadIdx.x;
    if (tid < 108) {
        int j = tid / 3, c = tid % 3;
        lsh[j][c] = lshp[((b * 36 + j) * 3 + c) * 2 + 0] + lshp[((b * 36 + j) * 3 + c) * 2 + 1];
    }
    __syncthreads();
    for (int i = tid; i < 576; i += 256) {
        int j = i >> 4, u = i & 15;
        float m = 0.f;
#pragma unroll
        for (int c = 0; c < 3; c++) m = fmaf(lsh[j][c], W0[c * 16 + u], m);
        llm[i] = m;
    }
    __syncthreads();
    int q = qc * 256 + tid;
    float acc[16];
#pragma unroll
    for (int u = 0; u < 16; u++) acc[u] = 0.f;
#pragma unroll 4
    for (int j = 0; j < 36; j++) {
        float d = Dg0t[j * QQ + q];
#pragma unroll
        for (int u = 0; u < 16; u++) acc[u] = fmaf(d, llm[j * 16 + u], acc[u]);
    }
    float rb = rs0[q];
#pragma unroll
    for (int u = 0; u < 16; u++) acc[u] = fmaf(b0[u], rb, acc[u]);
#pragma unroll
    for (int u = 0; u < 16; u++) yq[((size_t)b * 16 + u) * QQ + q] = acc[u];
    int lane = tid & 63, w = tid >> 6;
#pragma unroll
    for (int u = 0; u < 16; u++) {
        float v = acc[u], v2 = acc[u] * acc[u];
#pragma unroll
        for (int o = 32; o > 0; o >>= 1) {
            v += __shfl_xor(v, o, 64);
            v2 += __shfl_xor(v2, o, 64);
        }
        if (lane == 0) { lred[w][u] = v; lred[w][16 + u] = v2; }
    }
    __syncthreads();
    if (tid < 32) atomicAdd(&stats[tid], lred[0][tid] + lred[1][tid] + lred[2][tid] + lred[3][tid]);
}

template <int TT, int UU, int QKN>
__global__ __launch_bounds__(256) void k_coefG(const float* __restrict__ yq,
                                               const float* __restrict__ Dc,
                                               const float* __restrict__ stats,
                                               const float* __restrict__ g,
                                               const float* __restrict__ be,
                                               float* __restrict__ part) {
    constexpr int KC = QQ / QKN;
    __shared__ float lA[32][68];
    __shared__ float lB[32][68];
    __shared__ float lsu[UU], ltu[UU];
    int mt = blockIdx.x, nt = blockIdx.y, qk = blockIdx.z, tid = threadIdx.x;
    int m0 = mt * 64, n0 = nt * 64, k0 = qk * KC;
    if (tid < UU) {
        const float inv = 1.0f / (BB * QQ);
        float mm = stats[tid] * inv;
        float var = stats[UU + tid] * inv - mm * mm;
        float s = g[tid] * rsqrtf(fmaxf(var, 0.f) + 1e-3f);
        lsu[tid] = s;
        ltu[tid] = be[tid] - mm * s;
    }
    __syncthreads();
    int r = tid >> 2, f = (tid & 3) * 4;
    bool mok = (m0 + r) < TT;
    const float* arow = Dc + (size_t)(mok ? (m0 + r) : 0) * QQ;
    const float* brow = yq + (size_t)(n0 + r) * QQ;
    float su = lsu[(n0 + r) % UU], tu = ltu[(n0 + r) % UU];
    int tg = tid >> 4, ug = tid & 15;
    float acc[4][4];
#pragma unroll
    for (int i = 0; i < 4; i++)
#pragma unroll
        for (int j = 0; j < 4; j++) acc[i][j] = 0.f;
    for (int kb = 0; kb < KC; kb += 32) {
        int kg = k0 + kb;
#pragma unroll
        for (int p = 0; p < 2; p++) {
            int ko = f + p * 16;
            float4 a4 = make_float4(0.f, 0.f, 0.f, 0.f);
            if (mok) a4 = *(const float4*)(arow + kg + ko);
            float4 b4 = *(const float4*)(brow + kg + ko);
#pragma unroll
            for (int i = 0; i < 4; i++) {
                float v = fmaf((&b4.x)[i], su, tu);
                lA[ko + i][r] = (&a4.x)[i];
                lB[ko + i][r] = (v > 0.f) ? v : 0.3f * v;
            }
        }
        __syncthreads();
#pragma unroll 2
        for (int kk = 0; kk < 32; kk++) {
            float4 a4 = *(const float4*)&lA[kk][tg * 4];
            float4 b4 = *(const float4*)&lB[kk][ug * 4];
#pragma unroll
            for (int i = 0; i < 4; i++) {
                float av = (&a4.x)[i];
                acc[i][0] = fmaf(av, b4.x, acc[i][0]);
                acc[i][1] = fmaf(av, b4.y, acc[i][1]);
                acc[i][2] = fmaf(av, b4.z, acc[i][2]);
                acc[i][3] = fmaf(av, b4.w, acc[i][3]);
            }
        }
        __syncthreads();
    }
    int n = n0 + ug * 4;
    int b = n / UU, u0 = n % UU;
#pragma unroll
    for (int i = 0; i < 4; i++) {
        int t = m0 + tg * 4 + i;
        if (t < TT)
            *(float4*)&part[(((size_t)qk * BB + b) * TT + t) * UU + u0] =
                make_float4(acc[i][0], acc[i][1], acc[i][2], acc[i][3]);
    }
}

template <int TT, int CC, int UU, int QKN, int TTp, int TS>
__global__ __launch_bounds__(256) void k_redmix(const float* __restrict__ part,
                                                const float* __restrict__ W,
                                                const float* __restrict__ bias,
                                                float* __restrict__ ym) {
    constexpr int TSL = TTp / TS;
    __shared__ float lyt[TSL][CC + 1];
    int b = blockIdx.x, ts = blockIdx.y, tid = threadIdx.x;
    int t0 = ts * TSL;
    for (int i = tid; i < TSL * CC; i += 256) {
        int tl = i / CC, c = i % CC;
        int t = t0 + tl;
        float v = 0.f;
        if (t < TT) {
#pragma unroll
            for (int k = 0; k < QKN; k++)
                v += part[(size_t)k * (BB * TT * CC) + ((size_t)b * TT + t) * CC + c];
        }
        lyt[tl][c] = v;
    }
    __syncthreads();
    for (int i = tid; i < UU * TSL; i += 256) {
        int u = i / TSL, tl = i % TSL;
        int t = t0 + tl;
        float m = 0.f;
        if (t < TT) {
            m = bias[u];
#pragma unroll
            for (int c = 0; c < CC; c++) m = fmaf(lyt[tl][c], W[c * UU + u], m);
        }
        ym[((size_t)b * UU + u) * TTp + t] = m;
    }
}

template <int TT, int TTp, int UU>
__global__ __launch_bounds__(256) void k_evalG(const float* __restrict__ ym,
                                               const float* __restrict__ Det,
                                               float* __restrict__ yq,
                                               float* __restrict__ stats) {
    __shared__ float lA[32][68];
    __shared__ float lB[32][68];
    __shared__ float sred[2][64];
    int mt = blockIdx.x, qt = blockIdx.y, tid = threadIdx.x;
    int m0 = mt * 64, q0 = qt * 64;
    int r = tid >> 2, f = (tid & 3) * 4;
    const float* arow = ym + (size_t)(m0 + r) * TTp;
    int br = tid >> 4, bq = (tid & 15) * 4;
    int tg = tid >> 4, ug = tid & 15;
    float acc[4][4];
#pragma unroll
    for (int i = 0; i < 4; i++)
#pragma unroll
        for (int j = 0; j < 4; j++) acc[i][j] = 0.f;
    for (int kb = 0; kb < TT; kb += 32) {
#pragma unroll
        for (int p = 0; p < 2; p++) {
            int ko = f + p * 16;
            float4 a4 = *(const float4*)(arow + kb + ko);
#pragma unroll
            for (int i = 0; i < 4; i++) lA[ko + i][r] = (&a4.x)[i];
            int kk = br + p * 16;
            int t = kb + kk;
            float4 b4 = make_float4(0.f, 0.f, 0.f, 0.f);
            if (t < TT) b4 = *(const float4*)(Det + (size_t)t * QQ + q0 + bq);
            *(float4*)&lB[kk][bq] = b4;
        }
        __syncthreads();
#pragma unroll 2
        for (int kk = 0; kk < 32; kk++) {
            float4 a4 = *(const float4*)&lA[kk][tg * 4];
            float4 b4 = *(const float4*)&lB[kk][ug * 4];
#pragma unroll
            for (int i = 0; i < 4; i++) {
                float av = (&a4.x)[i];
                acc[i][0] = fmaf(av, b4.x, acc[i][0]);
                acc[i][1] = fmaf(av, b4.y, acc[i][1]);
                acc[i][2] = fmaf(av, b4.z, acc[i][2]);
                acc[i][3] = fmaf(av, b4.w, acc[i][3]);
            }
        }
        __syncthreads();
    }
    float s1[4], s2[4];
#pragma unroll
    for (int i = 0; i < 4; i++) {
        int m = m0 + tg * 4 + i;
        *(float4*)&yq[(size_t)m * QQ + q0 + ug * 4] =
            make_float4(acc[i][0], acc[i][1], acc[i][2], acc[i][3]);
        s1[i] = (acc[i][0] + acc[i][1]) + (acc[i][2] + acc[i][3]);
        s2[i] = fmaf(acc[i][0], acc[i][0], fmaf(acc[i][1], acc[i][1],
                 fmaf(acc[i][2], acc[i][2], acc[i][3] * acc[i][3])));
    }
#pragma unroll
    for (int o = 1; o < 16; o <<= 1) {
#pragma unroll
        for (int i = 0; i < 4; i++) {
            s1[i] += __shfl_xor(s1[i], o, 64);
            s2[i] += __shfl_xor(s2[i], o, 64);
        }
    }
    if (ug == 0) {
#pragma unroll
        for (int i = 0; i < 4; i++) {
            sred[0][tg * 4 + i] = s1[i];
            sred[1][tg * 4 + i] = s2[i];
        }
    }
    __syncthreads();
    if (tid < 2 * UU) {
        int which = tid / UU, u = tid % UU;
        float s = 0.f;
        for (int rr = u; rr < 64; rr += UU) s += sred[which][rr];
        atomicAdd(&stats[which * UU + u], s);
    }
}

__global__ __launch_bounds__(256) void k_norms(const float* __restrict__ part, float* __restrict__ ht0) {
    __shared__ float red[4][64];
    int b = blockIdx.x, blk = blockIdx.y;
    int tq = threadIdx.x >> 6, u = threadIdx.x & 63;
    const int offs[4] = {0, 1, 10, 35};
    const int ends[4] = {1, 10, 35, 84};
    float a = 0.f;
    for (int t = offs[blk] + tq; t < ends[blk]; t += 4) {
        float v = 0.f;
#pragma unroll
        for (int k = 0; k < QKN3; k++)
            v += part[(size_t)k * (BB * 84 * 64) + (b * 84 + t) * 64 + u];
        a = fmaf(v, v, a);
    }
    red[tq][u] = a;
    __syncthreads();
    if (tq == 0) {
        float s = red[0][u] + red[1][u] + red[2][u] + red[3][u];
        ht0[(blk * 64 + u) * BB + b] = sqrtf(fmaxf(s, 0.f));
    }
}

template <int K, int J>
__global__ __launch_bounds__(512) void k_fc(const float* __restrict__ in, const float* __restrict__ W,
                                            const float* __restrict__ bias, const float* __restrict__ g,
                                            const float* __restrict__ be, float* __restrict__ out) {
    __shared__ float red[8][64];
    int j = blockIdx.x;
    int b = threadIdx.x & 63, kq = threadIdx.x >> 6;
    constexpr int KS = K / 8;
    int kbeg = kq * KS;
    float a0 = 0.f, a1 = 0.f, a2 = 0.f, a3 = 0.f;
#pragma unroll 4
    for (int k = kbeg; k < kbeg + KS; k += 4) {
        a0 = fmaf(in[k * BB + b], W[(size_t)k * J + j], a0);
        a1 = fmaf(in[(k + 1) * BB + b], W[(size_t)(k + 1) * J + j], a1);
        a2 = fmaf(in[(k + 2) * BB + b], W[(size_t)(k + 2) * J + j], a2);
        a3 = fmaf(in[(k + 3) * BB + b], W[(size_t)(k + 3) * J + j], a3);
    }
    red[kq][b] = (a0 + a1) + (a2 + a3);
    __syncthreads();
    if (kq == 0) {
        float acc = bias[j];
#pragma unroll
        for (int i = 0; i < 8; i++) acc += red[i][b];
        float s1 = acc, s2 = acc * acc;
#pragma unroll
        for (int o = 32; o > 0; o >>= 1) {
            s1 += __shfl_xor(s1, o, 64);
            s2 += __shfl_xor(s2, o, 64);
        }
        float m = s1 * (1.0f / 64.f);
        float var = s2 * (1.0f / 64.f) - m * m;
        float sc = g[j] * rsqrtf(fmaxf(var, 0.f) + 1e-3f);
        float v = (acc - m) * sc + be[j];
        out[j * BB + b] = fmaxf(v, 0.f);
    }
}

__global__ __launch_bounds__(256) void k_out(const float* __restrict__ ht2, const float* __restrict__ Wout,
                                             const float* __restrict__ bout, float* __restrict__ outp) {
    __shared__ float red[4][64];
    __shared__ float sm[64];
    int b = blockIdx.x;
    int o = threadIdx.x & 63, kq = threadIdx.x >> 6;
    float a0 = 0.f, a1 = 0.f, a2 = 0.f, a3 = 0.f;
    int kbeg = kq * 64;
    if (o < 40) {
#pragma unroll 4
        for (int k = kbeg; k < kbeg + 64; k += 4) {
            a0 = fmaf(ht2[k * BB + b], Wout[k * 40 + o], a0);
            a1 = fmaf(ht2[(k + 1) * BB + b], Wout[(k + 1) * 40 + o], a1);
            a2 = fmaf(ht2[(k + 2) * BB + b], Wout[(k + 2) * 40 + o], a2);
            a3 = fmaf(ht2[(k + 3) * BB + b], Wout[(k + 3) * 40 + o], a3);
        }
    }
    red[kq][o] = (a0 + a1) + (a2 + a3);
    __syncthreads();
    if (kq == 0) {
        float acc = red[0][o] + red[1][o] + red[2][o] + red[3][o] + ((o < 40) ? bout[o] : 0.f);
        sm[o] = (o < 40) ? acc : -3.0e38f;
        __syncthreads();
        for (int s = 32; s > 0; s >>= 1) {
            if (o < s) sm[o] = fmaxf(sm[o], sm[o + s]);
            __syncthreads();
        }
        float m = sm[0];
        __syncthreads();
        const float L2E = 1.4426950408889634f;
        float e = (o < 40) ? exp2f((acc - m) * L2E) : 0.f;
        sm[o] = e;
        __syncthreads();
        for (int s = 32; s > 0; s >>= 1) {
            if (o < s) sm[o] += sm[o + s];
            __syncthreads();
        }
        if (o < 40) outp[b * 40 + o] = e / sm[0];
    }
}

// ---------------- workspace layout (float offsets, unchanged) ----------------
#define OFF_PBUF 0
#define OFF_DG0T 1572864
#define OFF_RS0 1609728
#define OFF_DET1 1610752
#define OFF_DET2 1779712
#define OFF_YQ 1865728
#define OFF_YM 6060032
#define OFF_LSH 6453248
#define OFF_HT0 6467072
#define OFF_HT1 6483456
#define OFF_HT2 6516224
#define OFF_STATS 6532608
#define OFF_PART 6532864
#define OFF_PART3 7909120

extern "C" void kernel_launch(void* const* d_in, const int* in_sizes, int n_in,
                              void* d_out, int out_size, void* d_ws, size_t ws_size,
                              hipStream_t stream) {
    float* ws = (float*)d_ws;
    MArgs a;
    a.x = (const float*)d_in[0];
    a.dirs = (const float*)d_in[1];
    a.A_sh = (const float*)d_in[2];
    a.De0 = (const float*)d_in[3];
    a.De1 = (const float*)d_in[4];
    a.De2 = (const float*)d_in[5];
    a.Dc1 = (const float*)d_in[6];
    a.Dc2 = (const float*)d_in[7];
    a.Dc3 = (const float*)d_in[8];
    a.W0 = (const float*)d_in[9];
    a.b0 = (const float*)d_in[10];
    a.W1 = (const float*)d_in[11];
    a.b1 = (const float*)d_in[12];
    a.W2 = (const float*)d_in[13];
    a.b2 = (const float*)d_in[14];
    a.g0 = (const float*)d_in[15];
    a.be0 = (const float*)d_in[16];
    a.g1 = (const float*)d_in[17];
    a.be1 = (const float*)d_in[18];
    a.g2 = (const float*)d_in[19];
    a.be2 = (const float*)d_in[20];
    a.Wfc1 = (const float*)d_in[21];
    a.bfc1 = (const float*)d_in[22];
    a.gfc1 = (const float*)d_in[23];
    a.befc1 = (const float*)d_in[24];
    a.Wfc2 = (const float*)d_in[25];
    a.bfc2 = (const float*)d_in[26];
    a.gfc2 = (const float*)d_in[27];
    a.befc2 = (const float*)d_in[28];
    a.Wout = (const float*)d_in[29];
    a.bout = (const float*)d_in[30];
    a.pbuf = ws + OFF_PBUF;
    a.Dg0t = ws + OFF_DG0T;
    a.rs0 = ws + OFF_RS0;
    a.Det1 = ws + OFF_DET1;
    a.Det2 = ws + OFF_DET2;
    a.yq = ws + OFF_YQ;
    a.ym = ws + OFF_YM;
    a.lshp = ws + OFF_LSH;
    a.ht0 = ws + OFF_HT0;
    a.ht1 = ws + OFF_HT1;
    a.ht2 = ws + OFF_HT2;
    a.stats = ws + OFF_STATS;
    a.part = ws + OFF_PART;
    a.part3 = ws + OFF_PART3;
    a.out = (float*)d_out;

    // ---- one-time cooperative viability gate (host queries only; no stream ops) ----
    static int mode = -1;
    static int gsize = 0;
    if (mode < 0) {
        int dev = 0;
        (void)hipGetDevice(&dev);
        int coop = 0;
        (void)hipDeviceGetAttribute(&coop, hipDeviceAttributeCooperativeLaunch, dev);
        int ncu = 0;
        (void)hipDeviceGetAttribute(&ncu, hipDeviceAttributeMultiprocessorCount, dev);
        int occ = 0;
        hipError_t e = hipOccupancyMaxActiveBlocksPerMultiprocessor(&occ, (const void*)k_mega, 256, 0);
        long long mg = (long long)occ * (long long)ncu;
        if (coop && e == hipSuccess && mg >= 256) {
            int gs = (int)(mg > 1024 ? 1024 : mg);
            gsize = gs & ~31;  // multiple of 32 for the tree barrier
            mode = (gsize >= 256) ? 1 : 0;
        } else {
            mode = 0;
        }
    }

    if (mode == 1) {
        void* kargs[] = {(void*)&a};
        hipError_t le =
            hipLaunchCooperativeKernel((const void*)k_mega, dim3(gsize), dim3(256), kargs, 0, stream);
        if (le == hipSuccess) return;
        mode = 0;  // permanent fallback if the runtime rejects cooperative launch
    }

    // ---- fallback: proven 14-kernel pipeline ----
    float* stats0 = a.stats;
    float* stats1 = a.stats + 32;
    float* stats2 = a.stats + 96;
    k_preshell<<<PREPB + BB * NCH, 256, 0, stream>>>(
        a.De0, a.De1, a.De2, a.Dg0t, a.rs0, a.Det1, a.Det2, a.stats, a.x, a.dirs, a.pbuf);
    k_sh<<<dim3(BB, 3, 2), 256, 0, stream>>>(a.pbuf, a.A_sh, a.lshp);
    k_eval0<<<dim3(4, BB), 256, 0, stream>>>(a.lshp, a.W0, a.b0, a.Dg0t, a.rs0, a.yq, stats0);
    k_coefG<165, 16, 8><<<dim3(3, 16, 8), 256, 0, stream>>>(a.yq, a.Dc1, stats0, a.g0, a.be0, a.part);
    k_redmix<165, 16, 32, 8, 192, 8><<<dim3(BB, 8), 256, 0, stream>>>(a.part, a.W1, a.b1, a.ym);
    k_evalG<165, 192, 32><<<dim3(32, 16), 256, 0, stream>>>(a.ym, a.Det1, a.yq, stats1);
    k_coefG<84, 32, 8><<<dim3(2, 32, 8), 256, 0, stream>>>(a.yq, a.Dc2, stats1, a.g1, a.be1, a.part);
    k_redmix<84, 32, 64, 8, 96, 8><<<dim3(BB, 8), 256, 0, stream>>>(a.part, a.W2, a.b2, a.ym);
    k_evalG<84, 96, 64><<<dim3(64, 16), 256, 0, stream>>>(a.ym, a.Det2, a.yq, stats2);
    k_coefG<84, 64, QKN3><<<dim3(2, 64, QKN3), 256, 0, stream>>>(a.yq, a.Dc3, stats2, a.g2, a.be2, a.part3);
    k_norms<<<dim3(BB, 4), 256, 0, stream>>>(a.part3, a.ht0);
    k_fc<256, 512><<<512, 512, 0, stream>>>(a.ht0, a.Wfc1, a.bfc1, a.gfc1, a.befc1, a.ht1);
    k_fc<512, 256><<<256, 512, 0, stream>>>(a.ht1, a.Wfc2, a.bfc2, a.gfc2, a.befc2, a.ht2);
    k_out<<<BB, 256, 0, stream>>>(a.ht2, a.Wout, a.bout, a.out);
}

// Round 4
// 438.697 us; speedup vs baseline: 2.7554x; 1.1380x over previous
//
#include <hip/hip_runtime.h>

#define BB 64
#define NN 2048
#define QQ 1024
#define SS 512
#define NCH 16
#define PREPB 609
#define QKN3 8

__device__ const int PIDX[36] = {
    0, 2, 5, 8, 12, 17, 22, 27, 32, 38, 45, 52, 59, 66, 73, 80,
    88, 97, 106, 115, 124, 133, 142, 151, 160,
    170, 181, 192, 203, 214, 225, 236, 247, 258, 269, 280};

struct MArgs {
    const float *x, *dirs, *A_sh, *De0, *De1, *De2, *Dc1, *Dc2, *Dc3;
    const float *W0, *b0, *W1, *b1, *W2, *b2;
    const float *g0, *be0, *g1, *be1, *g2, *be2;
    const float *Wfc1, *bfc1, *gfc1, *befc1, *Wfc2, *bfc2, *gfc2, *befc2, *Wout, *bout;
    float *pbuf, *Dg0t, *rs0, *Det1, *Det2;
    float *yq0, *yq1, *yq2, *ymA, *ymB, *lshp;
    float *ht0, *ht1, *ht2, *stats, *partA, *partB, *part3, *out;
};

struct SmGemm { float lA[32][68]; float lB[32][68]; float lsu[64]; float ltu[64]; };
struct SmEv   { float lA[32][68]; float lB[32][68]; float sred[2][64]; };
struct SmE0   { float lsh[36][3]; float llm[576]; float lred[4][32]; };

// ================= write-through publication stores =================
// Agent-scope relaxed atomic store -> global_store_dword sc1: the value lands at
// the memory-side coherence point (same path that makes atomicAdd stats correct).
// Combined with (a) no buffer written twice per run, (b) 128B-aligned buffers (no
// line spans two buffers), (c) the dispatch-boundary acquire invalidating all L2s
// once at kernel start, consumers' plain cached loads can never observe staleness:
// a consumer's L2 first touches a line only after its producer's memory-side write.
// => grid barriers need NO cache-maintenance fences at all.
__device__ __forceinline__ void st_wt(float* p, float v) {
    __hip_atomic_store(p, v, __ATOMIC_RELAXED, __HIP_MEMORY_SCOPE_AGENT);
}
__device__ __forceinline__ void st_wt4(float* p, float4 v) {
    st_wt(p + 0, v.x); st_wt(p + 1, v.y); st_wt(p + 2, v.z); st_wt(p + 3, v.w);
}

// ================= tree grid barrier: counters only, NO fences =================
// Round-3's per-block agent fences (buffer_wbl2/buffer_inv = full-L2 scans x 1024
// blocks x 14 barriers) were the ~300us overhead: they also nuked read-only data
// (Dc/Det/De refetched from HBM 14x -> 127MB @ 282GB/s). With write-through
// publication (above) the barrier is pure arrival counting. Probes are relaxed
// RMWs (memory-side, fresh, no buffer_inv). __syncthreads drains vmcnt (compiler
// emits s_waitcnt vmcnt(0) before s_barrier), so sc1 stores are at the coherence
// point before any block arrives. State lines padded 256B; counters return to 0
// each use; gens grow monotonically across graph replays. Grid multiple of 32.
__device__ unsigned g_grp_cnt[32 * 64];
__device__ unsigned g_grp_gen[32 * 64];
__device__ unsigned g_root_cnt[64];
__device__ unsigned g_root_gen[64];

__device__ __forceinline__ unsigned bar_probe(unsigned* p) {
    return __hip_atomic_fetch_add(p, 0u, __ATOMIC_RELAXED, __HIP_MEMORY_SCOPE_AGENT);
}

__device__ __forceinline__ void gbar() {
    __syncthreads();
    if (threadIdx.x == 0) {
        const int G = (int)gridDim.x;
        const int gsz = G >> 5;  // 32 groups; G is a multiple of 32
        const int grp = (int)blockIdx.x / gsz;
        unsigned* gcnt = &g_grp_cnt[grp << 6];
        unsigned* ggen = &g_grp_gen[grp << 6];
        if ((int)blockIdx.x % gsz == 0) {
            unsigned rg = bar_probe(&g_root_gen[0]);
            while (bar_probe(gcnt) < (unsigned)(gsz - 1)) __builtin_amdgcn_s_sleep(4);
            __hip_atomic_exchange(gcnt, 0u, __ATOMIC_RELAXED, __HIP_MEMORY_SCOPE_AGENT);
            unsigned arrived = __hip_atomic_fetch_add(&g_root_cnt[0], 1u, __ATOMIC_RELAXED,
                                                      __HIP_MEMORY_SCOPE_AGENT) + 1u;
            if (arrived == 32u) {
                __hip_atomic_exchange(&g_root_cnt[0], 0u, __ATOMIC_RELAXED, __HIP_MEMORY_SCOPE_AGENT);
                __hip_atomic_fetch_add(&g_root_gen[0], 1u, __ATOMIC_RELAXED, __HIP_MEMORY_SCOPE_AGENT);
            } else {
                while (bar_probe(&g_root_gen[0]) == rg) __builtin_amdgcn_s_sleep(4);
            }
            __hip_atomic_fetch_add(ggen, 1u, __ATOMIC_RELAXED, __HIP_MEMORY_SCOPE_AGENT);
        } else {
            unsigned gg = bar_probe(ggen);
            __hip_atomic_fetch_add(gcnt, 1u, __ATOMIC_RELAXED, __HIP_MEMORY_SCOPE_AGENT);
            while (bar_probe(ggen) == gg) __builtin_amdgcn_s_sleep(4);
        }
    }
    __syncthreads();
}

// ================= megakernel phase bodies =================
// Each phase leads with __syncthreads() to protect LDS reuse across grid-stride
// iterations. All phase-output stores are write-through (st_wt / st_wt4).

__device__ void ph_shell(const MArgs& a, int wb, char* smraw, int tid) {
    __syncthreads();
    float4* lx = reinterpret_cast<float4*>(smraw);
    int b = wb & 63, zc = wb >> 6;
    const float KL = 18.033688011112042f;  // log2(e)/SIGMA2, SIGMA2=0.08
    const float* xb = a.x + ((size_t)b * NN + zc * (NN / NCH)) * 3;
    for (int n = tid; n < NN / NCH; n += 256) {
        float X = xb[n * 3 + 0];
        float Y = xb[n * 3 + 1];
        float Z = xb[n * 3 + 2];
        lx[n] = make_float4(X, Y, Z, -KL * (X * X + Y * Y + Z * Z));
    }
    __syncthreads();
    float cxs[3][2], cys[3][2], czs[3][2], bas[3][2];
#pragma unroll
    for (int i = 0; i < 3; i++) {
        float r = (i == 0) ? 0.4f : ((i == 1) ? 0.8f : 1.2f);
#pragma unroll
        for (int h = 0; h < 2; h++) {
            int s = tid + h * 256;
            float cx = r * a.dirs[(i * SS + s) * 3 + 0];
            float cy = r * a.dirs[(i * SS + s) * 3 + 1];
            float cz = r * a.dirs[(i * SS + s) * 3 + 2];
            bas[i][h] = -KL * (cx * cx + cy * cy + cz * cz);
            cxs[i][h] = 2.f * KL * cx;
            cys[i][h] = 2.f * KL * cy;
            czs[i][h] = 2.f * KL * cz;
        }
    }
    float acc[3][2];
#pragma unroll
    for (int i = 0; i < 3; i++) { acc[i][0] = 0.f; acc[i][1] = 0.f; }
#pragma unroll 4
    for (int n = 0; n < NN / NCH; n++) {
        float4 p = lx[n];
#pragma unroll
        for (int i = 0; i < 3; i++)
#pragma unroll
            for (int h = 0; h < 2; h++)
                acc[i][h] += __builtin_amdgcn_exp2f(
                    fmaf(cxs[i][h], p.x, fmaf(cys[i][h], p.y, fmaf(czs[i][h], p.z, p.w))));
    }
#pragma unroll
    for (int i = 0; i < 3; i++) {
        float* o = a.pbuf + ((size_t)(zc * 3 + i) * BB + b) * SS;
        st_wt(o + tid, acc[i][0] * __builtin_amdgcn_exp2f(bas[i][0]));
        st_wt(o + tid + 256, acc[i][1] * __builtin_amdgcn_exp2f(bas[i][1]));
    }
}

__device__ void ph_sh(const MArgs& a, int wb, char* smraw, int tid) {
    __syncthreads();
    float* lf = reinterpret_cast<float*>(smraw);
    int b = wb & 63;
    int t = wb >> 6;  // 0..5
    int c = t % 3, h = t / 3;
    float v = 0.f;
#pragma unroll
    for (int zc = 0; zc < NCH; zc++)
        v += a.pbuf[((size_t)(zc * 3 + c) * BB + b) * SS + h * 256 + tid];
    lf[tid] = v * (1.0f / NN);
    __syncthreads();
    int w = tid >> 6, lane = tid & 63;
    for (int j = w; j < 36; j += 4) {
        const float* As = a.A_sh + j * SS + h * 256;
        float acc = 0.f;
#pragma unroll
        for (int k = 0; k < 4; k++) acc = fmaf(lf[lane + 64 * k], As[lane + 64 * k], acc);
#pragma unroll
        for (int o = 32; o > 0; o >>= 1) acc += __shfl_xor(acc, o, 64);
        if (lane == 0) st_wt(&a.lshp[((b * 36 + j) * 3 + c) * 2 + h], acc);
    }
}

__device__ void ph_prep(const MArgs& a, int wb, char* smraw, int tid) {
    __syncthreads();
    float (*tile)[33] = reinterpret_cast<float (*)[33]>(smraw);
    int r = tid >> 5, c = tid & 31;
    if (wb < 576) {  // De1 -> Det1 [165][1024]
        int i = wb - 384;
        int tq = i & 31, tt = i >> 5;
        int q0 = tq * 32, t0 = tt * 32;
        for (int rr = r; rr < 32; rr += 8) {
            int t = t0 + c;
            tile[rr][c] = (t < 165) ? a.De1[(q0 + rr) * 165 + t] : 0.f;
        }
        __syncthreads();
        for (int rr = r; rr < 32; rr += 8) {
            int t = t0 + rr;
            if (t < 165) st_wt(&a.Det1[t * QQ + q0 + c], tile[c][rr]);
        }
    } else if (wb < 672) {  // De2 -> Det2 [84][1024]
        int i = wb - 576;
        int tq = i & 31, tt = i >> 5;
        int q0 = tq * 32, t0 = tt * 32;
        for (int rr = r; rr < 32; rr += 8) {
            int t = t0 + c;
            tile[rr][c] = (t < 84) ? a.De2[(q0 + rr) * 84 + t] : 0.f;
        }
        __syncthreads();
        for (int rr = r; rr < 32; rr += 8) {
            int t = t0 + rr;
            if (t < 84) st_wt(&a.Det2[t * QQ + q0 + c], tile[c][rr]);
        }
    } else if (wb < 736) {  // gather De0[:, PIDX] -> Dg0t [36][1024]
        int i = wb - 672;
        int tq = i & 31, tj = i >> 5;
        int q0 = tq * 32, j0 = tj * 32;
        for (int rr = r; rr < 32; rr += 8) {
            int j = j0 + c;
            tile[rr][c] = (j < 36) ? a.De0[(q0 + rr) * 286 + PIDX[j]] : 0.f;
        }
        __syncthreads();
        for (int rr = r; rr < 32; rr += 8) {
            int j = j0 + rr;
            if (j < 36) st_wt(&a.Dg0t[j * QQ + q0 + c], tile[c][rr]);
        }
    } else {  // rowsum of De0: one q per wave
        int w = tid >> 6, lane = tid & 63;
        int q = (wb - 736) * 4 + w;
        float s = 0.f;
#pragma unroll
        for (int p = 0; p < 5; p++) {
            int idx = lane + p * 64;
            if (idx < 286) s += a.De0[q * 286 + idx];
        }
#pragma unroll
        for (int o = 32; o > 0; o >>= 1) s += __shfl_xor(s, o, 64);
        if (lane == 0) st_wt(&a.rs0[q], s);
    }
}

__device__ void ph_eval0(const MArgs& a, int wb, char* smraw, int tid) {
    __syncthreads();
    SmE0& s = *reinterpret_cast<SmE0*>(smraw);
    int qc = wb & 3, b = wb >> 2;
    if (tid < 108) {
        int j = tid / 3, c = tid % 3;
        s.lsh[j][c] = a.lshp[((b * 36 + j) * 3 + c) * 2 + 0] +
                      a.lshp[((b * 36 + j) * 3 + c) * 2 + 1];
    }
    __syncthreads();
    for (int i = tid; i < 576; i += 256) {
        int j = i >> 4, u = i & 15;
        float m = 0.f;
#pragma unroll
        for (int c = 0; c < 3; c++) m = fmaf(s.lsh[j][c], a.W0[c * 16 + u], m);
        s.llm[i] = m;
    }
    __syncthreads();
    int q = qc * 256 + tid;
    float acc[16];
#pragma unroll
    for (int u = 0; u < 16; u++) acc[u] = 0.f;
#pragma unroll 4
    for (int j = 0; j < 36; j++) {
        float d = a.Dg0t[j * QQ + q];
#pragma unroll
        for (int u = 0; u < 16; u++) acc[u] = fmaf(d, s.llm[j * 16 + u], acc[u]);
    }
    float rb = a.rs0[q];
#pragma unroll
    for (int u = 0; u < 16; u++) acc[u] = fmaf(a.b0[u], rb, acc[u]);
#pragma unroll
    for (int u = 0; u < 16; u++) st_wt(&a.yq0[((size_t)b * 16 + u) * QQ + q], acc[u]);
    int lane = tid & 63, w = tid >> 6;
#pragma unroll
    for (int u = 0; u < 16; u++) {
        float v = acc[u], v2 = acc[u] * acc[u];
#pragma unroll
        for (int o = 32; o > 0; o >>= 1) {
            v += __shfl_xor(v, o, 64);
            v2 += __shfl_xor(v2, o, 64);
        }
        if (lane == 0) { s.lred[w][u] = v; s.lred[w][16 + u] = v2; }
    }
    __syncthreads();
    if (tid < 32)
        atomicAdd(&a.stats[tid], s.lred[0][tid] + s.lred[1][tid] + s.lred[2][tid] + s.lred[3][tid]);
}

template <int TT, int UU, int QKN>
__device__ void ph_coefG(const float* __restrict__ yq, const float* __restrict__ Dc,
                         const float* __restrict__ stats, const float* __restrict__ g,
                         const float* __restrict__ be, float* __restrict__ part,
                         int mt, int nt, int qk, char* smraw, int tid) {
    __syncthreads();
    constexpr int KC = QQ / QKN;
    SmGemm& s = *reinterpret_cast<SmGemm*>(smraw);
    int m0 = mt * 64, n0 = nt * 64, k0 = qk * KC;
    if (tid < UU) {
        const float inv = 1.0f / (BB * QQ);
        float mm = stats[tid] * inv;
        float var = stats[UU + tid] * inv - mm * mm;
        float sc = g[tid] * rsqrtf(fmaxf(var, 0.f) + 1e-3f);
        s.lsu[tid] = sc;
        s.ltu[tid] = be[tid] - mm * sc;
    }
    __syncthreads();
    int r = tid >> 2, f = (tid & 3) * 4;
    bool mok = (m0 + r) < TT;
    const float* arow = Dc + (size_t)(mok ? (m0 + r) : 0) * QQ;
    const float* brow = yq + (size_t)(n0 + r) * QQ;
    float su = s.lsu[(n0 + r) % UU], tu = s.ltu[(n0 + r) % UU];
    int tg = tid >> 4, ug = tid & 15;
    float acc[4][4];
#pragma unroll
    for (int i = 0; i < 4; i++)
#pragma unroll
        for (int j = 0; j < 4; j++) acc[i][j] = 0.f;
    for (int kb = 0; kb < KC; kb += 32) {
        int kg = k0 + kb;
#pragma unroll
        for (int p = 0; p < 2; p++) {
            int ko = f + p * 16;
            float4 a4 = make_float4(0.f, 0.f, 0.f, 0.f);
            if (mok) a4 = *(const float4*)(arow + kg + ko);
            float4 b4 = *(const float4*)(brow + kg + ko);
#pragma unroll
            for (int i = 0; i < 4; i++) {
                float v = fmaf((&b4.x)[i], su, tu);
                s.lA[ko + i][r] = (&a4.x)[i];
                s.lB[ko + i][r] = (v > 0.f) ? v : 0.3f * v;
            }
        }
        __syncthreads();
#pragma unroll 2
        for (int kk = 0; kk < 32; kk++) {
            float4 a4 = *(const float4*)&s.lA[kk][tg * 4];
            float4 b4 = *(const float4*)&s.lB[kk][ug * 4];
#pragma unroll
            for (int i = 0; i < 4; i++) {
                float av = (&a4.x)[i];
                acc[i][0] = fmaf(av, b4.x, acc[i][0]);
                acc[i][1] = fmaf(av, b4.y, acc[i][1]);
                acc[i][2] = fmaf(av, b4.z, acc[i][2]);
                acc[i][3] = fmaf(av, b4.w, acc[i][3]);
            }
        }
        __syncthreads();
    }
    int n = n0 + ug * 4;
    int b = n / UU, u0 = n % UU;
#pragma unroll
    for (int i = 0; i < 4; i++) {
        int t = m0 + tg * 4 + i;
        if (t < TT)
            st_wt4(&part[(((size_t)qk * BB + b) * TT + t) * UU + u0],
                   make_float4(acc[i][0], acc[i][1], acc[i][2], acc[i][3]));
    }
}

template <int TT, int CC, int UU, int QKN, int TTp, int TS>
__device__ void ph_redmix(const float* __restrict__ part, const float* __restrict__ W,
                          const float* __restrict__ bias, float* __restrict__ ym,
                          int b, int ts, char* smraw, int tid) {
    __syncthreads();
    constexpr int TSL = TTp / TS;
    float* lyt = reinterpret_cast<float*>(smraw);  // [TSL][CC+1]
    int t0 = ts * TSL;
    for (int i = tid; i < TSL * CC; i += 256) {
        int tl = i / CC, c = i % CC;
        int t = t0 + tl;
        float v = 0.f;
        if (t < TT) {
#pragma unroll
            for (int k = 0; k < QKN; k++)
                v += part[(size_t)k * (BB * TT * CC) + ((size_t)b * TT + t) * CC + c];
        }
        lyt[tl * (CC + 1) + c] = v;
    }
    __syncthreads();
    for (int i = tid; i < UU * TSL; i += 256) {
        int u = i / TSL, tl = i % TSL;
        int t = t0 + tl;
        float m = 0.f;
        if (t < TT) {
            m = bias[u];
#pragma unroll
            for (int c = 0; c < CC; c++) m = fmaf(lyt[tl * (CC + 1) + c], W[c * UU + u], m);
        }
        st_wt(&ym[((size_t)b * UU + u) * TTp + t], m);
    }
}

template <int TT, int TTp, int UU>
__device__ void ph_evalG(const float* __restrict__ ym, const float* __restrict__ Det,
                         float* __restrict__ yq, float* __restrict__ stats,
                         int mt, int qt, char* smraw, int tid) {
    __syncthreads();
    SmEv& s = *reinterpret_cast<SmEv*>(smraw);
    int m0 = mt * 64, q0 = qt * 64;
    int r = tid >> 2, f = (tid & 3) * 4;
    const float* arow = ym + (size_t)(m0 + r) * TTp;
    int br = tid >> 4, bq = (tid & 15) * 4;
    int tg = tid >> 4, ug = tid & 15;
    float acc[4][4];
#pragma unroll
    for (int i = 0; i < 4; i++)
#pragma unroll
        for (int j = 0; j < 4; j++) acc[i][j] = 0.f;
    for (int kb = 0; kb < TT; kb += 32) {
#pragma unroll
        for (int p = 0; p < 2; p++) {
            int ko = f + p * 16;
            float4 a4 = *(const float4*)(arow + kb + ko);
#pragma unroll
            for (int i = 0; i < 4; i++) s.lA[ko + i][r] = (&a4.x)[i];
            int kk = br + p * 16;
            int t = kb + kk;
            float4 b4 = make_float4(0.f, 0.f, 0.f, 0.f);
            if (t < TT) b4 = *(const float4*)(Det + (size_t)t * QQ + q0 + bq);
            *(float4*)&s.lB[kk][bq] = b4;
        }
        __syncthreads();
#pragma unroll 2
        for (int kk = 0; kk < 32; kk++) {
            float4 a4 = *(const float4*)&s.lA[kk][tg * 4];
            float4 b4 = *(const float4*)&s.lB[kk][ug * 4];
#pragma unroll
            for (int i = 0; i < 4; i++) {
                float av = (&a4.x)[i];
                acc[i][0] = fmaf(av, b4.x, acc[i][0]);
                acc[i][1] = fmaf(av, b4.y, acc[i][1]);
                acc[i][2] = fmaf(av, b4.z, acc[i][2]);
                acc[i][3] = fmaf(av, b4.w, acc[i][3]);
            }
        }
        __syncthreads();
    }
    float s1[4], s2[4];
#pragma unroll
    for (int i = 0; i < 4; i++) {
        int m = m0 + tg * 4 + i;
        st_wt4(&yq[(size_t)m * QQ + q0 + ug * 4],
               make_float4(acc[i][0], acc[i][1], acc[i][2], acc[i][3]));
        s1[i] = (acc[i][0] + acc[i][1]) + (acc[i][2] + acc[i][3]);
        s2[i] = fmaf(acc[i][0], acc[i][0], fmaf(acc[i][1], acc[i][1],
                 fmaf(acc[i][2], acc[i][2], acc[i][3] * acc[i][3])));
    }
#pragma unroll
    for (int o = 1; o < 16; o <<= 1) {
#pragma unroll
        for (int i = 0; i < 4; i++) {
            s1[i] += __shfl_xor(s1[i], o, 64);
            s2[i] += __shfl_xor(s2[i], o, 64);
        }
    }
    if (ug == 0) {
#pragma unroll
        for (int i = 0; i < 4; i++) {
            s.sred[0][tg * 4 + i] = s1[i];
            s.sred[1][tg * 4 + i] = s2[i];
        }
    }
    __syncthreads();
    if (tid < 2 * UU) {
        int which = tid / UU, u = tid % UU;
        float sv = 0.f;
        for (int rr = u; rr < 64; rr += UU) sv += s.sred[which][rr];
        atomicAdd(&stats[which * UU + u], sv);
    }
}

__device__ void ph_norms(const float* __restrict__ part, float* __restrict__ ht0,
                         int b, int blk, char* smraw, int tid) {
    __syncthreads();
    float (*red)[64] = reinterpret_cast<float (*)[64]>(smraw);
    int tq = tid >> 6, u = tid & 63;
    const int offs[4] = {0, 1, 10, 35};
    const int ends[4] = {1, 10, 35, 84};
    float acc = 0.f;
    for (int t = offs[blk] + tq; t < ends[blk]; t += 4) {
        float v = 0.f;
#pragma unroll
        for (int k = 0; k < QKN3; k++)
            v += part[(size_t)k * (BB * 84 * 64) + (b * 84 + t) * 64 + u];
        acc = fmaf(v, v, acc);
    }
    red[tq][u] = acc;
    __syncthreads();
    if (tq == 0) {
        float sv = red[0][u] + red[1][u] + red[2][u] + red[3][u];
        st_wt(&ht0[(blk * 64 + u) * BB + b], sqrtf(fmaxf(sv, 0.f)));
    }
}

template <int K, int J>
__device__ void ph_fc(const float* __restrict__ in, const float* __restrict__ W,
                      const float* __restrict__ bias, const float* __restrict__ g,
                      const float* __restrict__ be, float* __restrict__ out,
                      int j, char* smraw, int tid) {
    __syncthreads();
    float (*red)[64] = reinterpret_cast<float (*)[64]>(smraw);
    int b = tid & 63, kq = tid >> 6;
    constexpr int KS = K / 4;
    int kbeg = kq * KS;
    float a0 = 0.f, a1 = 0.f, a2 = 0.f, a3 = 0.f;
#pragma unroll 4
    for (int k = kbeg; k < kbeg + KS; k += 4) {
        a0 = fmaf(in[k * BB + b], W[(size_t)k * J + j], a0);
        a1 = fmaf(in[(k + 1) * BB + b], W[(size_t)(k + 1) * J + j], a1);
        a2 = fmaf(in[(k + 2) * BB + b], W[(size_t)(k + 2) * J + j], a2);
        a3 = fmaf(in[(k + 3) * BB + b], W[(size_t)(k + 3) * J + j], a3);
    }
    red[kq][b] = (a0 + a1) + (a2 + a3);
    __syncthreads();
    if (kq == 0) {
        float acc = bias[j] + red[0][b] + red[1][b] + red[2][b] + red[3][b];
        float s1 = acc, s2 = acc * acc;
#pragma unroll
        for (int o = 32; o > 0; o >>= 1) {
            s1 += __shfl_xor(s1, o, 64);
            s2 += __shfl_xor(s2, o, 64);
        }
        float m = s1 * (1.0f / 64.f);
        float var = s2 * (1.0f / 64.f) - m * m;
        float sc = g[j] * rsqrtf(fmaxf(var, 0.f) + 1e-3f);
        float v = (acc - m) * sc + be[j];
        st_wt(&out[j * BB + b], fmaxf(v, 0.f));
    }
}

__device__ void ph_out(const float* __restrict__ ht2, const float* __restrict__ Wout,
                       const float* __restrict__ bout, float* __restrict__ outp,
                       int b, char* smraw, int tid) {
    __syncthreads();
    float (*red)[64] = reinterpret_cast<float (*)[64]>(smraw);
    int o = tid & 63, kq = tid >> 6;
    float a0 = 0.f, a1 = 0.f, a2 = 0.f, a3 = 0.f;
    int kbeg = kq * 64;
    if (o < 40) {
#pragma unroll 4
        for (int k = kbeg; k < kbeg + 64; k += 4) {
            a0 = fmaf(ht2[k * BB + b], Wout[k * 40 + o], a0);
            a1 = fmaf(ht2[(k + 1) * BB + b], Wout[(k + 1) * 40 + o], a1);
            a2 = fmaf(ht2[(k + 2) * BB + b], Wout[(k + 2) * 40 + o], a2);
            a3 = fmaf(ht2[(k + 3) * BB + b], Wout[(k + 3) * 40 + o], a3);
        }
    }
    red[kq][o] = (a0 + a1) + (a2 + a3);
    __syncthreads();
    if (kq == 0) {
        float acc = red[0][o] + red[1][o] + red[2][o] + red[3][o] + ((o < 40) ? bout[o] : 0.f);
        float m = (o < 40) ? acc : -3.0e38f;
#pragma unroll
        for (int s = 32; s > 0; s >>= 1) m = fmaxf(m, __shfl_xor(m, s, 64));
        const float L2E = 1.4426950408889634f;
        float e = (o < 40) ? exp2f((acc - m) * L2E) : 0.f;
        float ssum = e;
#pragma unroll
        for (int s = 32; s > 0; s >>= 1) ssum += __shfl_xor(ssum, s, 64);
        if (o < 40) outp[b * 40 + o] = e / ssum;  // kernel-end release flushes
    }
}

// ================= megakernel: grid-stride phases, works for any grid size =================
__global__ void __launch_bounds__(256, 2) k_mega(MArgs a) {
    __shared__ __align__(16) char smraw[17920];
    const int tid = threadIdx.x;
    const int G = gridDim.x;
    for (int wb = blockIdx.x; wb < 1024; wb += G) ph_shell(a, wb, smraw, tid);
    gbar();
    for (int wb = blockIdx.x; wb < 993; wb += G) {
        if (wb < 384) ph_sh(a, wb, smraw, tid);
        else if (wb < 992) ph_prep(a, wb, smraw, tid);
        else { __syncthreads(); if (tid < 224) st_wt(&a.stats[tid], 0.f); }
    }
    gbar();
    for (int wb = blockIdx.x; wb < 256; wb += G) ph_eval0(a, wb, smraw, tid);
    gbar();
    for (int wb = blockIdx.x; wb < 384; wb += G) {
        int mt = wb % 3, t = wb / 3;
        ph_coefG<165, 16, 8>(a.yq0, a.Dc1, a.stats, a.g0, a.be0, a.partA, mt, t & 15, t >> 4, smraw, tid);
    }
    gbar();
    for (int wb = blockIdx.x; wb < 512; wb += G)
        ph_redmix<165, 16, 32, 8, 192, 8>(a.partA, a.W1, a.b1, a.ymA, wb & 63, wb >> 6, smraw, tid);
    gbar();
    for (int wb = blockIdx.x; wb < 512; wb += G)
        ph_evalG<165, 192, 32>(a.ymA, a.Det1, a.yq1, a.stats + 32, wb & 31, wb >> 5, smraw, tid);
    gbar();
    for (int wb = blockIdx.x; wb < 512; wb += G) {
        int mt = wb & 1, t = wb >> 1;
        ph_coefG<84, 32, 8>(a.yq1, a.Dc2, a.stats + 32, a.g1, a.be1, a.partB, mt, t & 31, t >> 5, smraw, tid);
    }
    gbar();
    for (int wb = blockIdx.x; wb < 512; wb += G)
        ph_redmix<84, 32, 64, 8, 96, 8>(a.partB, a.W2, a.b2, a.ymB, wb & 63, wb >> 6, smraw, tid);
    gbar();
    for (int wb = blockIdx.x; wb < 1024; wb += G)
        ph_evalG<84, 96, 64>(a.ymB, a.Det2, a.yq2, a.stats + 96, wb & 63, wb >> 6, smraw, tid);
    gbar();
    for (int wb = blockIdx.x; wb < 1024; wb += G) {
        int mt = wb & 1, t = wb >> 1;
        ph_coefG<84, 64, QKN3>(a.yq2, a.Dc3, a.stats + 96, a.g2, a.be2, a.part3, mt, t & 63, t >> 6, smraw, tid);
    }
    gbar();
    for (int wb = blockIdx.x; wb < 256; wb += G) ph_norms(a.part3, a.ht0, wb & 63, wb >> 6, smraw, tid);
    gbar();
    for (int wb = blockIdx.x; wb < 512; wb += G)
        ph_fc<256, 512>(a.ht0, a.Wfc1, a.bfc1, a.gfc1, a.befc1, a.ht1, wb, smraw, tid);
    gbar();
    for (int wb = blockIdx.x; wb < 256; wb += G)
        ph_fc<512, 256>(a.ht1, a.Wfc2, a.bfc2, a.gfc2, a.befc2, a.ht2, wb, smraw, tid);
    gbar();
    for (int wb = blockIdx.x; wb < 64; wb += G) ph_out(a.ht2, a.Wout, a.bout, a.out, wb, smraw, tid);
}

// ================= fallback: the proven 14-kernel pipeline (verbatim baseline) =================
__global__ __launch_bounds__(256) void k_preshell(
    const float* __restrict__ De0, const float* __restrict__ De1, const float* __restrict__ De2,
    float* __restrict__ Dg0t, float* __restrict__ rs0,
    float* __restrict__ Det1, float* __restrict__ Det2,
    float* __restrict__ stats,
    const float* __restrict__ x, const float* __restrict__ dirs, float* __restrict__ pbuf) {
    __shared__ float tile[32][33];
    __shared__ float4 lx[NN / NCH];
    int blk = blockIdx.x, tid = threadIdx.x;
    if (blk < PREPB) {
        int r = tid >> 5, c = tid & 31;
        if (blk < 192) {
            int tq = blk & 31, tt = blk >> 5;
            int q0 = tq * 32, t0 = tt * 32;
            for (int rr = r; rr < 32; rr += 8) {
                int t = t0 + c;
                tile[rr][c] = (t < 165) ? De1[(q0 + rr) * 165 + t] : 0.f;
            }
            __syncthreads();
            for (int rr = r; rr < 32; rr += 8) {
                int t = t0 + rr;
                if (t < 165) Det1[t * QQ + q0 + c] = tile[c][rr];
            }
        } else if (blk < 288) {
            int i = blk - 192;
            int tq = i & 31, tt = i >> 5;
            int q0 = tq * 32, t0 = tt * 32;
            for (int rr = r; rr < 32; rr += 8) {
                int t = t0 + c;
                tile[rr][c] = (t < 84) ? De2[(q0 + rr) * 84 + t] : 0.f;
            }
            __syncthreads();
            for (int rr = r; rr < 32; rr += 8) {
                int t = t0 + rr;
                if (t < 84) Det2[t * QQ + q0 + c] = tile[c][rr];
            }
        } else if (blk < 352) {
            int i = blk - 288;
            int tq = i & 31, tj = i >> 5;
            int q0 = tq * 32, j0 = tj * 32;
            for (int rr = r; rr < 32; rr += 8) {
                int j = j0 + c;
                tile[rr][c] = (j < 36) ? De0[(q0 + rr) * 286 + PIDX[j]] : 0.f;
            }
            __syncthreads();
            for (int rr = r; rr < 32; rr += 8) {
                int j = j0 + rr;
                if (j < 36) Dg0t[j * QQ + q0 + c] = tile[c][rr];
            }
        } else if (blk < 608) {
            int w = tid >> 6, lane = tid & 63;
            int q = (blk - 352) * 4 + w;
            float s = 0.f;
#pragma unroll
            for (int p = 0; p < 5; p++) {
                int idx = lane + p * 64;
                if (idx < 286) s += De0[q * 286 + idx];
            }
#pragma unroll
            for (int o = 32; o > 0; o >>= 1) s += __shfl_xor(s, o, 64);
            if (lane == 0) rs0[q] = s;
        } else {
            if (tid < 224) stats[tid] = 0.f;
        }
        return;
    }
    int idx = blk - PREPB;
    int b = idx & 63, zc = idx >> 6;
    const float KL = 18.033688011112042f;
    const float* xb = x + ((size_t)b * NN + zc * (NN / NCH)) * 3;
    for (int n = tid; n < NN / NCH; n += 256) {
        float X = xb[n * 3 + 0];
        float Y = xb[n * 3 + 1];
        float Z = xb[n * 3 + 2];
        lx[n] = make_float4(X, Y, Z, -KL * (X * X + Y * Y + Z * Z));
    }
    __syncthreads();
    float cxs[3][2], cys[3][2], czs[3][2], bas[3][2];
#pragma unroll
    for (int i = 0; i < 3; i++) {
        float r = (i == 0) ? 0.4f : ((i == 1) ? 0.8f : 1.2f);
#pragma unroll
        for (int h = 0; h < 2; h++) {
            int s = tid + h * 256;
            float cx = r * dirs[(i * SS + s) * 3 + 0];
            float cy = r * dirs[(i * SS + s) * 3 + 1];
            float cz = r * dirs[(i * SS + s) * 3 + 2];
            bas[i][h] = -KL * (cx * cx + cy * cy + cz * cz);
            cxs[i][h] = 2.f * KL * cx;
            cys[i][h] = 2.f * KL * cy;
            czs[i][h] = 2.f * KL * cz;
        }
    }
    float acc[3][2];
#pragma unroll
    for (int i = 0; i < 3; i++) { acc[i][0] = 0.f; acc[i][1] = 0.f; }
#pragma unroll 4
    for (int n = 0; n < NN / NCH; n++) {
        float4 p = lx[n];
#pragma unroll
        for (int i = 0; i < 3; i++)
#pragma unroll
            for (int h = 0; h < 2; h++)
                acc[i][h] += __builtin_amdgcn_exp2f(
                    fmaf(cxs[i][h], p.x, fmaf(cys[i][h], p.y, fmaf(czs[i][h], p.z, p.w + bas[i][h]))));
    }
#pragma unroll
    for (int i = 0; i < 3; i++) {
        float* o = pbuf + ((size_t)(zc * 3 + i) * BB + b) * SS;
        o[tid] = acc[i][0];
        o[tid + 256] = acc[i][1];
    }
}

__global__ __launch_bounds__(256) void k_sh(const float* __restrict__ pbuf,
                                            const float* __restrict__ A_sh,
                                            float* __restrict__ lshp) {
    __shared__ float lf[256];
    int b = blockIdx.x, c = blockIdx.y, h = blockIdx.z, tid = threadIdx.x;
    float v = 0.f;
#pragma unroll
    for (int zc = 0; zc < NCH; zc++)
        v += pbuf[((size_t)(zc * 3 + c) * BB + b) * SS + h * 256 + tid];
    lf[tid] = v * (1.0f / NN);
    __syncthreads();
    int w = tid >> 6, lane = tid & 63;
    for (int j = w; j < 36; j += 4) {
        const float* As = A_sh + j * SS + h * 256;
        float a = 0.f;
#pragma unroll
        for (int k = 0; k < 4; k++) a = fmaf(lf[lane + 64 * k], As[lane + 64 * k], a);
#pragma unroll
        for (int o = 32; o > 0; o >>= 1) a += __shfl_xor(a, o, 64);
        if (lane == 0) lshp[((b * 36 + j) * 3 + c) * 2 + h] = a;
    }
}

__global__ __launch_bounds__(256) void k_eval0(const float* __restrict__ lshp,
                                               const float* __restrict__ W0,
                                               const float* __restrict__ b0,
                                               const float* __restrict__ Dg0t,
                                               const float* __restrict__ rs0,
                                               float* __restrict__ yq, float* __restrict__ stats) {
    __shared__ float lsh[36][3];
    __shared__ float llm[576];
    __shared__ float lred[4][32];
    int qc = blockIdx.x, b = blockIdx.y, tid = threadIdx.x;
    if (tid < 108) {
        int j = tid / 3, c = tid % 3;
        lsh[j][c] = lshp[((b * 36 + j) * 3 + c) * 2 + 0] + lshp[((b * 36 + j) * 3 + c) * 2 + 1];
    }
    __syncthreads();
    for (int i = tid; i < 576; i += 256) {
        int j = i >> 4, u = i & 15;
        float m = 0.f;
#pragma unroll
        for (int c = 0; c < 3; c++) m = fmaf(lsh[j][c], W0[c * 16 + u], m);
        llm[i] = m;
    }
    __syncthreads();
    int q = qc * 256 + tid;
    float acc[16];
#pragma unroll
    for (int u = 0; u < 16; u++) acc[u] = 0.f;
#pragma unroll 4
    for (int j = 0; j < 36; j++) {
        float d = Dg0t[j * QQ + q];
#pragma unroll
        for (int u = 0; u < 16; u++) acc[u] = fmaf(d, llm[j * 16 + u], acc[u]);
    }
    float rb = rs0[q];
#pragma unroll
    for (int u = 0; u < 16; u++) acc[u] = fmaf(b0[u], rb, acc[u]);
#pragma unroll
    for (int u = 0; u < 16; u++) yq[((size_t)b * 16 + u) * QQ + q] = acc[u];
    int lane = tid & 63, w = tid >> 6;
#pragma unroll
    for (int u = 0; u < 16; u++) {
        float v = acc[u], v2 = acc[u] * acc[u];
#pragma unroll
        for (int o = 32; o > 0; o >>= 1) {
            v += __shfl_xor(v, o, 64);
            v2 += __shfl_xor(v2, o, 64);
        }
        if (lane == 0) { lred[w][u] = v; lred[w][16 + u] = v2; }
    }
    __syncthreads();
    if (tid < 32) atomicAdd(&stats[tid], lred[0][tid] + lred[1][tid] + lred[2][tid] + lred[3][tid]);
}

template <int TT, int UU, int QKN>
__global__ __launch_bounds__(256) void k_coefG(const float* __restrict__ yq,
                                               const float* __restrict__ Dc,
                                               const float* __restrict__ stats,
                                               const float* __restrict__ g,
                                               const float* __restrict__ be,
                                               float* __restrict__ part) {
    constexpr int KC = QQ / QKN;
    __shared__ float lA[32][68];
    __shared__ float lB[32][68];
    __shared__ float lsu[UU], ltu[UU];
    int mt = blockIdx.x, nt = blockIdx.y, qk = blockIdx.z, tid = threadIdx.x;
    int m0 = mt * 64, n0 = nt * 64, k0 = qk * KC;
    if (tid < UU) {
        const float inv = 1.0f / (BB * QQ);
        float mm = stats[tid] * inv;
        float var = stats[UU + tid] * inv - mm * mm;
        float s = g[tid] * rsqrtf(fmaxf(var, 0.f) + 1e-3f);
        lsu[tid] = s;
        ltu[tid] = be[tid] - mm * s;
    }
    __syncthreads();
    int r = tid >> 2, f = (tid & 3) * 4;
    bool mok = (m0 + r) < TT;
    const float* arow = Dc + (size_t)(mok ? (m0 + r) : 0) * QQ;
    const float* brow = yq + (size_t)(n0 + r) * QQ;
    float su = lsu[(n0 + r) % UU], tu = ltu[(n0 + r) % UU];
    int tg = tid >> 4, ug = tid & 15;
    float acc[4][4];
#pragma unroll
    for (int i = 0; i < 4; i++)
#pragma unroll
        for (int j = 0; j < 4; j++) acc[i][j] = 0.f;
    for (int kb = 0; kb < KC; kb += 32) {
        int kg = k0 + kb;
#pragma unroll
        for (int p = 0; p < 2; p++) {
            int ko = f + p * 16;
            float4 a4 = make_float4(0.f, 0.f, 0.f, 0.f);
            if (mok) a4 = *(const float4*)(arow + kg + ko);
            float4 b4 = *(const float4*)(brow + kg + ko);
#pragma unroll
            for (int i = 0; i < 4; i++) {
                float v = fmaf((&b4.x)[i], su, tu);
                lA[ko + i][r] = (&a4.x)[i];
                lB[ko + i][r] = (v > 0.f) ? v : 0.3f * v;
            }
        }
        __syncthreads();
#pragma unroll 2
        for (int kk = 0; kk < 32; kk++) {
            float4 a4 = *(const float4*)&lA[kk][tg * 4];
            float4 b4 = *(const float4*)&lB[kk][ug * 4];
#pragma unroll
            for (int i = 0; i < 4; i++) {
                float av = (&a4.x)[i];
                acc[i][0] = fmaf(av, b4.x, acc[i][0]);
                acc[i][1] = fmaf(av, b4.y, acc[i][1]);
                acc[i][2] = fmaf(av, b4.z, acc[i][2]);
                acc[i][3] = fmaf(av, b4.w, acc[i][3]);
            }
        }
        __syncthreads();
    }
    int n = n0 + ug * 4;
    int b = n / UU, u0 = n % UU;
#pragma unroll
    for (int i = 0; i < 4; i++) {
        int t = m0 + tg * 4 + i;
        if (t < TT)
            *(float4*)&part[(((size_t)qk * BB + b) * TT + t) * UU + u0] =
                make_float4(acc[i][0], acc[i][1], acc[i][2], acc[i][3]);
    }
}

template <int TT, int CC, int UU, int QKN, int TTp, int TS>
__global__ __launch_bounds__(256) void k_redmix(const float* __restrict__ part,
                                                const float* __restrict__ W,
                                                const float* __restrict__ bias,
                                                float* __restrict__ ym) {
    constexpr int TSL = TTp / TS;
    __shared__ float lyt[TSL][CC + 1];
    int b = blockIdx.x, ts = blockIdx.y, tid = threadIdx.x;
    int t0 = ts * TSL;
    for (int i = tid; i < TSL * CC; i += 256) {
        int tl = i / CC, c = i % CC;
        int t = t0 + tl;
        float v = 0.f;
        if (t < TT) {
#pragma unroll
            for (int k = 0; k < QKN; k++)
                v += part[(size_t)k * (BB * TT * CC) + ((size_t)b * TT + t) * CC + c];
        }
        lyt[tl][c] = v;
    }
    __syncthreads();
    for (int i = tid; i < UU * TSL; i += 256) {
        int u = i / TSL, tl = i % TSL;
        int t = t0 + tl;
        float m = 0.f;
        if (t < TT) {
            m = bias[u];
#pragma unroll
            for (int c = 0; c < CC; c++) m = fmaf(lyt[tl][c], W[c * UU + u], m);
        }
        ym[((size_t)b * UU + u) * TTp + t] = m;
    }
}

template <int TT, int TTp, int UU>
__global__ __launch_bounds__(256) void k_evalG(const float* __restrict__ ym,
                                               const float* __restrict__ Det,
                                               float* __restrict__ yq,
                                               float* __restrict__ stats) {
    __shared__ float lA[32][68];
    __shared__ float lB[32][68];
    __shared__ float sred[2][64];
    int mt = blockIdx.x, qt = blockIdx.y, tid = threadIdx.x;
    int m0 = mt * 64, q0 = qt * 64;
    int r = tid >> 2, f = (tid & 3) * 4;
    const float* arow = ym + (size_t)(m0 + r) * TTp;
    int br = tid >> 4, bq = (tid & 15) * 4;
    int tg = tid >> 4, ug = tid & 15;
    float acc[4][4];
#pragma unroll
    for (int i = 0; i < 4; i++)
#pragma unroll
        for (int j = 0; j < 4; j++) acc[i][j] = 0.f;
    for (int kb = 0; kb < TT; kb += 32) {
#pragma unroll
        for (int p = 0; p < 2; p++) {
            int ko = f + p * 16;
            float4 a4 = *(const float4*)(arow + kb + ko);
#pragma unroll
            for (int i = 0; i < 4; i++) lA[ko + i][r] = (&a4.x)[i];
            int kk = br + p * 16;
            int t = kb + kk;
            float4 b4 = make_float4(0.f, 0.f, 0.f, 0.f);
            if (t < TT) b4 = *(const float4*)(Det + (size_t)t * QQ + q0 + bq);
            *(float4*)&lB[kk][bq] = b4;
        }
        __syncthreads();
#pragma unroll 2
        for (int kk = 0; kk < 32; kk++) {
            float4 a4 = *(const float4*)&lA[kk][tg * 4];
            float4 b4 = *(const float4*)&lB[kk][ug * 4];
#pragma unroll
            for (int i = 0; i < 4; i++) {
                float av = (&a4.x)[i];
                acc[i][0] = fmaf(av, b4.x, acc[i][0]);
                acc[i][1] = fmaf(av, b4.y, acc[i][1]);
                acc[i][2] = fmaf(av, b4.z, acc[i][2]);
                acc[i][3] = fmaf(av, b4.w, acc[i][3]);
            }
        }
        __syncthreads();
    }
    float s1[4], s2[4];
#pragma unroll
    for (int i = 0; i < 4; i++) {
        int m = m0 + tg * 4 + i;
        *(float4*)&yq[(size_t)m * QQ + q0 + ug * 4] =
            make_float4(acc[i][0], acc[i][1], acc[i][2], acc[i][3]);
        s1[i] = (acc[i][0] + acc[i][1]) + (acc[i][2] + acc[i][3]);
        s2[i] = fmaf(acc[i][0], acc[i][0], fmaf(acc[i][1], acc[i][1],
                 fmaf(acc[i][2], acc[i][2], acc[i][3] * acc[i][3])));
    }
#pragma unroll
    for (int o = 1; o < 16; o <<= 1) {
#pragma unroll
        for (int i = 0; i < 4; i++) {
            s1[i] += __shfl_xor(s1[i], o, 64);
            s2[i] += __shfl_xor(s2[i], o, 64);
        }
    }
    if (ug == 0) {
#pragma unroll
        for (int i = 0; i < 4; i++) {
            sred[0][tg * 4 + i] = s1[i];
            sred[1][tg * 4 + i] = s2[i];
        }
    }
    __syncthreads();
    if (tid < 2 * UU) {
        int which = tid / UU, u = tid % UU;
        float s = 0.f;
        for (int rr = u; rr < 64; rr += UU) s += sred[which][rr];
        atomicAdd(&stats[which * UU + u], s);
    }
}

__global__ __launch_bounds__(256) void k_norms(const float* __restrict__ part, float* __restrict__ ht0) {
    __shared__ float red[4][64];
    int b = blockIdx.x, blk = blockIdx.y;
    int tq = threadIdx.x >> 6, u = threadIdx.x & 63;
    const int offs[4] = {0, 1, 10, 35};
    const int ends[4] = {1, 10, 35, 84};
    float a = 0.f;
    for (int t = offs[blk] + tq; t < ends[blk]; t += 4) {
        float v = 0.f;
#pragma unroll
        for (int k = 0; k < QKN3; k++)
            v += part[(size_t)k * (BB * 84 * 64) + (b * 84 + t) * 64 + u];
        a = fmaf(v, v, a);
    }
    red[tq][u] = a;
    __syncthreads();
    if (tq == 0) {
        float s = red[0][u] + red[1][u] + red[2][u] + red[3][u];
        ht0[(blk * 64 + u) * BB + b] = sqrtf(fmaxf(s, 0.f));
    }
}

template <int K, int J>
__global__ __launch_bounds__(512) void k_fc(const float* __restrict__ in, const float* __restrict__ W,
                                            const float* __restrict__ bias, const float* __restrict__ g,
                                            const float* __restrict__ be, float* __restrict__ out) {
    __shared__ float red[8][64];
    int j = blockIdx.x;
    int b = threadIdx.x & 63, kq = threadIdx.x >> 6;
    constexpr int KS = K / 8;
    int kbeg = kq * KS;
    float a0 = 0.f, a1 = 0.f, a2 = 0.f, a3 = 0.f;
#pragma unroll 4
    for (int k = kbeg; k < kbeg + KS; k += 4) {
        a0 = fmaf(in[k * BB + b], W[(size_t)k * J + j], a0);
        a1 = fmaf(in[(k + 1) * BB + b], W[(size_t)(k + 1) * J + j], a1);
        a2 = fmaf(in[(k + 2) * BB + b], W[(size_t)(k + 2) * J + j], a2);
        a3 = fmaf(in[(k + 3) * BB + b], W[(size_t)(k + 3) * J + j], a3);
    }
    red[kq][b] = (a0 + a1) + (a2 + a3);
    __syncthreads();
    if (kq == 0) {
        float acc = bias[j];
#pragma unroll
        for (int i = 0; i < 8; i++) acc += red[i][b];
        float s1 = acc, s2 = acc * acc;
#pragma unroll
        for (int o = 32; o > 0; o >>= 1) {
            s1 += __shfl_xor(s1, o, 64);
            s2 += __shfl_xor(s2, o, 64);
        }
        float m = s1 * (1.0f / 64.f);
        float var = s2 * (1.0f / 64.f) - m * m;
        float sc = g[j] * rsqrtf(fmaxf(var, 0.f) + 1e-3f);
        float v = (acc - m) * sc + be[j];
        out[j * BB + b] = fmaxf(v, 0.f);
    }
}

__global__ __launch_bounds__(256) void k_out(const float* __restrict__ ht2, const float* __restrict__ Wout,
                                             const float* __restrict__ bout, float* __restrict__ outp) {
    __shared__ float red[4][64];
    __shared__ float sm[64];
    int b = blockIdx.x;
    int o = threadIdx.x & 63, kq = threadIdx.x >> 6;
    float a0 = 0.f, a1 = 0.f, a2 = 0.f, a3 = 0.f;
    int kbeg = kq * 64;
    if (o < 40) {
#pragma unroll 4
        for (int k = kbeg; k < kbeg + 64; k += 4) {
            a0 = fmaf(ht2[k * BB + b], Wout[k * 40 + o], a0);
            a1 = fmaf(ht2[(k + 1) * BB + b], Wout[(k + 1) * 40 + o], a1);
            a2 = fmaf(ht2[(k + 2) * BB + b], Wout[(k + 2) * 40 + o], a2);
            a3 = fmaf(ht2[(k + 3) * BB + b], Wout[(k + 3) * 40 + o], a3);
        }
    }
    red[kq][o] = (a0 + a1) + (a2 + a3);
    __syncthreads();
    if (kq == 0) {
        float acc = red[0][o] + red[1][o] + red[2][o] + red[3][o] + ((o < 40) ? bout[o] : 0.f);
        sm[o] = (o < 40) ? acc : -3.0e38f;
        __syncthreads();
        for (int s = 32; s > 0; s >>= 1) {
            if (o < s) sm[o] = fmaxf(sm[o], sm[o + s]);
            __syncthreads();
        }
        float m = sm[0];
        __syncthreads();
        const float L2E = 1.4426950408889634f;
        float e = (o < 40) ? exp2f((acc - m) * L2E) : 0.f;
        sm[o] = e;
        __syncthreads();
        for (int s = 32; s > 0; s >>= 1) {
            if (o < s) sm[o] += sm[o + s];
            __syncthreads();
        }
        if (o < 40) outp[b * 40 + o] = e / sm[0];
    }
}

// ---------------- workspace layout (float offsets; all 128B-aligned; no buffer
// written twice within a run — required by the write-through coherence scheme) ----
#define OFF_PBUF 0           // 1572864
#define OFF_DG0T 1572864     // 36864
#define OFF_RS0 1609728      // 1024
#define OFF_DET1 1610752     // 168960
#define OFF_DET2 1779712     // 86016
#define OFF_YQ0 1865728      // 1048576
#define OFF_YQ1 2914304      // 2097152
#define OFF_YQ2 5011456      // 4194304
#define OFF_YMA 9205760      // 393216
#define OFF_YMB 9598976      // 393216
#define OFF_LSH 9992192      // 13824
#define OFF_HT0 10006016     // 16384
#define OFF_HT1 10022400     // 32768
#define OFF_HT2 10055168     // 16384
#define OFF_STATS 10071552   // 224 (+pad to 256)
#define OFF_PARTA 10071808   // 1351680
#define OFF_PARTB 11423488   // 1376256
#define OFF_PART3 12799744   // 2752512 (ends 15552256 floats = 62 MB)

extern "C" void kernel_launch(void* const* d_in, const int* in_sizes, int n_in,
                              void* d_out, int out_size, void* d_ws, size_t ws_size,
                              hipStream_t stream) {
    float* ws = (float*)d_ws;
    MArgs a;
    a.x = (const float*)d_in[0];
    a.dirs = (const float*)d_in[1];
    a.A_sh = (const float*)d_in[2];
    a.De0 = (const float*)d_in[3];
    a.De1 = (const float*)d_in[4];
    a.De2 = (const float*)d_in[5];
    a.Dc1 = (const float*)d_in[6];
    a.Dc2 = (const float*)d_in[7];
    a.Dc3 = (const float*)d_in[8];
    a.W0 = (const float*)d_in[9];
    a.b0 = (const float*)d_in[10];
    a.W1 = (const float*)d_in[11];
    a.b1 = (const float*)d_in[12];
    a.W2 = (const float*)d_in[13];
    a.b2 = (const float*)d_in[14];
    a.g0 = (const float*)d_in[15];
    a.be0 = (const float*)d_in[16];
    a.g1 = (const float*)d_in[17];
    a.be1 = (const float*)d_in[18];
    a.g2 = (const float*)d_in[19];
    a.be2 = (const float*)d_in[20];
    a.Wfc1 = (const float*)d_in[21];
    a.bfc1 = (const float*)d_in[22];
    a.gfc1 = (const float*)d_in[23];
    a.befc1 = (const float*)d_in[24];
    a.Wfc2 = (const float*)d_in[25];
    a.bfc2 = (const float*)d_in[26];
    a.gfc2 = (const float*)d_in[27];
    a.befc2 = (const float*)d_in[28];
    a.Wout = (const float*)d_in[29];
    a.bout = (const float*)d_in[30];
    a.pbuf = ws + OFF_PBUF;
    a.Dg0t = ws + OFF_DG0T;
    a.rs0 = ws + OFF_RS0;
    a.Det1 = ws + OFF_DET1;
    a.Det2 = ws + OFF_DET2;
    a.yq0 = ws + OFF_YQ0;
    a.yq1 = ws + OFF_YQ1;
    a.yq2 = ws + OFF_YQ2;
    a.ymA = ws + OFF_YMA;
    a.ymB = ws + OFF_YMB;
    a.lshp = ws + OFF_LSH;
    a.ht0 = ws + OFF_HT0;
    a.ht1 = ws + OFF_HT1;
    a.ht2 = ws + OFF_HT2;
    a.stats = ws + OFF_STATS;
    a.partA = ws + OFF_PARTA;
    a.partB = ws + OFF_PARTB;
    a.part3 = ws + OFF_PART3;
    a.out = (float*)d_out;

    // ---- one-time cooperative viability gate (host queries only; no stream ops) ----
    static int mode = -1;
    static int gsize = 0;
    if (mode < 0) {
        int dev = 0;
        (void)hipGetDevice(&dev);
        int coop = 0;
        (void)hipDeviceGetAttribute(&coop, hipDeviceAttributeCooperativeLaunch, dev);
        int ncu = 0;
        (void)hipDeviceGetAttribute(&ncu, hipDeviceAttributeMultiprocessorCount, dev);
        int occ = 0;
        hipError_t e = hipOccupancyMaxActiveBlocksPerMultiprocessor(&occ, (const void*)k_mega, 256, 0);
        long long mg = (long long)occ * (long long)ncu;
        if (coop && e == hipSuccess && mg >= 256) {
            int gs = (int)(mg > 1024 ? 1024 : mg);
            gsize = gs & ~31;  // multiple of 32 for the tree barrier
            mode = (gsize >= 256) ? 1 : 0;
        } else {
            mode = 0;
        }
    }

    if (mode == 1) {
        void* kargs[] = {(void*)&a};
        hipError_t le =
            hipLaunchCooperativeKernel((const void*)k_mega, dim3(gsize), dim3(256), kargs, 0, stream);
        if (le == hipSuccess) return;
        mode = 0;  // permanent fallback if the runtime rejects cooperative launch
    }

    // ---- fallback: proven 14-kernel pipeline ----
    float* stats0 = a.stats;
    float* stats1 = a.stats + 32;
    float* stats2 = a.stats + 96;
    k_preshell<<<PREPB + BB * NCH, 256, 0, stream>>>(
        a.De0, a.De1, a.De2, a.Dg0t, a.rs0, a.Det1, a.Det2, a.stats, a.x, a.dirs, a.pbuf);
    k_sh<<<dim3(BB, 3, 2), 256, 0, stream>>>(a.pbuf, a.A_sh, a.lshp);
    k_eval0<<<dim3(4, BB), 256, 0, stream>>>(a.lshp, a.W0, a.b0, a.Dg0t, a.rs0, a.yq0, stats0);
    k_coefG<165, 16, 8><<<dim3(3, 16, 8), 256, 0, stream>>>(a.yq0, a.Dc1, stats0, a.g0, a.be0, a.partA);
    k_redmix<165, 16, 32, 8, 192, 8><<<dim3(BB, 8), 256, 0, stream>>>(a.partA, a.W1, a.b1, a.ymA);
    k_evalG<165, 192, 32><<<dim3(32, 16), 256, 0, stream>>>(a.ymA, a.Det1, a.yq1, stats1);
    k_coefG<84, 32, 8><<<dim3(2, 32, 8), 256, 0, stream>>>(a.yq1, a.Dc2, stats1, a.g1, a.be1, a.partB);
    k_redmix<84, 32, 64, 8, 96, 8><<<dim3(BB, 8), 256, 0, stream>>>(a.partB, a.W2, a.b2, a.ymB);
    k_evalG<84, 96, 64><<<dim3(64, 16), 256, 0, stream>>>(a.ymB, a.Det2, a.yq2, stats2);
    k_coefG<84, 64, QKN3><<<dim3(2, 64, QKN3), 256, 0, stream>>>(a.yq2, a.Dc3, stats2, a.g2, a.be2, a.part3);
    k_norms<<<dim3(BB, 4), 256, 0, stream>>>(a.part3, a.ht0);
    k_fc<256, 512><<<512, 512, 0, stream>>>(a.ht0, a.Wfc1, a.bfc1, a.gfc1, a.befc1, a.ht1);
    k_fc<512, 256><<<256, 512, 0, stream>>>(a.ht1, a.Wfc2, a.bfc2, a.gfc2, a.befc2, a.ht2);
    k_out<<<BB, 256, 0, stream>>>(a.ht2, a.Wout, a.bout, a.out);
}

// Round 8
// 382.467 us; speedup vs baseline: 3.1605x; 1.1470x over previous
//
#include <hip/hip_runtime.h>

#define BB 64
#define NN 2048
#define QQ 1024
#define SS 512
#define NCH 16
#define PREPB 609
#define QKN3 8

__device__ const int PIDX[36] = {
    0, 2, 5, 8, 12, 17, 22, 27, 32, 38, 45, 52, 59, 66, 73, 80,
    88, 97, 106, 115, 124, 133, 142, 151, 160,
    170, 181, 192, 203, 214, 225, 236, 247, 258, 269, 280};

struct MArgs {
    const float *x, *dirs, *A_sh, *De0, *De1, *De2, *Dc1, *Dc2, *Dc3;
    const float *W0, *b0, *W1, *b1, *W2, *b2;
    const float *g0, *be0, *g1, *be1, *g2, *be2;
    const float *Wfc1, *bfc1, *gfc1, *befc1, *Wfc2, *bfc2, *gfc2, *befc2, *Wout, *bout;
    float *pbuf, *Dg0t, *rs0, *Det1, *Det2;
    float *yq0, *yq1, *yq2, *ymA, *ymB, *lshp;
    float *ht0, *ht1, *ht2, *stats, *partA, *partB, *part3, *out;
};

struct SmGemm { float lA[32][68]; float lB[32][68]; float lsu[64]; float ltu[64]; };
struct SmEv   { float lA[32][68]; float lB[32][68]; float sred[2][64]; };
struct SmE0   { float lsh[36][3]; float llm[576]; float lred[4][32]; };

// ================= write-through publication stores =================
// COMPILER-EMITTED agent-scope relaxed atomic stores ONLY (global_store sc1,
// vmcnt-tracked, coherence-point semantics guaranteed by the memory model).
// Rounds 6/7 proved the hand-rolled `global_store_dwordx4 sc0 sc1` inline asm
// does NOT provide equivalent visibility (absmax 0.14 both with and without an
// explicit vmcnt(0) drain) — the vector-store experiment is abandoned. The
// resulting partial-line write-through amplification (201MB vs 61MB logical,
// Round-4 measured) costs ~20us of HBM write time; correctness wins.
// Coherence argument (Round-4 proven): no buffer written twice per run,
// 128B-aligned buffers, dispatch-start acquire invalidates L1/L2 once per
// replay; a consumer's cache first touches a line only after its producer's
// memory-side write -> plain cached consumer loads are safe, and the grid
// barrier needs NO cache-maintenance fences.
__device__ __forceinline__ void st_wt(float* p, float v) {
    __hip_atomic_store(p, v, __ATOMIC_RELAXED, __HIP_MEMORY_SCOPE_AGENT);
}
__device__ __forceinline__ void st_wt4(float* p, float4 v) {
    st_wt(p + 0, v.x); st_wt(p + 1, v.y); st_wt(p + 2, v.z); st_wt(p + 3, v.w);
}

// ================= tree grid barrier: counters only, NO fences =================
// (verbatim Round-4-proven protocol; only the sleep constant differs, perf-only)
// Probes are relaxed RMWs (memory-side, fresh cross-XCD, no buffer_inv).
// __syncthreads drains vmcnt before arrival (compiler-tracked sc1 stores), so
// all stores are at the coherence point before any block arrives. State lines
// padded 256B; counters return to 0 each use; gens grow monotonically across
// graph replays. Grid is a multiple of 32.
__device__ unsigned g_grp_cnt[32 * 64];
__device__ unsigned g_grp_gen[32 * 64];
__device__ unsigned g_root_cnt[64];
__device__ unsigned g_root_gen[64];

__device__ __forceinline__ unsigned bar_probe(unsigned* p) {
    return __hip_atomic_fetch_add(p, 0u, __ATOMIC_RELAXED, __HIP_MEMORY_SCOPE_AGENT);
}

__device__ __forceinline__ void gbar() {
    __syncthreads();
    if (threadIdx.x == 0) {
        const int G = (int)gridDim.x;
        const int gsz = G >> 5;  // 32 groups; G is a multiple of 32
        const int grp = (int)blockIdx.x / gsz;
        unsigned* gcnt = &g_grp_cnt[grp << 6];
        unsigned* ggen = &g_grp_gen[grp << 6];
        if ((int)blockIdx.x % gsz == 0) {
            unsigned rg = bar_probe(&g_root_gen[0]);
            while (bar_probe(gcnt) < (unsigned)(gsz - 1)) __builtin_amdgcn_s_sleep(1);
            __hip_atomic_exchange(gcnt, 0u, __ATOMIC_RELAXED, __HIP_MEMORY_SCOPE_AGENT);
            unsigned arrived = __hip_atomic_fetch_add(&g_root_cnt[0], 1u, __ATOMIC_RELAXED,
                                                      __HIP_MEMORY_SCOPE_AGENT) + 1u;
            if (arrived == 32u) {
                __hip_atomic_exchange(&g_root_cnt[0], 0u, __ATOMIC_RELAXED, __HIP_MEMORY_SCOPE_AGENT);
                __hip_atomic_fetch_add(&g_root_gen[0], 1u, __ATOMIC_RELAXED, __HIP_MEMORY_SCOPE_AGENT);
            } else {
                while (bar_probe(&g_root_gen[0]) == rg) __builtin_amdgcn_s_sleep(1);
            }
            __hip_atomic_fetch_add(ggen, 1u, __ATOMIC_RELAXED, __HIP_MEMORY_SCOPE_AGENT);
        } else {
            unsigned gg = bar_probe(ggen);
            __hip_atomic_fetch_add(gcnt, 1u, __ATOMIC_RELAXED, __HIP_MEMORY_SCOPE_AGENT);
            while (bar_probe(ggen) == gg) __builtin_amdgcn_s_sleep(1);
        }
    }
    __syncthreads();
}

// ================= megakernel phase bodies =================
// Each phase leads with __syncthreads() to protect LDS reuse across grid-stride
// iterations. All phase-output stores are write-through (st_wt / st_wt4).

__device__ void ph_shell(const MArgs& a, int wb, char* smraw, int tid) {
    __syncthreads();
    float4* lx = reinterpret_cast<float4*>(smraw);
    int b = wb & 63, zc = wb >> 6;
    const float KL = 18.033688011112042f;  // log2(e)/SIGMA2, SIGMA2=0.08
    const float* xb = a.x + ((size_t)b * NN + zc * (NN / NCH)) * 3;
    for (int n = tid; n < NN / NCH; n += 256) {
        float X = xb[n * 3 + 0];
        float Y = xb[n * 3 + 1];
        float Z = xb[n * 3 + 2];
        lx[n] = make_float4(X, Y, Z, -KL * (X * X + Y * Y + Z * Z));
    }
    __syncthreads();
    float cxs[3][2], cys[3][2], czs[3][2], bas[3][2];
#pragma unroll
    for (int i = 0; i < 3; i++) {
        float r = (i == 0) ? 0.4f : ((i == 1) ? 0.8f : 1.2f);
#pragma unroll
        for (int h = 0; h < 2; h++) {
            int s = tid + h * 256;
            float cx = r * a.dirs[(i * SS + s) * 3 + 0];
            float cy = r * a.dirs[(i * SS + s) * 3 + 1];
            float cz = r * a.dirs[(i * SS + s) * 3 + 2];
            bas[i][h] = -KL * (cx * cx + cy * cy + cz * cz);
            cxs[i][h] = 2.f * KL * cx;
            cys[i][h] = 2.f * KL * cy;
            czs[i][h] = 2.f * KL * cz;
        }
    }
    float acc[3][2];
#pragma unroll
    for (int i = 0; i < 3; i++) { acc[i][0] = 0.f; acc[i][1] = 0.f; }
#pragma unroll 4
    for (int n = 0; n < NN / NCH; n++) {
        float4 p = lx[n];
#pragma unroll
        for (int i = 0; i < 3; i++)
#pragma unroll
            for (int h = 0; h < 2; h++)
                acc[i][h] += __builtin_amdgcn_exp2f(
                    fmaf(cxs[i][h], p.x, fmaf(cys[i][h], p.y, fmaf(czs[i][h], p.z, p.w))));
    }
#pragma unroll
    for (int i = 0; i < 3; i++) {
        float* o = a.pbuf + ((size_t)(zc * 3 + i) * BB + b) * SS;
        st_wt(o + tid, acc[i][0] * __builtin_amdgcn_exp2f(bas[i][0]));
        st_wt(o + tid + 256, acc[i][1] * __builtin_amdgcn_exp2f(bas[i][1]));
    }
}

__device__ void ph_sh(const MArgs& a, int wb, char* smraw, int tid) {
    __syncthreads();
    float* lf = reinterpret_cast<float*>(smraw);
    int b = wb & 63;
    int t = wb >> 6;  // 0..5
    int c = t % 3, h = t / 3;
    float v = 0.f;
#pragma unroll
    for (int zc = 0; zc < NCH; zc++)
        v += a.pbuf[((size_t)(zc * 3 + c) * BB + b) * SS + h * 256 + tid];
    lf[tid] = v * (1.0f / NN);
    __syncthreads();
    int w = tid >> 6, lane = tid & 63;
    for (int j = w; j < 36; j += 4) {
        const float* As = a.A_sh + j * SS + h * 256;
        float acc = 0.f;
#pragma unroll
        for (int k = 0; k < 4; k++) acc = fmaf(lf[lane + 64 * k], As[lane + 64 * k], acc);
#pragma unroll
        for (int o = 32; o > 0; o >>= 1) acc += __shfl_xor(acc, o, 64);
        if (lane == 0) st_wt(&a.lshp[((b * 36 + j) * 3 + c) * 2 + h], acc);
    }
}

__device__ void ph_prep(const MArgs& a, int wb, char* smraw, int tid) {
    __syncthreads();
    float (*tile)[33] = reinterpret_cast<float (*)[33]>(smraw);
    int r = tid >> 5, c = tid & 31;
    if (wb < 576) {  // De1 -> Det1 [165][1024]
        int i = wb - 384;
        int tq = i & 31, tt = i >> 5;
        int q0 = tq * 32, t0 = tt * 32;
        for (int rr = r; rr < 32; rr += 8) {
            int t = t0 + c;
            tile[rr][c] = (t < 165) ? a.De1[(q0 + rr) * 165 + t] : 0.f;
        }
        __syncthreads();
        for (int rr = r; rr < 32; rr += 8) {
            int t = t0 + rr;
            if (t < 165) st_wt(&a.Det1[t * QQ + q0 + c], tile[c][rr]);
        }
    } else if (wb < 672) {  // De2 -> Det2 [84][1024]
        int i = wb - 576;
        int tq = i & 31, tt = i >> 5;
        int q0 = tq * 32, t0 = tt * 32;
        for (int rr = r; rr < 32; rr += 8) {
            int t = t0 + c;
            tile[rr][c] = (t < 84) ? a.De2[(q0 + rr) * 84 + t] : 0.f;
        }
        __syncthreads();
        for (int rr = r; rr < 32; rr += 8) {
            int t = t0 + rr;
            if (t < 84) st_wt(&a.Det2[t * QQ + q0 + c], tile[c][rr]);
        }
    } else if (wb < 736) {  // gather De0[:, PIDX] -> Dg0t [36][1024]
        int i = wb - 672;
        int tq = i & 31, tj = i >> 5;
        int q0 = tq * 32, j0 = tj * 32;
        for (int rr = r; rr < 32; rr += 8) {
            int j = j0 + c;
            tile[rr][c] = (j < 36) ? a.De0[(q0 + rr) * 286 + PIDX[j]] : 0.f;
        }
        __syncthreads();
        for (int rr = r; rr < 32; rr += 8) {
            int j = j0 + rr;
            if (j < 36) st_wt(&a.Dg0t[j * QQ + q0 + c], tile[c][rr]);
        }
    } else {  // rowsum of De0: one q per wave
        int w = tid >> 6, lane = tid & 63;
        int q = (wb - 736) * 4 + w;
        float s = 0.f;
#pragma unroll
        for (int p = 0; p < 5; p++) {
            int idx = lane + p * 64;
            if (idx < 286) s += a.De0[q * 286 + idx];
        }
#pragma unroll
        for (int o = 32; o > 0; o >>= 1) s += __shfl_xor(s, o, 64);
        if (lane == 0) st_wt(&a.rs0[q], s);
    }
}

__device__ void ph_eval0(const MArgs& a, int wb, char* smraw, int tid) {
    __syncthreads();
    SmE0& s = *reinterpret_cast<SmE0*>(smraw);
    int qc = wb & 3, b = wb >> 2;
    if (tid < 108) {
        int j = tid / 3, c = tid % 3;
        s.lsh[j][c] = a.lshp[((b * 36 + j) * 3 + c) * 2 + 0] +
                      a.lshp[((b * 36 + j) * 3 + c) * 2 + 1];
    }
    __syncthreads();
    for (int i = tid; i < 576; i += 256) {
        int j = i >> 4, u = i & 15;
        float m = 0.f;
#pragma unroll
        for (int c = 0; c < 3; c++) m = fmaf(s.lsh[j][c], a.W0[c * 16 + u], m);
        s.llm[i] = m;
    }
    __syncthreads();
    int q = qc * 256 + tid;
    float acc[16];
#pragma unroll
    for (int u = 0; u < 16; u++) acc[u] = 0.f;
#pragma unroll 4
    for (int j = 0; j < 36; j++) {
        float d = a.Dg0t[j * QQ + q];
#pragma unroll
        for (int u = 0; u < 16; u++) acc[u] = fmaf(d, s.llm[j * 16 + u], acc[u]);
    }
    float rb = a.rs0[q];
#pragma unroll
    for (int u = 0; u < 16; u++) acc[u] = fmaf(a.b0[u], rb, acc[u]);
#pragma unroll
    for (int u = 0; u < 16; u++) st_wt(&a.yq0[((size_t)b * 16 + u) * QQ + q], acc[u]);
    int lane = tid & 63, w = tid >> 6;
#pragma unroll
    for (int u = 0; u < 16; u++) {
        float v = acc[u], v2 = acc[u] * acc[u];
#pragma unroll
        for (int o = 32; o > 0; o >>= 1) {
            v += __shfl_xor(v, o, 64);
            v2 += __shfl_xor(v2, o, 64);
        }
        if (lane == 0) { s.lred[w][u] = v; s.lred[w][16 + u] = v2; }
    }
    __syncthreads();
    if (tid < 32)
        atomicAdd(&a.stats[tid], s.lred[0][tid] + s.lred[1][tid] + s.lred[2][tid] + s.lred[3][tid]);
}

template <int TT, int UU, int QKN>
__device__ void ph_coefG(const float* __restrict__ yq, const float* __restrict__ Dc,
                         const float* __restrict__ stats, const float* __restrict__ g,
                         const float* __restrict__ be, float* __restrict__ part,
                         int mt, int nt, int qk, char* smraw, int tid) {
    __syncthreads();
    constexpr int KC = QQ / QKN;
    SmGemm& s = *reinterpret_cast<SmGemm*>(smraw);
    int m0 = mt * 64, n0 = nt * 64, k0 = qk * KC;
    if (tid < UU) {
        const float inv = 1.0f / (BB * QQ);
        float mm = stats[tid] * inv;
        float var = stats[UU + tid] * inv - mm * mm;
        float sc = g[tid] * rsqrtf(fmaxf(var, 0.f) + 1e-3f);
        s.lsu[tid] = sc;
        s.ltu[tid] = be[tid] - mm * sc;
    }
    __syncthreads();
    int r = tid >> 2, f = (tid & 3) * 4;
    bool mok = (m0 + r) < TT;
    const float* arow = Dc + (size_t)(mok ? (m0 + r) : 0) * QQ;
    const float* brow = yq + (size_t)(n0 + r) * QQ;
    float su = s.lsu[(n0 + r) % UU], tu = s.ltu[(n0 + r) % UU];
    int tg = tid >> 4, ug = tid & 15;
    float acc[4][4];
#pragma unroll
    for (int i = 0; i < 4; i++)
#pragma unroll
        for (int j = 0; j < 4; j++) acc[i][j] = 0.f;
    for (int kb = 0; kb < KC; kb += 32) {
        int kg = k0 + kb;
#pragma unroll
        for (int p = 0; p < 2; p++) {
            int ko = f + p * 16;
            float4 a4 = make_float4(0.f, 0.f, 0.f, 0.f);
            if (mok) a4 = *(const float4*)(arow + kg + ko);
            float4 b4 = *(const float4*)(brow + kg + ko);
#pragma unroll
            for (int i = 0; i < 4; i++) {
                float v = fmaf((&b4.x)[i], su, tu);
                s.lA[ko + i][r] = (&a4.x)[i];
                s.lB[ko + i][r] = (v > 0.f) ? v : 0.3f * v;
            }
        }
        __syncthreads();
#pragma unroll 2
        for (int kk = 0; kk < 32; kk++) {
            float4 a4 = *(const float4*)&s.lA[kk][tg * 4];
            float4 b4 = *(const float4*)&s.lB[kk][ug * 4];
#pragma unroll
            for (int i = 0; i < 4; i++) {
                float av = (&a4.x)[i];
                acc[i][0] = fmaf(av, b4.x, acc[i][0]);
                acc[i][1] = fmaf(av, b4.y, acc[i][1]);
                acc[i][2] = fmaf(av, b4.z, acc[i][2]);
                acc[i][3] = fmaf(av, b4.w, acc[i][3]);
            }
        }
        __syncthreads();
    }
    int n = n0 + ug * 4;
    int b = n / UU, u0 = n % UU;
#pragma unroll
    for (int i = 0; i < 4; i++) {
        int t = m0 + tg * 4 + i;
        if (t < TT)
            st_wt4(&part[(((size_t)qk * BB + b) * TT + t) * UU + u0],
                   make_float4(acc[i][0], acc[i][1], acc[i][2], acc[i][3]));
    }
}

template <int TT, int CC, int UU, int QKN, int TTp, int TS>
__device__ void ph_redmix(const float* __restrict__ part, const float* __restrict__ W,
                          const float* __restrict__ bias, float* __restrict__ ym,
                          int b, int ts, char* smraw, int tid) {
    __syncthreads();
    constexpr int TSL = TTp / TS;
    float* lyt = reinterpret_cast<float*>(smraw);  // [TSL][CC+1]
    int t0 = ts * TSL;
    for (int i = tid; i < TSL * CC; i += 256) {
        int tl = i / CC, c = i % CC;
        int t = t0 + tl;
        float v = 0.f;
        if (t < TT) {
#pragma unroll
            for (int k = 0; k < QKN; k++)
                v += part[(size_t)k * (BB * TT * CC) + ((size_t)b * TT + t) * CC + c];
        }
        lyt[tl * (CC + 1) + c] = v;
    }
    __syncthreads();
    for (int i = tid; i < UU * TSL; i += 256) {
        int u = i / TSL, tl = i % TSL;
        int t = t0 + tl;
        float m = 0.f;
        if (t < TT) {
            m = bias[u];
#pragma unroll
            for (int c = 0; c < CC; c++) m = fmaf(lyt[tl * (CC + 1) + c], W[c * UU + u], m);
        }
        st_wt(&ym[((size_t)b * UU + u) * TTp + t], m);
    }
}

template <int TT, int TTp, int UU>
__device__ void ph_evalG(const float* __restrict__ ym, const float* __restrict__ Det,
                         float* __restrict__ yq, float* __restrict__ stats,
                         int mt, int qt, char* smraw, int tid) {
    __syncthreads();
    SmEv& s = *reinterpret_cast<SmEv*>(smraw);
    int m0 = mt * 64, q0 = qt * 64;
    int r = tid >> 2, f = (tid & 3) * 4;
    const float* arow = ym + (size_t)(m0 + r) * TTp;
    int br = tid >> 4, bq = (tid & 15) * 4;
    int tg = tid >> 4, ug = tid & 15;
    float acc[4][4];
#pragma unroll
    for (int i = 0; i < 4; i++)
#pragma unroll
        for (int j = 0; j < 4; j++) acc[i][j] = 0.f;
    for (int kb = 0; kb < TT; kb += 32) {
#pragma unroll
        for (int p = 0; p < 2; p++) {
            int ko = f + p * 16;
            float4 a4 = *(const float4*)(arow + kb + ko);
#pragma unroll
            for (int i = 0; i < 4; i++) s.lA[ko + i][r] = (&a4.x)[i];
            int kk = br + p * 16;
            int t = kb + kk;
            float4 b4 = make_float4(0.f, 0.f, 0.f, 0.f);
            if (t < TT) b4 = *(const float4*)(Det + (size_t)t * QQ + q0 + bq);
            *(float4*)&s.lB[kk][bq] = b4;
        }
        __syncthreads();
#pragma unroll 2
        for (int kk = 0; kk < 32; kk++) {
            float4 a4 = *(const float4*)&s.lA[kk][tg * 4];
            float4 b4 = *(const float4*)&s.lB[kk][ug * 4];
#pragma unroll
            for (int i = 0; i < 4; i++) {
                float av = (&a4.x)[i];
                acc[i][0] = fmaf(av, b4.x, acc[i][0]);
                acc[i][1] = fmaf(av, b4.y, acc[i][1]);
                acc[i][2] = fmaf(av, b4.z, acc[i][2]);
                acc[i][3] = fmaf(av, b4.w, acc[i][3]);
            }
        }
        __syncthreads();
    }
    float s1[4], s2[4];
#pragma unroll
    for (int i = 0; i < 4; i++) {
        int m = m0 + tg * 4 + i;
        st_wt4(&yq[(size_t)m * QQ + q0 + ug * 4],
               make_float4(acc[i][0], acc[i][1], acc[i][2], acc[i][3]));
        s1[i] = (acc[i][0] + acc[i][1]) + (acc[i][2] + acc[i][3]);
        s2[i] = fmaf(acc[i][0], acc[i][0], fmaf(acc[i][1], acc[i][1],
                 fmaf(acc[i][2], acc[i][2], acc[i][3] * acc[i][3])));
    }
#pragma unroll
    for (int o = 1; o < 16; o <<= 1) {
#pragma unroll
        for (int i = 0; i < 4; i++) {
            s1[i] += __shfl_xor(s1[i], o, 64);
            s2[i] += __shfl_xor(s2[i], o, 64);
        }
    }
    if (ug == 0) {
#pragma unroll
        for (int i = 0; i < 4; i++) {
            s.sred[0][tg * 4 + i] = s1[i];
            s.sred[1][tg * 4 + i] = s2[i];
        }
    }
    __syncthreads();
    if (tid < 2 * UU) {
        int which = tid / UU, u = tid % UU;
        float sv = 0.f;
        for (int rr = u; rr < 64; rr += UU) sv += s.sred[which][rr];
        atomicAdd(&stats[which * UU + u], sv);
    }
}

__device__ void ph_norms(const float* __restrict__ part, float* __restrict__ ht0,
                         int b, int blk, char* smraw, int tid) {
    __syncthreads();
    float (*red)[64] = reinterpret_cast<float (*)[64]>(smraw);
    int tq = tid >> 6, u = tid & 63;
    const int offs[4] = {0, 1, 10, 35};
    const int ends[4] = {1, 10, 35, 84};
    float acc = 0.f;
    for (int t = offs[blk] + tq; t < ends[blk]; t += 4) {
        float v = 0.f;
#pragma unroll
        for (int k = 0; k < QKN3; k++)
            v += part[(size_t)k * (BB * 84 * 64) + (b * 84 + t) * 64 + u];
        acc = fmaf(v, v, acc);
    }
    red[tq][u] = acc;
    __syncthreads();
    if (tq == 0) {
        float sv = red[0][u] + red[1][u] + red[2][u] + red[3][u];
        st_wt(&ht0[(blk * 64 + u) * BB + b], sqrtf(fmaxf(sv, 0.f)));
    }
}

template <int K, int J>
__device__ void ph_fc(const float* __restrict__ in, const float* __restrict__ W,
                      const float* __restrict__ bias, const float* __restrict__ g,
                      const float* __restrict__ be, float* __restrict__ out,
                      int j, char* smraw, int tid) {
    __syncthreads();
    float (*red)[64] = reinterpret_cast<float (*)[64]>(smraw);
    int b = tid & 63, kq = tid >> 6;
    constexpr int KS = K / 4;
    int kbeg = kq * KS;
    float a0 = 0.f, a1 = 0.f, a2 = 0.f, a3 = 0.f;
#pragma unroll 4
    for (int k = kbeg; k < kbeg + KS; k += 4) {
        a0 = fmaf(in[k * BB + b], W[(size_t)k * J + j], a0);
        a1 = fmaf(in[(k + 1) * BB + b], W[(size_t)(k + 1) * J + j], a1);
        a2 = fmaf(in[(k + 2) * BB + b], W[(size_t)(k + 2) * J + j], a2);
        a3 = fmaf(in[(k + 3) * BB + b], W[(size_t)(k + 3) * J + j], a3);
    }
    red[kq][b] = (a0 + a1) + (a2 + a3);
    __syncthreads();
    if (kq == 0) {
        float acc = bias[j] + red[0][b] + red[1][b] + red[2][b] + red[3][b];
        float s1 = acc, s2 = acc * acc;
#pragma unroll
        for (int o = 32; o > 0; o >>= 1) {
            s1 += __shfl_xor(s1, o, 64);
            s2 += __shfl_xor(s2, o, 64);
        }
        float m = s1 * (1.0f / 64.f);
        float var = s2 * (1.0f / 64.f) - m * m;
        float sc = g[j] * rsqrtf(fmaxf(var, 0.f) + 1e-3f);
        float v = (acc - m) * sc + be[j];
        st_wt(&out[j * BB + b], fmaxf(v, 0.f));
    }
}

__device__ void ph_out(const float* __restrict__ ht2, const float* __restrict__ Wout,
                       const float* __restrict__ bout, float* __restrict__ outp,
                       int b, char* smraw, int tid) {
    __syncthreads();
    float (*red)[64] = reinterpret_cast<float (*)[64]>(smraw);
    int o = tid & 63, kq = tid >> 6;
    float a0 = 0.f, a1 = 0.f, a2 = 0.f, a3 = 0.f;
    int kbeg = kq * 64;
    if (o < 40) {
#pragma unroll 4
        for (int k = kbeg; k < kbeg + 64; k += 4) {
            a0 = fmaf(ht2[k * BB + b], Wout[k * 40 + o], a0);
            a1 = fmaf(ht2[(k + 1) * BB + b], Wout[(k + 1) * 40 + o], a1);
            a2 = fmaf(ht2[(k + 2) * BB + b], Wout[(k + 2) * 40 + o], a2);
            a3 = fmaf(ht2[(k + 3) * BB + b], Wout[(k + 3) * 40 + o], a3);
        }
    }
    red[kq][o] = (a0 + a1) + (a2 + a3);
    __syncthreads();
    if (kq == 0) {
        float acc = red[0][o] + red[1][o] + red[2][o] + red[3][o] + ((o < 40) ? bout[o] : 0.f);
        float m = (o < 40) ? acc : -3.0e38f;
#pragma unroll
        for (int s = 32; s > 0; s >>= 1) m = fmaxf(m, __shfl_xor(m, s, 64));
        const float L2E = 1.4426950408889634f;
        float e = (o < 40) ? exp2f((acc - m) * L2E) : 0.f;
        float ssum = e;
#pragma unroll
        for (int s = 32; s > 0; s >>= 1) ssum += __shfl_xor(ssum, s, 64);
        if (o < 40) outp[b * 40 + o] = e / ssum;  // kernel-end release flushes
    }
}

// ================= megakernel: grid-stride phases, works for any grid size =================
__global__ void __launch_bounds__(256, 2) k_mega(MArgs a) {
    __shared__ __align__(16) char smraw[17920];
    const int tid = threadIdx.x;
    const int G = gridDim.x;
    for (int wb = blockIdx.x; wb < 1024; wb += G) ph_shell(a, wb, smraw, tid);
    gbar();
    for (int wb = blockIdx.x; wb < 993; wb += G) {
        if (wb < 384) ph_sh(a, wb, smraw, tid);
        else if (wb < 992) ph_prep(a, wb, smraw, tid);
        else { __syncthreads(); if (tid < 224) st_wt(&a.stats[tid], 0.f); }
    }
    gbar();
    for (int wb = blockIdx.x; wb < 256; wb += G) ph_eval0(a, wb, smraw, tid);
    gbar();
    for (int wb = blockIdx.x; wb < 384; wb += G) {
        int mt = wb % 3, t = wb / 3;
        ph_coefG<165, 16, 8>(a.yq0, a.Dc1, a.stats, a.g0, a.be0, a.partA, mt, t & 15, t >> 4, smraw, tid);
    }
    gbar();
    for (int wb = blockIdx.x; wb < 512; wb += G)
        ph_redmix<165, 16, 32, 8, 192, 8>(a.partA, a.W1, a.b1, a.ymA, wb & 63, wb >> 6, smraw, tid);
    gbar();
    for (int wb = blockIdx.x; wb < 512; wb += G)
        ph_evalG<165, 192, 32>(a.ymA, a.Det1, a.yq1, a.stats + 32, wb & 31, wb >> 5, smraw, tid);
    gbar();
    for (int wb = blockIdx.x; wb < 512; wb += G) {
        int mt = wb & 1, t = wb >> 1;
        ph_coefG<84, 32, 8>(a.yq1, a.Dc2, a.stats + 32, a.g1, a.be1, a.partB, mt, t & 31, t >> 5, smraw, tid);
    }
    gbar();
    for (int wb = blockIdx.x; wb < 512; wb += G)
        ph_redmix<84, 32, 64, 8, 96, 8>(a.partB, a.W2, a.b2, a.ymB, wb & 63, wb >> 6, smraw, tid);
    gbar();
    for (int wb = blockIdx.x; wb < 1024; wb += G)
        ph_evalG<84, 96, 64>(a.ymB, a.Det2, a.yq2, a.stats + 96, wb & 63, wb >> 6, smraw, tid);
    gbar();
    for (int wb = blockIdx.x; wb < 1024; wb += G) {
        int mt = wb & 1, t = wb >> 1;
        ph_coefG<84, 64, QKN3>(a.yq2, a.Dc3, a.stats + 96, a.g2, a.be2, a.part3, mt, t & 63, t >> 6, smraw, tid);
    }
    gbar();
    for (int wb = blockIdx.x; wb < 256; wb += G) ph_norms(a.part3, a.ht0, wb & 63, wb >> 6, smraw, tid);
    gbar();
    for (int wb = blockIdx.x; wb < 512; wb += G)
        ph_fc<256, 512>(a.ht0, a.Wfc1, a.bfc1, a.gfc1, a.befc1, a.ht1, wb, smraw, tid);
    gbar();
    for (int wb = blockIdx.x; wb < 256; wb += G)
        ph_fc<512, 256>(a.ht1, a.Wfc2, a.bfc2, a.gfc2, a.befc2, a.ht2, wb, smraw, tid);
    gbar();
    for (int wb = blockIdx.x; wb < 64; wb += G) ph_out(a.ht2, a.Wout, a.bout, a.out, wb, smraw, tid);
}

// ================= fallback: the proven 14-kernel pipeline (verbatim baseline) =================
__global__ __launch_bounds__(256) void k_preshell(
    const float* __restrict__ De0, const float* __restrict__ De1, const float* __restrict__ De2,
    float* __restrict__ Dg0t, float* __restrict__ rs0,
    float* __restrict__ Det1, float* __restrict__ Det2,
    float* __restrict__ stats,
    const float* __restrict__ x, const float* __restrict__ dirs, float* __restrict__ pbuf) {
    __shared__ float tile[32][33];
    __shared__ float4 lx[NN / NCH];
    int blk = blockIdx.x, tid = threadIdx.x;
    if (blk < PREPB) {
        int r = tid >> 5, c = tid & 31;
        if (blk < 192) {
            int tq = blk & 31, tt = blk >> 5;
            int q0 = tq * 32, t0 = tt * 32;
            for (int rr = r; rr < 32; rr += 8) {
                int t = t0 + c;
                tile[rr][c] = (t < 165) ? De1[(q0 + rr) * 165 + t] : 0.f;
            }
            __syncthreads();
            for (int rr = r; rr < 32; rr += 8) {
                int t = t0 + rr;
                if (t < 165) Det1[t * QQ + q0 + c] = tile[c][rr];
            }
        } else if (blk < 288) {
            int i = blk - 192;
            int tq = i & 31, tt = i >> 5;
            int q0 = tq * 32, t0 = tt * 32;
            for (int rr = r; rr < 32; rr += 8) {
                int t = t0 + c;
                tile[rr][c] = (t < 84) ? De2[(q0 + rr) * 84 + t] : 0.f;
            }
            __syncthreads();
            for (int rr = r; rr < 32; rr += 8) {
                int t = t0 + rr;
                if (t < 84) Det2[t * QQ + q0 + c] = tile[c][rr];
            }
        } else if (blk < 352) {
            int i = blk - 288;
            int tq = i & 31, tj = i >> 5;
            int q0 = tq * 32, j0 = tj * 32;
            for (int rr = r; rr < 32; rr += 8) {
                int j = j0 + c;
                tile[rr][c] = (j < 36) ? De0[(q0 + rr) * 286 + PIDX[j]] : 0.f;
            }
            __syncthreads();
            for (int rr = r; rr < 32; rr += 8) {
                int j = j0 + rr;
                if (j < 36) Dg0t[j * QQ + q0 + c] = tile[c][rr];
            }
        } else if (blk < 608) {
            int w = tid >> 6, lane = tid & 63;
            int q = (blk - 352) * 4 + w;
            float s = 0.f;
#pragma unroll
            for (int p = 0; p < 5; p++) {
                int idx = lane + p * 64;
                if (idx < 286) s += De0[q * 286 + idx];
            }
#pragma unroll
            for (int o = 32; o > 0; o >>= 1) s += __shfl_xor(s, o, 64);
            if (lane == 0) rs0[q] = s;
        } else {
            if (tid < 224) stats[tid] = 0.f;
        }
        return;
    }
    int idx = blk - PREPB;
    int b = idx & 63, zc = idx >> 6;
    const float KL = 18.033688011112042f;
    const float* xb = x + ((size_t)b * NN + zc * (NN / NCH)) * 3;
    for (int n = tid; n < NN / NCH; n += 256) {
        float X = xb[n * 3 + 0];
        float Y = xb[n * 3 + 1];
        float Z = xb[n * 3 + 2];
        lx[n] = make_float4(X, Y, Z, -KL * (X * X + Y * Y + Z * Z));
    }
    __syncthreads();
    float cxs[3][2], cys[3][2], czs[3][2], bas[3][2];
#pragma unroll
    for (int i = 0; i < 3; i++) {
        float r = (i == 0) ? 0.4f : ((i == 1) ? 0.8f : 1.2f);
#pragma unroll
        for (int h = 0; h < 2; h++) {
            int s = tid + h * 256;
            float cx = r * dirs[(i * SS + s) * 3 + 0];
            float cy = r * dirs[(i * SS + s) * 3 + 1];
            float cz = r * dirs[(i * SS + s) * 3 + 2];
            bas[i][h] = -KL * (cx * cx + cy * cy + cz * cz);
            cxs[i][h] = 2.f * KL * cx;
            cys[i][h] = 2.f * KL * cy;
            czs[i][h] = 2.f * KL * cz;
        }
    }
    float acc[3][2];
#pragma unroll
    for (int i = 0; i < 3; i++) { acc[i][0] = 0.f; acc[i][1] = 0.f; }
#pragma unroll 4
    for (int n = 0; n < NN / NCH; n++) {
        float4 p = lx[n];
#pragma unroll
        for (int i = 0; i < 3; i++)
#pragma unroll
            for (int h = 0; h < 2; h++)
                acc[i][h] += __builtin_amdgcn_exp2f(
                    fmaf(cxs[i][h], p.x, fmaf(cys[i][h], p.y, fmaf(czs[i][h], p.z, p.w + bas[i][h]))));
    }
#pragma unroll
    for (int i = 0; i < 3; i++) {
        float* o = pbuf + ((size_t)(zc * 3 + i) * BB + b) * SS;
        o[tid] = acc[i][0];
        o[tid + 256] = acc[i][1];
    }
}

__global__ __launch_bounds__(256) void k_sh(const float* __restrict__ pbuf,
                                            const float* __restrict__ A_sh,
                                            float* __restrict__ lshp) {
    __shared__ float lf[256];
    int b = blockIdx.x, c = blockIdx.y, h = blockIdx.z, tid = threadIdx.x;
    float v = 0.f;
#pragma unroll
    for (int zc = 0; zc < NCH; zc++)
        v += pbuf[((size_t)(zc * 3 + c) * BB + b) * SS + h * 256 + tid];
    lf[tid] = v * (1.0f / NN);
    __syncthreads();
    int w = tid >> 6, lane = tid & 63;
    for (int j = w; j < 36; j += 4) {
        const float* As = A_sh + j * SS + h * 256;
        float a = 0.f;
#pragma unroll
        for (int k = 0; k < 4; k++) a = fmaf(lf[lane + 64 * k], As[lane + 64 * k], a);
#pragma unroll
        for (int o = 32; o > 0; o >>= 1) a += __shfl_xor(a, o, 64);
        if (lane == 0) lshp[((b * 36 + j) * 3 + c) * 2 + h] = a;
    }
}

__global__ __launch_bounds__(256) void k_eval0(const float* __restrict__ lshp,
                                               const float* __restrict__ W0,
                                               const float* __restrict__ b0,
                                               const float* __restrict__ Dg0t,
                                               const float* __restrict__ rs0,
                                               float* __restrict__ yq, float* __restrict__ stats) {
    __shared__ float lsh[36][3];
    __shared__ float llm[576];
    __shared__ float lred[4][32];
    int qc = blockIdx.x, b = blockIdx.y, tid = threadIdx.x;
    if (tid < 108) {
        int j = tid / 3, c = tid % 3;
        lsh[j][c] = lshp[((b * 36 + j) * 3 + c) * 2 + 0] + lshp[((b * 36 + j) * 3 + c) * 2 + 1];
    }
    __syncthreads();
    for (int i = tid; i < 576; i += 256) {
        int j = i >> 4, u = i & 15;
        float m = 0.f;
#pragma unroll
        for (int c = 0; c < 3; c++) m = fmaf(lsh[j][c], W0[c * 16 + u], m);
        llm[i] = m;
    }
    __syncthreads();
    int q = qc * 256 + tid;
    float acc[16];
#pragma unroll
    for (int u = 0; u < 16; u++) acc[u] = 0.f;
#pragma unroll 4
    for (int j = 0; j < 36; j++) {
        float d = Dg0t[j * QQ + q];
#pragma unroll
        for (int u = 0; u < 16; u++) acc[u] = fmaf(d, llm[j * 16 + u], acc[u]);
    }
    float rb = rs0[q];
#pragma unroll
    for (int u = 0; u < 16; u++) acc[u] = fmaf(b0[u], rb, acc[u]);
#pragma unroll
    for (int u = 0; u < 16; u++) yq[((size_t)b * 16 + u) * QQ + q] = acc[u];
    int lane = tid & 63, w = tid >> 6;
#pragma unroll
    for (int u = 0; u < 16; u++) {
        float v = acc[u], v2 = acc[u] * acc[u];
#pragma unroll
        for (int o = 32; o > 0; o >>= 1) {
            v += __shfl_xor(v, o, 64);
            v2 += __shfl_xor(v2, o, 64);
        }
        if (lane == 0) { lred[w][u] = v; lred[w][16 + u] = v2; }
    }
    __syncthreads();
    if (tid < 32) atomicAdd(&stats[tid], lred[0][tid] + lred[1][tid] + lred[2][tid] + lred[3][tid]);
}

template <int TT, int UU, int QKN>
__global__ __launch_bounds__(256) void k_coefG(const float* __restrict__ yq,
                                               const float* __restrict__ Dc,
                                               const float* __restrict__ stats,
                                               const float* __restrict__ g,
                                               const float* __restrict__ be,
                                               float* __restrict__ part) {
    constexpr int KC = QQ / QKN;
    __shared__ float lA[32][68];
    __shared__ float lB[32][68];
    __shared__ float lsu[UU], ltu[UU];
    int mt = blockIdx.x, nt = blockIdx.y, qk = blockIdx.z, tid = threadIdx.x;
    int m0 = mt * 64, n0 = nt * 64, k0 = qk * KC;
    if (tid < UU) {
        const float inv = 1.0f / (BB * QQ);
        float mm = stats[tid] * inv;
        float var = stats[UU + tid] * inv - mm * mm;
        float s = g[tid] * rsqrtf(fmaxf(var, 0.f) + 1e-3f);
        lsu[tid] = s;
        ltu[tid] = be[tid] - mm * s;
    }
    __syncthreads();
    int r = tid >> 2, f = (tid & 3) * 4;
    bool mok = (m0 + r) < TT;
    const float* arow = Dc + (size_t)(mok ? (m0 + r) : 0) * QQ;
    const float* brow = yq + (size_t)(n0 + r) * QQ;
    float su = lsu[(n0 + r) % UU], tu = ltu[(n0 + r) % UU];
    int tg = tid >> 4, ug = tid & 15;
    float acc[4][4];
#pragma unroll
    for (int i = 0; i < 4; i++)
#pragma unroll
        for (int j = 0; j < 4; j++) acc[i][j] = 0.f;
    for (int kb = 0; kb < KC; kb += 32) {
        int kg = k0 + kb;
#pragma unroll
        for (int p = 0; p < 2; p++) {
            int ko = f + p * 16;
            float4 a4 = make_float4(0.f, 0.f, 0.f, 0.f);
            if (mok) a4 = *(const float4*)(arow + kg + ko);
            float4 b4 = *(const float4*)(brow + kg + ko);
#pragma unroll
            for (int i = 0; i < 4; i++) {
                float v = fmaf((&b4.x)[i], su, tu);
                lA[ko + i][r] = (&a4.x)[i];
                lB[ko + i][r] = (v > 0.f) ? v : 0.3f * v;
            }
        }
        __syncthreads();
#pragma unroll 2
        for (int kk = 0; kk < 32; kk++) {
            float4 a4 = *(const float4*)&lA[kk][tg * 4];
            float4 b4 = *(const float4*)&lB[kk][ug * 4];
#pragma unroll
            for (int i = 0; i < 4; i++) {
                float av = (&a4.x)[i];
                acc[i][0] = fmaf(av, b4.x, acc[i][0]);
                acc[i][1] = fmaf(av, b4.y, acc[i][1]);
                acc[i][2] = fmaf(av, b4.z, acc[i][2]);
                acc[i][3] = fmaf(av, b4.w, acc[i][3]);
            }
        }
        __syncthreads();
    }
    int n = n0 + ug * 4;
    int b = n / UU, u0 = n % UU;
#pragma unroll
    for (int i = 0; i < 4; i++) {
        int t = m0 + tg * 4 + i;
        if (t < TT)
            *(float4*)&part[(((size_t)qk * BB + b) * TT + t) * UU + u0] =
                make_float4(acc[i][0], acc[i][1], acc[i][2], acc[i][3]);
    }
}

template <int TT, int CC, int UU, int QKN, int TTp, int TS>
__global__ __launch_bounds__(256) void k_redmix(const float* __restrict__ part,
                                                const float* __restrict__ W,
                                                const float* __restrict__ bias,
                                                float* __restrict__ ym) {
    constexpr int TSL = TTp / TS;
    __shared__ float lyt[TSL][CC + 1];
    int b = blockIdx.x, ts = blockIdx.y, tid = threadIdx.x;
    int t0 = ts * TSL;
    for (int i = tid; i < TSL * CC; i += 256) {
        int tl = i / CC, c = i % CC;
        int t = t0 + tl;
        float v = 0.f;
        if (t < TT) {
#pragma unroll
            for (int k = 0; k < QKN; k++)
                v += part[(size_t)k * (BB * TT * CC) + ((size_t)b * TT + t) * CC + c];
        }
        lyt[tl][c] = v;
    }
    __syncthreads();
    for (int i = tid; i < UU * TSL; i += 256) {
        int u = i / TSL, tl = i % TSL;
        int t = t0 + tl;
        float m = 0.f;
        if (t < TT) {
            m = bias[u];
#pragma unroll
            for (int c = 0; c < CC; c++) m = fmaf(lyt[tl][c], W[c * UU + u], m);
        }
        ym[((size_t)b * UU + u) * TTp + t] = m;
    }
}

template <int TT, int TTp, int UU>
__global__ __launch_bounds__(256) void k_evalG(const float* __restrict__ ym,
                                               const float* __restrict__ Det,
                                               float* __restrict__ yq,
                                               float* __restrict__ stats) {
    __shared__ float lA[32][68];
    __shared__ float lB[32][68];
    __shared__ float sred[2][64];
    int mt = blockIdx.x, qt = blockIdx.y, tid = threadIdx.x;
    int m0 = mt * 64, q0 = qt * 64;
    int r = tid >> 2, f = (tid & 3) * 4;
    const float* arow = ym + (size_t)(m0 + r) * TTp;
    int br = tid >> 4, bq = (tid & 15) * 4;
    int tg = tid >> 4, ug = tid & 15;
    float acc[4][4];
#pragma unroll
    for (int i = 0; i < 4; i++)
#pragma unroll
        for (int j = 0; j < 4; j++) acc[i][j] = 0.f;
    for (int kb = 0; kb < TT; kb += 32) {
#pragma unroll
        for (int p = 0; p < 2; p++) {
            int ko = f + p * 16;
            float4 a4 = *(const float4*)(arow + kb + ko);
#pragma unroll
            for (int i = 0; i < 4; i++) lA[ko + i][r] = (&a4.x)[i];
            int kk = br + p * 16;
            int t = kb + kk;
            float4 b4 = make_float4(0.f, 0.f, 0.f, 0.f);
            if (t < TT) b4 = *(const float4*)(Det + (size_t)t * QQ + q0 + bq);
            *(float4*)&lB[kk][bq] = b4;
        }
        __syncthreads();
#pragma unroll 2
        for (int kk = 0; kk < 32; kk++) {
            float4 a4 = *(const float4*)&lA[kk][tg * 4];
            float4 b4 = *(const float4*)&lB[kk][ug * 4];
#pragma unroll
            for (int i = 0; i < 4; i++) {
                float av = (&a4.x)[i];
                acc[i][0] = fmaf(av, b4.x, acc[i][0]);
                acc[i][1] = fmaf(av, b4.y, acc[i][1]);
                acc[i][2] = fmaf(av, b4.z, acc[i][2]);
                acc[i][3] = fmaf(av, b4.w, acc[i][3]);
            }
        }
        __syncthreads();
    }
    float s1[4], s2[4];
#pragma unroll
    for (int i = 0; i < 4; i++) {
        int m = m0 + tg * 4 + i;
        *(float4*)&yq[(size_t)m * QQ + q0 + ug * 4] =
            make_float4(acc[i][0], acc[i][1], acc[i][2], acc[i][3]);
        s1[i] = (acc[i][0] + acc[i][1]) + (acc[i][2] + acc[i][3]);
        s2[i] = fmaf(acc[i][0], acc[i][0], fmaf(acc[i][1], acc[i][1],
                 fmaf(acc[i][2], acc[i][2], acc[i][3] * acc[i][3])));
    }
#pragma unroll
    for (int o = 1; o < 16; o <<= 1) {
#pragma unroll
        for (int i = 0; i < 4; i++) {
            s1[i] += __shfl_xor(s1[i], o, 64);
            s2[i] += __shfl_xor(s2[i], o, 64);
        }
    }
    if (ug == 0) {
#pragma unroll
        for (int i = 0; i < 4; i++) {
            sred[0][tg * 4 + i] = s1[i];
            sred[1][tg * 4 + i] = s2[i];
        }
    }
    __syncthreads();
    if (tid < 2 * UU) {
        int which = tid / UU, u = tid % UU;
        float s = 0.f;
        for (int rr = u; rr < 64; rr += UU) s += sred[which][rr];
        atomicAdd(&stats[which * UU + u], s);
    }
}

__global__ __launch_bounds__(256) void k_norms(const float* __restrict__ part, float* __restrict__ ht0) {
    __shared__ float red[4][64];
    int b = blockIdx.x, blk = blockIdx.y;
    int tq = threadIdx.x >> 6, u = threadIdx.x & 63;
    const int offs[4] = {0, 1, 10, 35};
    const int ends[4] = {1, 10, 35, 84};
    float a = 0.f;
    for (int t = offs[blk] + tq; t < ends[blk]; t += 4) {
        float v = 0.f;
#pragma unroll
        for (int k = 0; k < QKN3; k++)
            v += part[(size_t)k * (BB * 84 * 64) + (b * 84 + t) * 64 + u];
        a = fmaf(v, v, a);
    }
    red[tq][u] = a;
    __syncthreads();
    if (tq == 0) {
        float s = red[0][u] + red[1][u] + red[2][u] + red[3][u];
        ht0[(blk * 64 + u) * BB + b] = sqrtf(fmaxf(s, 0.f));
    }
}

template <int K, int J>
__global__ __launch_bounds__(512) void k_fc(const float* __restrict__ in, const float* __restrict__ W,
                                            const float* __restrict__ bias, const float* __restrict__ g,
                                            const float* __restrict__ be, float* __restrict__ out) {
    __shared__ float red[8][64];
    int j = blockIdx.x;
    int b = threadIdx.x & 63, kq = threadIdx.x >> 6;
    constexpr int KS = K / 8;
    int kbeg = kq * KS;
    float a0 = 0.f, a1 = 0.f, a2 = 0.f, a3 = 0.f;
#pragma unroll 4
    for (int k = kbeg; k < kbeg + KS; k += 4) {
        a0 = fmaf(in[k * BB + b], W[(size_t)k * J + j], a0);
        a1 = fmaf(in[(k + 1) * BB + b], W[(size_t)(k + 1) * J + j], a1);
        a2 = fmaf(in[(k + 2) * BB + b], W[(size_t)(k + 2) * J + j], a2);
        a3 = fmaf(in[(k + 3) * BB + b], W[(size_t)(k + 3) * J + j], a3);
    }
    red[kq][b] = (a0 + a1) + (a2 + a3);
    __syncthreads();
    if (kq == 0) {
        float acc = bias[j];
#pragma unroll
        for (int i = 0; i < 8; i++) acc += red[i][b];
        float s1 = acc, s2 = acc * acc;
#pragma unroll
        for (int o = 32; o > 0; o >>= 1) {
            s1 += __shfl_xor(s1, o, 64);
            s2 += __shfl_xor(s2, o, 64);
        }
        float m = s1 * (1.0f / 64.f);
        float var = s2 * (1.0f / 64.f) - m * m;
        float sc = g[j] * rsqrtf(fmaxf(var, 0.f) + 1e-3f);
        float v = (acc - m) * sc + be[j];
        out[j * BB + b] = fmaxf(v, 0.f);
    }
}

__global__ __launch_bounds__(256) void k_out(const float* __restrict__ ht2, const float* __restrict__ Wout,
                                             const float* __restrict__ bout, float* __restrict__ outp) {
    __shared__ float red[4][64];
    __shared__ float sm[64];
    int b = blockIdx.x;
    int o = threadIdx.x & 63, kq = threadIdx.x >> 6;
    float a0 = 0.f, a1 = 0.f, a2 = 0.f, a3 = 0.f;
    int kbeg = kq * 64;
    if (o < 40) {
#pragma unroll 4
        for (int k = kbeg; k < kbeg + 64; k += 4) {
            a0 = fmaf(ht2[k * BB + b], Wout[k * 40 + o], a0);
            a1 = fmaf(ht2[(k + 1) * BB + b], Wout[(k + 1) * 40 + o], a1);
            a2 = fmaf(ht2[(k + 2) * BB + b], Wout[(k + 2) * 40 + o], a2);
            a3 = fmaf(ht2[(k + 3) * BB + b], Wout[(k + 3) * 40 + o], a3);
        }
    }
    red[kq][o] = (a0 + a1) + (a2 + a3);
    __syncthreads();
    if (kq == 0) {
        float acc = red[0][o] + red[1][o] + red[2][o] + red[3][o] + ((o < 40) ? bout[o] : 0.f);
        sm[o] = (o < 40) ? acc : -3.0e38f;
        __syncthreads();
        for (int s = 32; s > 0; s >>= 1) {
            if (o < s) sm[o] = fmaxf(sm[o], sm[o + s]);
            __syncthreads();
        }
        float m = sm[0];
        __syncthreads();
        const float L2E = 1.4426950408889634f;
        float e = (o < 40) ? exp2f((acc - m) * L2E) : 0.f;
        sm[o] = e;
        __syncthreads();
        for (int s = 32; s > 0; s >>= 1) {
            if (o < s) sm[o] += sm[o + s];
            __syncthreads();
        }
        if (o < 40) outp[b * 40 + o] = e / sm[0];
    }
}

// ---------------- workspace layout (float offsets; all 128B-aligned; no buffer
// written twice within a run — required by the write-through coherence scheme) ----
#define OFF_PBUF 0           // 1572864
#define OFF_DG0T 1572864     // 36864
#define OFF_RS0 1609728      // 1024
#define OFF_DET1 1610752     // 168960
#define OFF_DET2 1779712     // 86016
#define OFF_YQ0 1865728      // 1048576
#define OFF_YQ1 2914304      // 2097152
#define OFF_YQ2 5011456      // 4194304
#define OFF_YMA 9205760      // 393216
#define OFF_YMB 9598976      // 393216
#define OFF_LSH 9992192      // 13824
#define OFF_HT0 10006016     // 16384
#define OFF_HT1 10022400     // 32768
#define OFF_HT2 10055168     // 16384
#define OFF_STATS 10071552   // 224 (+pad to 256)
#define OFF_PARTA 10071808   // 1351680
#define OFF_PARTB 11423488   // 1376256
#define OFF_PART3 12799744   // 2752512 (ends 15552256 floats = 62 MB)

extern "C" void kernel_launch(void* const* d_in, const int* in_sizes, int n_in,
                              void* d_out, int out_size, void* d_ws, size_t ws_size,
                              hipStream_t stream) {
    float* ws = (float*)d_ws;
    MArgs a;
    a.x = (const float*)d_in[0];
    a.dirs = (const float*)d_in[1];
    a.A_sh = (const float*)d_in[2];
    a.De0 = (const float*)d_in[3];
    a.De1 = (const float*)d_in[4];
    a.De2 = (const float*)d_in[5];
    a.Dc1 = (const float*)d_in[6];
    a.Dc2 = (const float*)d_in[7];
    a.Dc3 = (const float*)d_in[8];
    a.W0 = (const float*)d_in[9];
    a.b0 = (const float*)d_in[10];
    a.W1 = (const float*)d_in[11];
    a.b1 = (const float*)d_in[12];
    a.W2 = (const float*)d_in[13];
    a.b2 = (const float*)d_in[14];
    a.g0 = (const float*)d_in[15];
    a.be0 = (const float*)d_in[16];
    a.g1 = (const float*)d_in[17];
    a.be1 = (const float*)d_in[18];
    a.g2 = (const float*)d_in[19];
    a.be2 = (const float*)d_in[20];
    a.Wfc1 = (const float*)d_in[21];
    a.bfc1 = (const float*)d_in[22];
    a.gfc1 = (const float*)d_in[23];
    a.befc1 = (const float*)d_in[24];
    a.Wfc2 = (const float*)d_in[25];
    a.bfc2 = (const float*)d_in[26];
    a.gfc2 = (const float*)d_in[27];
    a.befc2 = (const float*)d_in[28];
    a.Wout = (const float*)d_in[29];
    a.bout = (const float*)d_in[30];
    a.pbuf = ws + OFF_PBUF;
    a.Dg0t = ws + OFF_DG0T;
    a.rs0 = ws + OFF_RS0;
    a.Det1 = ws + OFF_DET1;
    a.Det2 = ws + OFF_DET2;
    a.yq0 = ws + OFF_YQ0;
    a.yq1 = ws + OFF_YQ1;
    a.yq2 = ws + OFF_YQ2;
    a.ymA = ws + OFF_YMA;
    a.ymB = ws + OFF_YMB;
    a.lshp = ws + OFF_LSH;
    a.ht0 = ws + OFF_HT0;
    a.ht1 = ws + OFF_HT1;
    a.ht2 = ws + OFF_HT2;
    a.stats = ws + OFF_STATS;
    a.partA = ws + OFF_PARTA;
    a.partB = ws + OFF_PARTB;
    a.part3 = ws + OFF_PART3;
    a.out = (float*)d_out;

    // ---- one-time viability gate (host queries only; no stream ops) ----
    // REGULAR launch (not cooperative): the barrier needs only co-residency,
    // guaranteed when grid <= occ x CUs per the occupancy query (plain launch
    // completed fine in R6/R7 — liveness proven). Cooperative dispatch carried
    // ~120us/replay of queue-drain overhead (Round-4 decomposition).
    static int mode = -1;
    static int gsize = 0;
    if (mode < 0) {
        int dev = 0;
        (void)hipGetDevice(&dev);
        int ncu = 0;
        (void)hipDeviceGetAttribute(&ncu, hipDeviceAttributeMultiprocessorCount, dev);
        int occ = 0;
        hipError_t e = hipOccupancyMaxActiveBlocksPerMultiprocessor(&occ, (const void*)k_mega, 256, 0);
        long long mg = (long long)occ * (long long)ncu;
        if (e == hipSuccess && mg >= 256) {
            int gs = (int)(mg > 1024 ? 1024 : mg);
            gsize = gs & ~31;  // multiple of 32 for the tree barrier
            mode = (gsize >= 256) ? 1 : 0;
        } else {
            mode = 0;
        }
    }

    if (mode == 1) {
        k_mega<<<dim3(gsize), dim3(256), 0, stream>>>(a);
        return;
    }

    // ---- fallback: proven 14-kernel pipeline ----
    float* stats0 = a.stats;
    float* stats1 = a.stats + 32;
    float* stats2 = a.stats + 96;
    k_preshell<<<PREPB + BB * NCH, 256, 0, stream>>>(
        a.De0, a.De1, a.De2, a.Dg0t, a.rs0, a.Det1, a.Det2, a.stats, a.x, a.dirs, a.pbuf);
    k_sh<<<dim3(BB, 3, 2), 256, 0, stream>>>(a.pbuf, a.A_sh, a.lshp);
    k_eval0<<<dim3(4, BB), 256, 0, stream>>>(a.lshp, a.W0, a.b0, a.Dg0t, a.rs0, a.yq0, stats0);
    k_coefG<165, 16, 8><<<dim3(3, 16, 8), 256, 0, stream>>>(a.yq0, a.Dc1, stats0, a.g0, a.be0, a.partA);
    k_redmix<165, 16, 32, 8, 192, 8><<<dim3(BB, 8), 256, 0, stream>>>(a.partA, a.W1, a.b1, a.ymA);
    k_evalG<165, 192, 32><<<dim3(32, 16), 256, 0, stream>>>(a.ymA, a.Det1, a.yq1, stats1);
    k_coefG<84, 32, 8><<<dim3(2, 32, 8), 256, 0, stream>>>(a.yq1, a.Dc2, stats1, a.g1, a.be1, a.partB);
    k_redmix<84, 32, 64, 8, 96, 8><<<dim3(BB, 8), 256, 0, stream>>>(a.partB, a.W2, a.b2, a.ymB);
    k_evalG<84, 96, 64><<<dim3(64, 16), 256, 0, stream>>>(a.ymB, a.Det2, a.yq2, stats2);
    k_coefG<84, 64, QKN3><<<dim3(2, 64, QKN3), 256, 0, stream>>>(a.yq2, a.Dc3, stats2, a.g2, a.be2, a.part3);
    k_norms<<<dim3(BB, 4), 256, 0, stream>>>(a.part3, a.ht0);
    k_fc<256, 512><<<512, 512, 0, stream>>>(a.ht0, a.Wfc1, a.bfc1, a.gfc1, a.befc1, a.ht1);
    k_fc<512, 256><<<256, 512, 0, stream>>>(a.ht1, a.Wfc2, a.bfc2, a.gfc2, a.befc2, a.ht2);
    k_out<<<BB, 256, 0, stream>>>(a.ht2, a.Wout, a.bout, a.out);
}